// Round 5
// baseline (713.129 us; speedup 1.0000x reference)
//
#include <hip/hip_runtime.h>
#include <math.h>

#define N_NODES 20000
#define N_EDGES 320000
#define F_IN    518
#define HIDDEN  256
#define DIM     128
#define NH      4

typedef __attribute__((ext_vector_type(8))) short bf16x8;
typedef __attribute__((ext_vector_type(4))) float f32x4;

__device__ __forceinline__ float lrelu02(float x) { return x > 0.f ? x : 0.2f * x; }

// ========== split-bf16 MFMA GEMM: C[M,N] = act(A@B + bias) ==========
// 128x64 tile, 4 waves (each 64x32 = 4x2 mfma 16x16x32 tiles), double-buffered
// LDS, one barrier per K-block. A fp32 -> bf16 hi/lo split in-kernel;
// B pre-split to [kb][n][32] hi/lo. C = Ah*Bh + Ah*Bl + Al*Bh.
__global__ __launch_bounds__(256, 2) void gemm_mfma_split(
    const float* __restrict__ A, const unsigned short* __restrict__ Bth,
    const unsigned short* __restrict__ Btl, const float* __restrict__ bias,
    float* __restrict__ C, int M, int N, int K, int act)
{
    // per-buffer ushort layout, row stride 40 (80 B, 16B-aligned):
    // Ah [0,128*40) | Al [128*40,256*40) | Bh [256*40,320*40) | Bl [320*40,384*40)
    __shared__ __align__(16) unsigned short lds[2][384 * 40];

    const int tid = threadIdx.x;
    const int row0 = blockIdx.y * 128, col0 = blockIdx.x * 64;
    const int nkb = (K + 31) >> 5;

    // --- A staging role: row = tid>>1, k-half = (tid&1)*16 ---
    const int ar  = tid >> 1;
    const int ahf = tid & 1;
    const bool avalid = (row0 + ar) < M;
    const float* aptr = A + (size_t)(row0 + ar) * K;

    // --- B staging role: col = tid&63; quarter = tid>>6 -> {k-half, hi/lo} ---
    const int bcol = tid & 63;
    const int bq  = tid >> 6;
    const int bkh = bq & 1;
    const int bw  = bq >> 1;
    const unsigned short* bsrc = bw ? Btl : Bth;

    float2 astg[8];
    uint4  bstg[2];

    auto stage_load = [&](int kb) {
        const int kt = kb * 32 + ahf * 16;
        #pragma unroll
        for (int i = 0; i < 8; ++i) {
            const int gk = kt + 2 * i;
            float2 v = {0.f, 0.f};
            if (avalid && gk < K) {
                if (gk + 1 < K) v = *(const float2*)(aptr + gk);
                else            v.x = aptr[gk];
            }
            astg[i] = v;
        }
        const unsigned short* bp = bsrc + ((size_t)kb * N + col0 + bcol) * 32 + bkh * 16;
        bstg[0] = *(const uint4*)bp;
        bstg[1] = *(const uint4*)(bp + 8);
    };

    auto stage_write = [&](unsigned short* buf) {
        unsigned int hp[8], lp[8];
        #pragma unroll
        for (int i = 0; i < 8; ++i) {
            unsigned int bx = __float_as_uint(astg[i].x);
            unsigned int by = __float_as_uint(astg[i].y);
            unsigned int hx = bx & 0xFFFF0000u, hy = by & 0xFFFF0000u;
            hp[i] = hy | (hx >> 16);
            float lx = astg[i].x - __uint_as_float(hx);
            float ly = astg[i].y - __uint_as_float(hy);
            lp[i] = (__float_as_uint(ly) & 0xFFFF0000u) | (__float_as_uint(lx) >> 16);
        }
        unsigned short* pa = buf + ar * 40 + ahf * 16;
        ((uint4*)pa)[0] = make_uint4(hp[0], hp[1], hp[2], hp[3]);
        ((uint4*)pa)[1] = make_uint4(hp[4], hp[5], hp[6], hp[7]);
        unsigned short* pl = buf + 128 * 40 + ar * 40 + ahf * 16;
        ((uint4*)pl)[0] = make_uint4(lp[0], lp[1], lp[2], lp[3]);
        ((uint4*)pl)[1] = make_uint4(lp[4], lp[5], lp[6], lp[7]);
        unsigned short* pb = buf + (256 + bw * 64 + bcol) * 40 + bkh * 16;
        ((uint4*)pb)[0] = bstg[0];
        ((uint4*)pb)[1] = bstg[1];
    };

    // --- compute roles: wave w -> (wm*64 rows, wn*32 cols) ---
    const int w = tid >> 6, lane = tid & 63;
    const int wm = w & 1, wn = w >> 1;
    const int m16 = lane & 15, q = lane >> 4;

    f32x4 acc[4][2] = {};

    stage_load(0);
    stage_write(lds[0]);
    __syncthreads();

    for (int kb = 0; kb < nkb; ++kb) {
        unsigned short* buf = lds[kb & 1];
        if (kb + 1 < nkb) stage_load(kb + 1);

        bf16x8 ah[4], al[4], bh[2], bl[2];
        #pragma unroll
        for (int mi = 0; mi < 4; ++mi) {
            const int off = (wm * 64 + mi * 16 + m16) * 40 + q * 8;
            ah[mi] = *(const bf16x8*)&buf[off];
            al[mi] = *(const bf16x8*)&buf[128 * 40 + off];
        }
        #pragma unroll
        for (int ni = 0; ni < 2; ++ni) {
            const int cl = wn * 32 + ni * 16 + m16;
            bh[ni] = *(const bf16x8*)&buf[(256 + cl) * 40 + q * 8];
            bl[ni] = *(const bf16x8*)&buf[(320 + cl) * 40 + q * 8];
        }
        #pragma unroll
        for (int mi = 0; mi < 4; ++mi)
            #pragma unroll
            for (int ni = 0; ni < 2; ++ni)
                acc[mi][ni] = __builtin_amdgcn_mfma_f32_16x16x32_bf16(ah[mi], bh[ni], acc[mi][ni], 0, 0, 0);
        #pragma unroll
        for (int mi = 0; mi < 4; ++mi)
            #pragma unroll
            for (int ni = 0; ni < 2; ++ni)
                acc[mi][ni] = __builtin_amdgcn_mfma_f32_16x16x32_bf16(ah[mi], bl[ni], acc[mi][ni], 0, 0, 0);
        #pragma unroll
        for (int mi = 0; mi < 4; ++mi)
            #pragma unroll
            for (int ni = 0; ni < 2; ++ni)
                acc[mi][ni] = __builtin_amdgcn_mfma_f32_16x16x32_bf16(al[mi], bh[ni], acc[mi][ni], 0, 0, 0);

        if (kb + 1 < nkb) stage_write(lds[(kb + 1) & 1]);
        __syncthreads();
    }

    // epilogue: C/D row=(lane>>4)*4+reg, col=lane&15
    #pragma unroll
    for (int ni = 0; ni < 2; ++ni) {
        const int col = col0 + wn * 32 + ni * 16 + m16;
        const float bb = bias ? bias[col] : 0.f;
        #pragma unroll
        for (int mi = 0; mi < 4; ++mi) {
            const int rbase = row0 + wm * 64 + mi * 16 + q * 4;
            #pragma unroll
            for (int r = 0; r < 4; ++r) {
                const int row = rbase + r;
                if (row < M) {
                    float v = acc[mi][ni][r] + bb;
                    if (act) v = fmaxf(v, 0.f);
                    C[(size_t)row * N + col] = v;
                }
            }
        }
    }
}

// ---- weight conversion: w[K,N] fp32 -> Bt hi/lo bf16, layout [kb][n][32] ----
__global__ __launch_bounds__(256) void conv_b_kernel(
    const float* __restrict__ w, unsigned short* __restrict__ bh,
    unsigned short* __restrict__ bl, int K, int N, int total)
{
    const int idx = blockIdx.x * 256 + threadIdx.x;
    if (idx >= total) return;
    const int ki = idx & 31;
    const int rem = idx >> 5;
    const int n = rem % N;
    const int kb = rem / N;
    const int k = kb * 32 + ki;
    const float v = (k < K) ? w[(size_t)k * N + n] : 0.f;
    const unsigned int b = __float_as_uint(v);
    const unsigned int h = b & 0xFFFF0000u;
    bh[idx] = (unsigned short)(h >> 16);
    const float lo = v - __uint_as_float(h);
    bl[idx] = (unsigned short)(__float_as_uint(lo) >> 16);
}

// ------------- a_s[n,h], a_d[n,h]: one wave per (n,h) pair -------------
__global__ __launch_bounds__(256) void as_ad_kernel(
    const float* __restrict__ hfeat, const float* __restrict__ atts,
    const float* __restrict__ attd, float* __restrict__ a_s, float* __restrict__ a_d)
{
    const int gw = blockIdx.x * 4 + (threadIdx.x >> 6);
    const int lane = threadIdx.x & 63;
    if (gw >= N_NODES * NH) return;
    const int n = gw >> 2, h = gw & 3;
    const float* hp = hfeat + (size_t)n * (NH * DIM) + h * DIM;
    float2 hv = *(const float2*)(hp + lane * 2);
    float2 sv = *(const float2*)(atts + h * DIM + lane * 2);
    float2 dv = *(const float2*)(attd + h * DIM + lane * 2);
    float s = hv.x * sv.x + hv.y * sv.y;
    float d = hv.x * dv.x + hv.y * dv.y;
    #pragma unroll
    for (int off = 32; off > 0; off >>= 1) {
        s += __shfl_down(s, off);
        d += __shfl_down(d, off);
    }
    if (lane == 0) { a_s[n * 4 + h] = s; a_d[n * 4 + h] = d; }
}

// ------------- rel attention table[r,h] -------------
__global__ __launch_bounds__(128) void rel_table_kernel(
    const float* __restrict__ rel_emb, const float* __restrict__ line,
    const float* __restrict__ atte, float* __restrict__ table)
{
    __shared__ float we[32][NH];
    const int tid = threadIdx.x;
    const int k = tid >> 2, h = tid & 3;
    float acc = 0.f;
    for (int d = 0; d < DIM; ++d)
        acc += line[(size_t)k * (NH * DIM) + h * DIM + d] * atte[h * DIM + d];
    we[k][h] = acc;
    __syncthreads();
    if (tid < 26 * NH) {
        int r = tid >> 2, hh = tid & 3;
        float t = 0.f;
        for (int kk = 0; kk < 32; ++kk) t += rel_emb[r * 32 + kk] * we[kk][hh];
        table[r * 4 + hh] = t;
    }
}

// ================= CSR build =================
__global__ __launch_bounds__(256) void hist_kernel(
    const int* __restrict__ dst, int* __restrict__ cnt)
{
    const int e = blockIdx.x * blockDim.x + threadIdx.x;
    if (e >= N_EDGES) return;
    atomicAdd(&cnt[dst[e]], 1);
}

__global__ __launch_bounds__(1024) void scan_kernel(
    const int* __restrict__ cnt, int* __restrict__ ptr, int* __restrict__ ptr_copy)
{
    __shared__ int tsum[1024];
    const int tid = threadIdx.x;
    const int CH = 20;
    const int base = tid * CH;
    int s = 0;
    #pragma unroll
    for (int i = 0; i < CH; ++i) {
        int idx = base + i;
        if (idx < N_NODES) s += cnt[idx];
    }
    tsum[tid] = s;
    __syncthreads();
    for (int off = 1; off < 1024; off <<= 1) {
        int v = (tid >= off) ? tsum[tid - off] : 0;
        __syncthreads();
        tsum[tid] += v;
        __syncthreads();
    }
    int run = (tid == 0) ? 0 : tsum[tid - 1];
    #pragma unroll
    for (int i = 0; i < CH; ++i) {
        int idx = base + i;
        if (idx < N_NODES) {
            ptr[idx] = run;
            ptr_copy[idx] = run;
            run += cnt[idx];
        }
    }
    if (tid == 0) ptr[N_NODES] = N_EDGES;
}

__global__ __launch_bounds__(256) void scatter_kernel(
    const int* __restrict__ src, const int* __restrict__ dst, const int* __restrict__ etype,
    int* __restrict__ ptr_copy, int* __restrict__ src_s, int* __restrict__ etype_s)
{
    const int e = blockIdx.x * blockDim.x + threadIdx.x;
    if (e >= N_EDGES) return;
    const int d = dst[e];
    const int pos = atomicAdd(&ptr_copy[d], 1);
    src_s[pos] = src[e];
    etype_s[pos] = etype[e];
}

// ===== fused per-node GAT aggregate. One wave/node; 2x dwordx4 gather =====
// Lane layout: vA = hfeat[s][lane*4 .. +3]   -> heads 0 (lanes<32) / 1 (>=32)
//              vB = hfeat[s][256+lane*4..+3] -> heads 2 / 3
// Final col c combines lanes c/4 and 32+c/4 via shfl_xor(32).
__global__ __launch_bounds__(256) void node_agg_kernel(
    const int* __restrict__ ptr, const int* __restrict__ src_s, const int* __restrict__ etype_s,
    const float* __restrict__ a_s, const float* __restrict__ a_d,
    const float* __restrict__ table, const float* __restrict__ hfeat,
    const float* __restrict__ bias, float* __restrict__ out)
{
    const int n = blockIdx.x * 4 + (threadIdx.x >> 6);
    const int lane = threadIdx.x & 63;
    if (n >= N_NODES) return;
    const int beg = ptr[n], end = ptr[n + 1];
    const bool lo_half = lane < 32;
    const int coff = lane * 4;

    const float4 ad4 = *(const float4*)(a_d + n * 4);
    float4 accA = {0,0,0,0}, accB = {0,0,0,0};
    float d0 = 0, d1 = 0, d2 = 0, d3 = 0;
    float e0 = 0, e1 = 0, e2 = 0, e3 = 0;

    int sj = 0, tj = 0;
    if (beg < end) { sj = src_s[beg]; tj = etype_s[beg]; }
    for (int j = beg; j < end; ++j) {
        const int s = sj, t = tj;
        if (j + 1 < end) { sj = src_s[j + 1]; tj = etype_s[j + 1]; }
        const float4 as4 = *(const float4*)(a_s + s * 4);
        const float4 tv  = *(const float4*)(table + t * 4);
        const float* hp = hfeat + (size_t)s * (NH * DIM);
        const float4 vA = *(const float4*)(hp + coff);
        const float4 vB = *(const float4*)(hp + 256 + coff);
        const float p0 = __expf(lrelu02(as4.x + ad4.x + tv.x));
        const float p1 = __expf(lrelu02(as4.y + ad4.y + tv.y));
        const float p2 = __expf(lrelu02(as4.z + ad4.z + tv.z));
        const float p3 = __expf(lrelu02(as4.w + ad4.w + tv.w));
        e0 += tv.x; e1 += tv.y; e2 += tv.z; e3 += tv.w;
        d0 += p0; d1 += p1; d2 += p2; d3 += p3;
        const float wA = lo_half ? p0 : p1;
        const float wB = lo_half ? p2 : p3;
        accA.x += wA * vA.x; accA.y += wA * vA.y; accA.z += wA * vA.z; accA.w += wA * vA.w;
        accB.x += wB * vB.x; accB.y += wB * vB.y; accB.z += wB * vB.z; accB.w += wB * vB.w;
    }

    // self-loop (fill_value='mean')
    const float inv = 1.0f / fmaxf((float)(end - beg), 1.0f);
    const float4 asn = *(const float4*)(a_s + n * 4);
    {
        const float p0 = __expf(lrelu02(asn.x + ad4.x + e0 * inv));
        const float p1 = __expf(lrelu02(asn.y + ad4.y + e1 * inv));
        const float p2 = __expf(lrelu02(asn.z + ad4.z + e2 * inv));
        const float p3 = __expf(lrelu02(asn.w + ad4.w + e3 * inv));
        d0 += p0; d1 += p1; d2 += p2; d3 += p3;
        const float* hp = hfeat + (size_t)n * (NH * DIM);
        const float4 vA = *(const float4*)(hp + coff);
        const float4 vB = *(const float4*)(hp + 256 + coff);
        const float wA = lo_half ? p0 : p1;
        const float wB = lo_half ? p2 : p3;
        accA.x += wA * vA.x; accA.y += wA * vA.y; accA.z += wA * vA.z; accA.w += wA * vA.w;
        accB.x += wB * vB.x; accB.y += wB * vB.y; accB.z += wB * vB.z; accB.w += wB * vB.w;
    }

    const float iA = 0.25f / ((lo_half ? d0 : d1) + 1e-16f);
    const float iB = 0.25f / ((lo_half ? d2 : d3) + 1e-16f);
    float4 tmp;
    tmp.x = accA.x * iA + accB.x * iB;
    tmp.y = accA.y * iA + accB.y * iB;
    tmp.z = accA.z * iA + accB.z * iB;
    tmp.w = accA.w * iA + accB.w * iB;
    tmp.x += __shfl_xor(tmp.x, 32);
    tmp.y += __shfl_xor(tmp.y, 32);
    tmp.z += __shfl_xor(tmp.z, 32);
    tmp.w += __shfl_xor(tmp.w, 32);
    if (lo_half) {
        const float4 b = *(const float4*)(bias + coff);
        float4 o;
        o.x = fmaxf(tmp.x + b.x, 0.f);
        o.y = fmaxf(tmp.y + b.y, 0.f);
        o.z = fmaxf(tmp.z + b.z, 0.f);
        o.w = fmaxf(tmp.w + b.w, 0.f);
        *(float4*)(out + (size_t)n * DIM + coff) = o;
    }
}

extern "C" void kernel_launch(void* const* d_in, const int* in_sizes, int n_in,
                              void* d_out, int out_size, void* d_ws, size_t ws_size,
                              hipStream_t stream)
{
    const float* x       = (const float*)d_in[0];
    const int*   eidx    = (const int*)d_in[1];
    const int*   etype   = (const int*)d_in[2];
    const float* w1      = (const float*)d_in[3];
    const float* b1      = (const float*)d_in[4];
    const float* w2      = (const float*)d_in[5];
    const float* b2      = (const float*)d_in[6];
    const float* rel_emb = (const float*)d_in[7];
    const float* lin[2]  = {(const float*)d_in[8],  (const float*)d_in[14]};
    const float* line[2] = {(const float*)d_in[9],  (const float*)d_in[15]};
    const float* atts[2] = {(const float*)d_in[10], (const float*)d_in[16]};
    const float* attd[2] = {(const float*)d_in[11], (const float*)d_in[17]};
    const float* atte[2] = {(const float*)d_in[12], (const float*)d_in[18]};
    const float* bias[2] = {(const float*)d_in[13], (const float*)d_in[19]};
    const int* src = eidx;
    const int* dst = eidx + N_EDGES;

    float* wsf   = (float*)d_ws;
    float* hfeat = wsf;                                   // N*512
    float* xbuf  = hfeat + (size_t)N_NODES * (NH * DIM);  // N*128
    float* a_s   = xbuf + (size_t)N_NODES * DIM;          // N*4
    float* a_d   = a_s + N_NODES * 4;                     // N*4
    float* table = a_d + N_NODES * 4;                     // 128
    unsigned short* b1h = (unsigned short*)(table + 128); // 17*256*32
    unsigned short* b1l = b1h + 17 * 256 * 32;
    unsigned short* b2h = b1l + 17 * 256 * 32;            // 8*128*32
    unsigned short* b2l = b2h + 8 * 128 * 32;
    unsigned short* b3h = b2l + 8 * 128 * 32;             // 4*512*32
    unsigned short* b3l = b3h + 4 * 512 * 32;
    unsigned short* b4h = b3l + 4 * 512 * 32;
    unsigned short* b4l = b4h + 4 * 512 * 32;
    int*   iws   = (int*)(b4l + 4 * 512 * 32);
    int*   cnt_i = iws;                                   // N
    int*   ptr   = cnt_i + N_NODES;                       // N+1
    int*   ptrc  = ptr + N_NODES + 1;                     // N
    int*   src_s = ptrc + N_NODES;                        // E
    int*   ety_s = src_s + N_EDGES;                       // E

    const int mtiles = (N_NODES + 127) / 128;             // 157

    // ---- weight conversions ----
    conv_b_kernel<<<(17*256*32 + 255)/256, 256, 0, stream>>>(w1, b1h, b1l, F_IN, HIDDEN, 17*256*32);
    conv_b_kernel<<<(8*128*32 + 255)/256, 256, 0, stream>>>(w2, b2h, b2l, HIDDEN, DIM, 8*128*32);
    conv_b_kernel<<<(4*512*32 + 255)/256, 256, 0, stream>>>(lin[0], b3h, b3l, DIM, NH*DIM, 4*512*32);
    conv_b_kernel<<<(4*512*32 + 255)/256, 256, 0, stream>>>(lin[1], b4h, b4l, DIM, NH*DIM, 4*512*32);

    // ---- CSR build ----
    hipMemsetAsync(cnt_i, 0, N_NODES * sizeof(int), stream);
    hist_kernel<<<(N_EDGES + 255) / 256, 256, 0, stream>>>(dst, cnt_i);
    scan_kernel<<<1, 1024, 0, stream>>>(cnt_i, ptr, ptrc);
    scatter_kernel<<<(N_EDGES + 255) / 256, 256, 0, stream>>>(src, dst, etype, ptrc, src_s, ety_s);

    // ---- node encoder ----
    gemm_mfma_split<<<dim3(HIDDEN / 64, mtiles), 256, 0, stream>>>(
        x, b1h, b1l, b1, hfeat, N_NODES, HIDDEN, F_IN, 1);
    gemm_mfma_split<<<dim3(DIM / 64, mtiles), 256, 0, stream>>>(
        hfeat, b2h, b2l, b2, xbuf, N_NODES, DIM, HIDDEN, 0);

    for (int L = 0; L < 2; ++L) {
        float* outp = (L == 0) ? xbuf : (float*)d_out;
        const unsigned short* bh = (L == 0) ? b3h : b4h;
        const unsigned short* bl = (L == 0) ? b3l : b4l;

        gemm_mfma_split<<<dim3((NH * DIM) / 64, mtiles), 256, 0, stream>>>(
            xbuf, bh, bl, nullptr, hfeat, N_NODES, NH * DIM, DIM, 0);
        as_ad_kernel<<<N_NODES, 256, 0, stream>>>(hfeat, atts[L], attd[L], a_s, a_d);
        rel_table_kernel<<<1, 128, 0, stream>>>(rel_emb, line[L], atte[L], table);
        node_agg_kernel<<<(N_NODES + 3) / 4, 256, 0, stream>>>(
            ptr, src_s, ety_s, a_s, a_d, table, hfeat, bias[L], outp);
    }
}

// Round 6
// 565.511 us; speedup vs baseline: 1.2610x; 1.2610x over previous
//
#include <hip/hip_runtime.h>
#include <math.h>

#define N_NODES 20000
#define MP      20032          // M padded to 64
#define N_EDGES 320000
#define F_IN    518
#define KP_X    544            // F_IN padded to 32
#define HIDDEN  256
#define DIM     128
#define NH      4

typedef __attribute__((ext_vector_type(8))) short bf16x8;
typedef __attribute__((ext_vector_type(4))) float f32x4;
typedef unsigned short ushort_t;

__device__ __forceinline__ float lrelu02(float x) { return x > 0.f ? x : 0.2f * x; }

__device__ __forceinline__ void gl_lds16(const void* g, void* l) {
    __builtin_amdgcn_global_load_lds(
        (const __attribute__((address_space(1))) unsigned int*)g,
        (__attribute__((address_space(3))) unsigned int*)l, 16, 0, 0);
}

__device__ __forceinline__ unsigned int hi16(float v) { return __float_as_uint(v) >> 16; }
__device__ __forceinline__ unsigned int lo16(float v) {
    unsigned int h = __float_as_uint(v) & 0xFFFF0000u;
    return __float_as_uint(v - __uint_as_float(h)) >> 16;
}

// ====== split-bf16 MFMA GEMM, all operands pre-split, k-chunk-major ======
// A layout: [K8][MP][8] bf16 (hi/lo). B layout: [K8][N][8] bf16 (hi/lo).
// Tile 64 rows x 128 cols, 4 waves; wave w computes all 64 rows x cols w*32..+31
// (4x2 mfma_f32_16x16x32_bf16 tiles). C = Ah*Bh + Ah*Bl + Al*Bh.
// LDS 24KB: Ah[0,2048) Al[2048,4096) Bh[4096,8192) Bl[8192,12288) (ushort idx)
// LDS layout q-major: A addr=q*512+row*8, B addr=q*1024+n*8 -> conflict-free b128.
__global__ __launch_bounds__(256, 4) void gemm_mfma_v2(
    const ushort_t* __restrict__ Ah, const ushort_t* __restrict__ Al,
    const ushort_t* __restrict__ Bh, const ushort_t* __restrict__ Bl,
    const float* __restrict__ bias,
    int M, int K8, int N, int act,
    float* __restrict__ Cf, ushort_t* __restrict__ Ch, ushort_t* __restrict__ Cl)
{
    __shared__ __align__(16) ushort_t lds[12288];
    const int tid = threadIdx.x;
    const int w = tid >> 6, lane = tid & 63;
    const int row0 = blockIdx.y * 64, col0 = blockIdx.x * 128;
    const int nkb = K8 >> 2;
    const int m16 = lane & 15, q = lane >> 4;

    f32x4 acc[4][2] = {};

    for (int kb = 0; kb < nkb; ++kb) {
        const size_t kc = (size_t)(kb * 4 + w);          // wave w stages k-chunk q=w
        const size_t aoff = (kc * MP + row0) * 8 + lane * 8;
        const size_t boff = (kc * N + col0) * 8 + lane * 8;
        gl_lds16(Ah + aoff, &lds[w * 512]);
        gl_lds16(Al + aoff, &lds[2048 + w * 512]);
        gl_lds16(Bh + boff,       &lds[4096 + w * 1024]);
        gl_lds16(Bh + boff + 512, &lds[4096 + w * 1024 + 512]);
        gl_lds16(Bl + boff,       &lds[8192 + w * 1024]);
        gl_lds16(Bl + boff + 512, &lds[8192 + w * 1024 + 512]);
        __syncthreads();

        bf16x8 fah[4], fal[4], fbh[2], fbl[2];
        const int fa = q * 512 + m16 * 8;
        #pragma unroll
        for (int mi = 0; mi < 4; ++mi) {
            fah[mi] = *(const bf16x8*)&lds[fa + mi * 128];
            fal[mi] = *(const bf16x8*)&lds[2048 + fa + mi * 128];
        }
        const int fb = q * 1024 + (w * 32 + m16) * 8;
        #pragma unroll
        for (int ni = 0; ni < 2; ++ni) {
            fbh[ni] = *(const bf16x8*)&lds[4096 + fb + ni * 128];
            fbl[ni] = *(const bf16x8*)&lds[8192 + fb + ni * 128];
        }
        #pragma unroll
        for (int mi = 0; mi < 4; ++mi)
            #pragma unroll
            for (int ni = 0; ni < 2; ++ni) {
                acc[mi][ni] = __builtin_amdgcn_mfma_f32_16x16x32_bf16(fah[mi], fbh[ni], acc[mi][ni], 0, 0, 0);
                acc[mi][ni] = __builtin_amdgcn_mfma_f32_16x16x32_bf16(fah[mi], fbl[ni], acc[mi][ni], 0, 0, 0);
                acc[mi][ni] = __builtin_amdgcn_mfma_f32_16x16x32_bf16(fal[mi], fbh[ni], acc[mi][ni], 0, 0, 0);
            }
        __syncthreads();
    }

    // epilogue: C/D row=(lane>>4)*4+reg, col=lane&15
    #pragma unroll
    for (int ni = 0; ni < 2; ++ni) {
        const int col = col0 + w * 32 + ni * 16 + m16;
        const float bb = bias ? bias[col] : 0.f;
        #pragma unroll
        for (int mi = 0; mi < 4; ++mi) {
            #pragma unroll
            for (int r = 0; r < 4; ++r) {
                const int row = row0 + mi * 16 + q * 4 + r;
                if (row < M) {
                    float v = acc[mi][ni][r] + bb;
                    if (act) v = fmaxf(v, 0.f);
                    if (Cf) Cf[(size_t)row * N + col] = v;
                    if (Ch) {
                        const size_t p = (((size_t)(col >> 3)) * MP + row) * 8 + (col & 7);
                        Ch[p] = (ushort_t)hi16(v);
                        Cl[p] = (ushort_t)lo16(v);
                    }
                }
            }
        }
    }
}

// ---- x fp32 [N_NODES][F_IN] -> xh/xl bf16 [K8][MP][8], zero-padded ----
__global__ __launch_bounds__(256) void conv_a_kernel(
    const float* __restrict__ x, ushort_t* __restrict__ xh, ushort_t* __restrict__ xl)
{
    const int row = blockIdx.x * 256 + threadIdx.x;
    const int k8 = blockIdx.y;
    if (row >= MP) return;
    float v[8];
    #pragma unroll
    for (int j = 0; j < 8; ++j) {
        const int k = k8 * 8 + j;
        v[j] = (row < N_NODES && k < F_IN) ? x[(size_t)row * F_IN + k] : 0.f;
    }
    unsigned int hp[4], lp[4];
    #pragma unroll
    for (int i = 0; i < 4; ++i) {
        hp[i] = (hi16(v[2*i+1]) << 16) | hi16(v[2*i]);
        lp[i] = (lo16(v[2*i+1]) << 16) | lo16(v[2*i]);
    }
    const size_t p = ((size_t)k8 * MP + row) * 8;
    *(uint4*)(xh + p) = make_uint4(hp[0], hp[1], hp[2], hp[3]);
    *(uint4*)(xl + p) = make_uint4(lp[0], lp[1], lp[2], lp[3]);
}

// ---- weight w[K][N] fp32 -> bh/bl bf16 [K8][N][8] ----
__global__ __launch_bounds__(256) void conv_b_kernel(
    const float* __restrict__ w, ushort_t* __restrict__ bh, ushort_t* __restrict__ bl,
    int K, int N, int total)
{
    const int idx = blockIdx.x * 256 + threadIdx.x;
    if (idx >= total) return;
    const int j = idx & 7;
    const int rem = idx >> 3;        // k8*N + n
    const int n = rem % N;
    const int k = (rem / N) * 8 + j;
    const float v = (k < K) ? w[(size_t)k * N + n] : 0.f;
    bh[idx] = (ushort_t)hi16(v);
    bl[idx] = (ushort_t)lo16(v);
}

// ---- wa_s/wa_d [H][D]: folded lin @ att (a_s = xbuf @ wa_s^T per head) ----
__global__ __launch_bounds__(256) void wa_kernel(
    const float* __restrict__ lin, const float* __restrict__ atts,
    const float* __restrict__ attd, float* __restrict__ wa_s, float* __restrict__ wa_d)
{
    const int wrk = blockIdx.x * 256 + threadIdx.x;   // grid 4 -> 1024 items
    if (wrk >= 1024) return;
    const int sd = wrk >> 9;
    const int p = wrk & 511;
    const int h = p >> 7, d = p & 127;
    const float* av = (sd ? attd : atts) + h * DIM;
    const float* lp = lin + (size_t)d * (NH * DIM) + h * DIM;
    float acc = 0.f;
    #pragma unroll 8
    for (int i = 0; i < DIM; ++i) acc += lp[i] * av[i];
    (sd ? wa_d : wa_s)[h * DIM + d] = acc;
}

// ---- a_s[n,h], a_d[n,h] from xbuf (fp32 [N][128]) ----
__global__ __launch_bounds__(256) void as_ad_kernel(
    const float* __restrict__ xb, const float* __restrict__ wa_s,
    const float* __restrict__ wa_d, float* __restrict__ a_s, float* __restrict__ a_d)
{
    const int gw = blockIdx.x * 4 + (threadIdx.x >> 6);
    const int lane = threadIdx.x & 63;
    if (gw >= N_NODES * NH) return;
    const int n = gw >> 2, h = gw & 3;
    const float* hp = xb + (size_t)n * DIM;
    float2 hv = *(const float2*)(hp + lane * 2);
    float2 sv = *(const float2*)(wa_s + h * DIM + lane * 2);
    float2 dv = *(const float2*)(wa_d + h * DIM + lane * 2);
    float s = hv.x * sv.x + hv.y * sv.y;
    float d = hv.x * dv.x + hv.y * dv.y;
    #pragma unroll
    for (int off = 32; off > 0; off >>= 1) {
        s += __shfl_down(s, off);
        d += __shfl_down(d, off);
    }
    if (lane == 0) { a_s[n * 4 + h] = s; a_d[n * 4 + h] = d; }
}

// ---- rel attention table[r,h] ----
__global__ __launch_bounds__(128) void rel_table_kernel(
    const float* __restrict__ rel_emb, const float* __restrict__ line,
    const float* __restrict__ atte, float* __restrict__ table)
{
    __shared__ float we[32][NH];
    const int tid = threadIdx.x;
    const int k = tid >> 2, h = tid & 3;
    float acc = 0.f;
    for (int d = 0; d < DIM; ++d)
        acc += line[(size_t)k * (NH * DIM) + h * DIM + d] * atte[h * DIM + d];
    we[k][h] = acc;
    __syncthreads();
    if (tid < 26 * NH) {
        int r = tid >> 2, hh = tid & 3;
        float t = 0.f;
        for (int kk = 0; kk < 32; ++kk) t += rel_emb[r * 32 + kk] * we[kk][hh];
        table[r * 4 + hh] = t;
    }
}

// ================= CSR build =================
__global__ __launch_bounds__(256) void hist_kernel(
    const int* __restrict__ dst, int* __restrict__ cnt)
{
    const int e = blockIdx.x * blockDim.x + threadIdx.x;
    if (e >= N_EDGES) return;
    atomicAdd(&cnt[dst[e]], 1);
}

__global__ __launch_bounds__(1024) void scan_kernel(
    const int* __restrict__ cnt, int* __restrict__ ptr, int* __restrict__ ptr_copy)
{
    __shared__ int tsum[1024];
    const int tid = threadIdx.x;
    const int CH = 20;
    const int base = tid * CH;
    int s = 0;
    #pragma unroll
    for (int i = 0; i < CH; ++i) {
        int idx = base + i;
        if (idx < N_NODES) s += cnt[idx];
    }
    tsum[tid] = s;
    __syncthreads();
    for (int off = 1; off < 1024; off <<= 1) {
        int v = (tid >= off) ? tsum[tid - off] : 0;
        __syncthreads();
        tsum[tid] += v;
        __syncthreads();
    }
    int run = (tid == 0) ? 0 : tsum[tid - 1];
    #pragma unroll
    for (int i = 0; i < CH; ++i) {
        int idx = base + i;
        if (idx < N_NODES) {
            ptr[idx] = run;
            ptr_copy[idx] = run;
            run += cnt[idx];
        }
    }
    if (tid == 0) ptr[N_NODES] = N_EDGES;
}

__global__ __launch_bounds__(256) void scatter_kernel(
    const int* __restrict__ src, const int* __restrict__ dst, const int* __restrict__ etype,
    int* __restrict__ ptr_copy, int2* __restrict__ se)
{
    const int e = blockIdx.x * blockDim.x + threadIdx.x;
    if (e >= N_EDGES) return;
    const int d = dst[e];
    const int pos = atomicAdd(&ptr_copy[d], 1);
    se[pos] = make_int2(src[e], etype[e]);
}

// ===== fused per-node GAT aggregate; edge-unrolled x2; optional bf16 out =====
__global__ __launch_bounds__(256) void node_agg_kernel(
    const int* __restrict__ ptr, const int2* __restrict__ se,
    const float* __restrict__ a_s, const float* __restrict__ a_d,
    const float* __restrict__ table, const float* __restrict__ hfeat,
    const float* __restrict__ bias,
    float* __restrict__ outf, ushort_t* __restrict__ oh, ushort_t* __restrict__ ol)
{
    const int n = blockIdx.x * 4 + (threadIdx.x >> 6);
    const int lane = threadIdx.x & 63;
    if (n >= N_NODES) return;
    const int beg = ptr[n], end = ptr[n + 1];
    const bool lo_half = lane < 32;
    const int coff = lane * 4;

    const float4 ad4 = *(const float4*)(a_d + n * 4);
    float4 accA = {0,0,0,0}, accB = {0,0,0,0};
    float d0 = 0, d1 = 0, d2 = 0, d3 = 0;
    float e0 = 0, e1 = 0, e2 = 0, e3 = 0;

    int j = beg;
    for (; j + 2 <= end; j += 2) {
        const int2 E0 = se[j], E1 = se[j + 1];
        const float4 as0 = *(const float4*)(a_s + E0.x * 4);
        const float4 tv0 = *(const float4*)(table + E0.y * 4);
        const float4 as1 = *(const float4*)(a_s + E1.x * 4);
        const float4 tv1 = *(const float4*)(table + E1.y * 4);
        const float* h0 = hfeat + (size_t)E0.x * (NH * DIM);
        const float* h1 = hfeat + (size_t)E1.x * (NH * DIM);
        const float4 vA0 = *(const float4*)(h0 + coff);
        const float4 vB0 = *(const float4*)(h0 + 256 + coff);
        const float4 vA1 = *(const float4*)(h1 + coff);
        const float4 vB1 = *(const float4*)(h1 + 256 + coff);
        const float p00 = __expf(lrelu02(as0.x + ad4.x + tv0.x));
        const float p01 = __expf(lrelu02(as0.y + ad4.y + tv0.y));
        const float p02 = __expf(lrelu02(as0.z + ad4.z + tv0.z));
        const float p03 = __expf(lrelu02(as0.w + ad4.w + tv0.w));
        const float p10 = __expf(lrelu02(as1.x + ad4.x + tv1.x));
        const float p11 = __expf(lrelu02(as1.y + ad4.y + tv1.y));
        const float p12 = __expf(lrelu02(as1.z + ad4.z + tv1.z));
        const float p13 = __expf(lrelu02(as1.w + ad4.w + tv1.w));
        e0 += tv0.x + tv1.x; e1 += tv0.y + tv1.y;
        e2 += tv0.z + tv1.z; e3 += tv0.w + tv1.w;
        d0 += p00 + p10; d1 += p01 + p11; d2 += p02 + p12; d3 += p03 + p13;
        const float wA0 = lo_half ? p00 : p01, wB0 = lo_half ? p02 : p03;
        const float wA1 = lo_half ? p10 : p11, wB1 = lo_half ? p12 : p13;
        accA.x += wA0 * vA0.x + wA1 * vA1.x;
        accA.y += wA0 * vA0.y + wA1 * vA1.y;
        accA.z += wA0 * vA0.z + wA1 * vA1.z;
        accA.w += wA0 * vA0.w + wA1 * vA1.w;
        accB.x += wB0 * vB0.x + wB1 * vB1.x;
        accB.y += wB0 * vB0.y + wB1 * vB1.y;
        accB.z += wB0 * vB0.z + wB1 * vB1.z;
        accB.w += wB0 * vB0.w + wB1 * vB1.w;
    }
    if (j < end) {
        const int2 E0 = se[j];
        const float4 as0 = *(const float4*)(a_s + E0.x * 4);
        const float4 tv0 = *(const float4*)(table + E0.y * 4);
        const float* h0 = hfeat + (size_t)E0.x * (NH * DIM);
        const float4 vA0 = *(const float4*)(h0 + coff);
        const float4 vB0 = *(const float4*)(h0 + 256 + coff);
        const float p00 = __expf(lrelu02(as0.x + ad4.x + tv0.x));
        const float p01 = __expf(lrelu02(as0.y + ad4.y + tv0.y));
        const float p02 = __expf(lrelu02(as0.z + ad4.z + tv0.z));
        const float p03 = __expf(lrelu02(as0.w + ad4.w + tv0.w));
        e0 += tv0.x; e1 += tv0.y; e2 += tv0.z; e3 += tv0.w;
        d0 += p00; d1 += p01; d2 += p02; d3 += p03;
        const float wA0 = lo_half ? p00 : p01, wB0 = lo_half ? p02 : p03;
        accA.x += wA0 * vA0.x; accA.y += wA0 * vA0.y;
        accA.z += wA0 * vA0.z; accA.w += wA0 * vA0.w;
        accB.x += wB0 * vB0.x; accB.y += wB0 * vB0.y;
        accB.z += wB0 * vB0.z; accB.w += wB0 * vB0.w;
    }

    // self-loop (fill_value='mean')
    const float inv = 1.0f / fmaxf((float)(end - beg), 1.0f);
    const float4 asn = *(const float4*)(a_s + n * 4);
    {
        const float p0 = __expf(lrelu02(asn.x + ad4.x + e0 * inv));
        const float p1 = __expf(lrelu02(asn.y + ad4.y + e1 * inv));
        const float p2 = __expf(lrelu02(asn.z + ad4.z + e2 * inv));
        const float p3 = __expf(lrelu02(asn.w + ad4.w + e3 * inv));
        d0 += p0; d1 += p1; d2 += p2; d3 += p3;
        const float* hp = hfeat + (size_t)n * (NH * DIM);
        const float4 vA = *(const float4*)(hp + coff);
        const float4 vB = *(const float4*)(hp + 256 + coff);
        const float wA = lo_half ? p0 : p1, wB = lo_half ? p2 : p3;
        accA.x += wA * vA.x; accA.y += wA * vA.y; accA.z += wA * vA.z; accA.w += wA * vA.w;
        accB.x += wB * vB.x; accB.y += wB * vB.y; accB.z += wB * vB.z; accB.w += wB * vB.w;
    }

    const float iA = 0.25f / ((lo_half ? d0 : d1) + 1e-16f);
    const float iB = 0.25f / ((lo_half ? d2 : d3) + 1e-16f);
    float4 tmp;
    tmp.x = accA.x * iA + accB.x * iB;
    tmp.y = accA.y * iA + accB.y * iB;
    tmp.z = accA.z * iA + accB.z * iB;
    tmp.w = accA.w * iA + accB.w * iB;
    tmp.x += __shfl_xor(tmp.x, 32);
    tmp.y += __shfl_xor(tmp.y, 32);
    tmp.z += __shfl_xor(tmp.z, 32);
    tmp.w += __shfl_xor(tmp.w, 32);
    if (lo_half) {
        const float4 b = *(const float4*)(bias + coff);
        float4 o;
        o.x = fmaxf(tmp.x + b.x, 0.f);
        o.y = fmaxf(tmp.y + b.y, 0.f);
        o.z = fmaxf(tmp.z + b.z, 0.f);
        o.w = fmaxf(tmp.w + b.w, 0.f);
        if (outf) *(float4*)(outf + (size_t)n * DIM + coff) = o;
        if (oh) {
            const float ov[4] = {o.x, o.y, o.z, o.w};
            #pragma unroll
            for (int i = 0; i < 4; ++i) {
                const int c = coff + i;
                const size_t p = (((size_t)(c >> 3)) * MP + n) * 8 + (c & 7);
                oh[p] = (ushort_t)hi16(ov[i]);
                ol[p] = (ushort_t)lo16(ov[i]);
            }
        }
    }
}

extern "C" void kernel_launch(void* const* d_in, const int* in_sizes, int n_in,
                              void* d_out, int out_size, void* d_ws, size_t ws_size,
                              hipStream_t stream)
{
    const float* x       = (const float*)d_in[0];
    const int*   eidx    = (const int*)d_in[1];
    const int*   etype   = (const int*)d_in[2];
    const float* w1      = (const float*)d_in[3];
    const float* b1      = (const float*)d_in[4];
    const float* w2      = (const float*)d_in[5];
    const float* b2      = (const float*)d_in[6];
    const float* rel_emb = (const float*)d_in[7];
    const float* lin[2]  = {(const float*)d_in[8],  (const float*)d_in[14]};
    const float* line[2] = {(const float*)d_in[9],  (const float*)d_in[15]};
    const float* atts[2] = {(const float*)d_in[10], (const float*)d_in[16]};
    const float* attd[2] = {(const float*)d_in[11], (const float*)d_in[17]};
    const float* atte[2] = {(const float*)d_in[12], (const float*)d_in[18]};
    const float* bias[2] = {(const float*)d_in[13], (const float*)d_in[19]};
    const int* src = eidx;
    const int* dst = eidx + N_EDGES;

    // ---- workspace layout (bump allocator, 256B aligned) ----
    char* base = (char*)d_ws;
    size_t off = 0;
    auto alloc = [&](size_t bytes) -> void* {
        void* p = base + off;
        off = (off + bytes + 255) & ~(size_t)255;
        return p;
    };
    ushort_t* xh  = (ushort_t*)alloc((size_t)68 * MP * 8 * 2);  // also hfeat overlay
    ushort_t* xl  = (ushort_t*)alloc((size_t)68 * MP * 8 * 2);
    ushort_t* h1h = (ushort_t*)alloc((size_t)32 * MP * 8 * 2);  // also xbuf1 overlay
    ushort_t* h1l = (ushort_t*)alloc((size_t)32 * MP * 8 * 2);
    ushort_t* x0h = (ushort_t*)alloc((size_t)16 * MP * 8 * 2);
    ushort_t* x0l = (ushort_t*)alloc((size_t)16 * MP * 8 * 2);
    void* reg1    = alloc((size_t)16 * MP * 8 * 2 * 2);         // xbuf0 fp32 | x1h+x1l
    ushort_t* w1h = (ushort_t*)alloc(68 * 256 * 8 * 2);
    ushort_t* w1l = (ushort_t*)alloc(68 * 256 * 8 * 2);
    ushort_t* w2h = (ushort_t*)alloc(32 * 128 * 8 * 2);
    ushort_t* w2l = (ushort_t*)alloc(32 * 128 * 8 * 2);
    ushort_t* l0h = (ushort_t*)alloc(16 * 512 * 8 * 2);
    ushort_t* l0l = (ushort_t*)alloc(16 * 512 * 8 * 2);
    ushort_t* l1h = (ushort_t*)alloc(16 * 512 * 8 * 2);
    ushort_t* l1l = (ushort_t*)alloc(16 * 512 * 8 * 2);
    float* a_s   = (float*)alloc(N_NODES * 4 * 4);
    float* a_d   = (float*)alloc(N_NODES * 4 * 4);
    float* table = (float*)alloc(128 * 4);
    float* wa_s  = (float*)alloc(512 * 4);
    float* wa_d  = (float*)alloc(512 * 4);
    int*  cnt_i  = (int*)alloc(N_NODES * 4);
    int*  ptr    = (int*)alloc((N_NODES + 4) * 4);
    int*  ptrc   = (int*)alloc(N_NODES * 4);
    int2* se     = (int2*)alloc((size_t)N_EDGES * 8);

    float* hfeat = (float*)xh;      // 41 MB, spans xh+xl (dead after enc1)
    float* xbuf1 = (float*)h1h;     // written by node_agg L0 (h1 dead after enc2)
    float* xbuf0 = (float*)reg1;    // written by enc2, dead after as_ad L0
    ushort_t* x1h = (ushort_t*)reg1;         // written by node_agg L0 (after as_ad L0)
    ushort_t* x1l = x1h + (size_t)16 * MP * 8;

    const int mtiles = MP / 64;     // 313

    // ---- input conversions ----
    conv_a_kernel<<<dim3((MP + 255) / 256, 68), 256, 0, stream>>>(x, xh, xl);
    conv_b_kernel<<<(68*256*8 + 255) / 256, 256, 0, stream>>>(w1, w1h, w1l, F_IN, HIDDEN, 68*256*8);
    conv_b_kernel<<<(32*128*8 + 255) / 256, 256, 0, stream>>>(w2, w2h, w2l, HIDDEN, DIM, 32*128*8);
    conv_b_kernel<<<(16*512*8 + 255) / 256, 256, 0, stream>>>(lin[0], l0h, l0l, DIM, NH*DIM, 16*512*8);
    conv_b_kernel<<<(16*512*8 + 255) / 256, 256, 0, stream>>>(lin[1], l1h, l1l, DIM, NH*DIM, 16*512*8);

    // ---- CSR build ----
    hipMemsetAsync(cnt_i, 0, N_NODES * sizeof(int), stream);
    hist_kernel<<<(N_EDGES + 255) / 256, 256, 0, stream>>>(dst, cnt_i);
    scan_kernel<<<1, 1024, 0, stream>>>(cnt_i, ptr, ptrc);
    scatter_kernel<<<(N_EDGES + 255) / 256, 256, 0, stream>>>(src, dst, etype, ptrc, se);

    // ---- node encoder ----
    // enc1: h1 = relu(x@w1+b1), bf16 out only
    gemm_mfma_v2<<<dim3(HIDDEN / 128, mtiles), 256, 0, stream>>>(
        xh, xl, w1h, w1l, b1, N_NODES, 68, HIDDEN, 1, nullptr, h1h, h1l);
    // enc2: x0 = h1@w2+b2, fp32 (for as_ad) + bf16 (for L0 gemm)
    gemm_mfma_v2<<<dim3(DIM / 128, mtiles), 256, 0, stream>>>(
        h1h, h1l, w2h, w2l, b2, N_NODES, 32, DIM, 0, xbuf0, x0h, x0l);

    // ---- layer 0 ----
    gemm_mfma_v2<<<dim3((NH * DIM) / 128, mtiles), 256, 0, stream>>>(
        x0h, x0l, l0h, l0l, nullptr, N_NODES, 16, NH * DIM, 0, hfeat, nullptr, nullptr);
    wa_kernel<<<4, 256, 0, stream>>>(lin[0], atts[0], attd[0], wa_s, wa_d);
    as_ad_kernel<<<N_NODES, 256, 0, stream>>>(xbuf0, wa_s, wa_d, a_s, a_d);
    rel_table_kernel<<<1, 128, 0, stream>>>(rel_emb, line[0], atte[0], table);
    node_agg_kernel<<<(N_NODES + 3) / 4, 256, 0, stream>>>(
        ptr, se, a_s, a_d, table, hfeat, bias[0], xbuf1, x1h, x1l);

    // ---- layer 1 ----
    gemm_mfma_v2<<<dim3((NH * DIM) / 128, mtiles), 256, 0, stream>>>(
        x1h, x1l, l1h, l1l, nullptr, N_NODES, 16, NH * DIM, 0, hfeat, nullptr, nullptr);
    wa_kernel<<<4, 256, 0, stream>>>(lin[1], atts[1], attd[1], wa_s, wa_d);
    as_ad_kernel<<<N_NODES, 256, 0, stream>>>(xbuf1, wa_s, wa_d, a_s, a_d);
    rel_table_kernel<<<1, 128, 0, stream>>>(rel_emb, line[1], atte[1], table);
    node_agg_kernel<<<(N_NODES + 3) / 4, 256, 0, stream>>>(
        ptr, se, a_s, a_d, table, hfeat, bias[1], (float*)d_out, nullptr, nullptr);
}

// Round 7
// 495.495 us; speedup vs baseline: 1.4392x; 1.1413x over previous
//
#include <hip/hip_runtime.h>
#include <math.h>

#define N_NODES 20000
#define MP      20032          // M padded to 64
#define N_EDGES 320000
#define F_IN    518
#define HIDDEN  256
#define DIM     128
#define NH      4

typedef __attribute__((ext_vector_type(8))) short bf16x8;
typedef __attribute__((ext_vector_type(4))) float f32x4;
typedef unsigned short ushort_t;

__device__ __forceinline__ float lrelu02(float x) { return x > 0.f ? x : 0.2f * x; }

__device__ __forceinline__ void gl_lds16(const void* g, void* l) {
    __builtin_amdgcn_global_load_lds(
        (const __attribute__((address_space(1))) unsigned int*)g,
        (__attribute__((address_space(3))) unsigned int*)l, 16, 0, 0);
}

__device__ __forceinline__ unsigned int hi16(float v) { return __float_as_uint(v) >> 16; }
__device__ __forceinline__ unsigned int lo16(float v) {
    unsigned int h = __float_as_uint(v) & 0xFFFF0000u;
    return __float_as_uint(v - __uint_as_float(h)) >> 16;
}
// round-to-nearest-even bf16
__device__ __forceinline__ unsigned int rnd16(float v) {
    unsigned int u = __float_as_uint(v);
    return (u + 0x7FFFu + ((u >> 16) & 1u)) >> 16;
}
__device__ __forceinline__ float bfl(unsigned int u) { return __uint_as_float(u << 16); }
__device__ __forceinline__ float bfh(unsigned int u) { return __uint_as_float(u & 0xFFFF0000u); }

// ====== split-bf16 MFMA GEMM, all operands pre-split, k-chunk-major ======
// A: [K8][MP][8] bf16 hi/lo. B: [K8][N][8] bf16 hi/lo. C = Ah*Bh + Ah*Bl + Al*Bh.
// Tile 64x128, 4 waves; LDS 24KB; conflict-free ds_read_b128; global_load_lds x16.
__global__ __launch_bounds__(256, 4) void gemm_mfma_v2(
    const ushort_t* __restrict__ Ah, const ushort_t* __restrict__ Al,
    const ushort_t* __restrict__ Bh, const ushort_t* __restrict__ Bl,
    const float* __restrict__ bias,
    int M, int K8, int N, int act,
    float* __restrict__ Cf, ushort_t* __restrict__ Ch, ushort_t* __restrict__ Cl,
    ushort_t* __restrict__ Cb)   // plain bf16 [M][N], rounded
{
    __shared__ __align__(16) ushort_t lds[12288];
    const int tid = threadIdx.x;
    const int w = tid >> 6, lane = tid & 63;
    const int row0 = blockIdx.y * 64, col0 = blockIdx.x * 128;
    const int nkb = K8 >> 2;
    const int m16 = lane & 15, q = lane >> 4;

    f32x4 acc[4][2] = {};

    for (int kb = 0; kb < nkb; ++kb) {
        const size_t kc = (size_t)(kb * 4 + w);
        const size_t aoff = (kc * MP + row0) * 8 + lane * 8;
        const size_t boff = (kc * N + col0) * 8 + lane * 8;
        gl_lds16(Ah + aoff, &lds[w * 512]);
        gl_lds16(Al + aoff, &lds[2048 + w * 512]);
        gl_lds16(Bh + boff,       &lds[4096 + w * 1024]);
        gl_lds16(Bh + boff + 512, &lds[4096 + w * 1024 + 512]);
        gl_lds16(Bl + boff,       &lds[8192 + w * 1024]);
        gl_lds16(Bl + boff + 512, &lds[8192 + w * 1024 + 512]);
        __syncthreads();

        bf16x8 fah[4], fal[4], fbh[2], fbl[2];
        const int fa = q * 512 + m16 * 8;
        #pragma unroll
        for (int mi = 0; mi < 4; ++mi) {
            fah[mi] = *(const bf16x8*)&lds[fa + mi * 128];
            fal[mi] = *(const bf16x8*)&lds[2048 + fa + mi * 128];
        }
        const int fb = q * 1024 + (w * 32 + m16) * 8;
        #pragma unroll
        for (int ni = 0; ni < 2; ++ni) {
            fbh[ni] = *(const bf16x8*)&lds[4096 + fb + ni * 128];
            fbl[ni] = *(const bf16x8*)&lds[8192 + fb + ni * 128];
        }
        #pragma unroll
        for (int mi = 0; mi < 4; ++mi)
            #pragma unroll
            for (int ni = 0; ni < 2; ++ni) {
                acc[mi][ni] = __builtin_amdgcn_mfma_f32_16x16x32_bf16(fah[mi], fbh[ni], acc[mi][ni], 0, 0, 0);
                acc[mi][ni] = __builtin_amdgcn_mfma_f32_16x16x32_bf16(fah[mi], fbl[ni], acc[mi][ni], 0, 0, 0);
                acc[mi][ni] = __builtin_amdgcn_mfma_f32_16x16x32_bf16(fal[mi], fbh[ni], acc[mi][ni], 0, 0, 0);
            }
        __syncthreads();
    }

    // epilogue: C/D row=(lane>>4)*4+reg, col=lane&15
    #pragma unroll
    for (int ni = 0; ni < 2; ++ni) {
        const int col = col0 + w * 32 + ni * 16 + m16;
        const float bb = bias ? bias[col] : 0.f;
        #pragma unroll
        for (int mi = 0; mi < 4; ++mi) {
            #pragma unroll
            for (int r = 0; r < 4; ++r) {
                const int row = row0 + mi * 16 + q * 4 + r;
                if (row < M) {
                    float v = acc[mi][ni][r] + bb;
                    if (act) v = fmaxf(v, 0.f);
                    if (Cf) Cf[(size_t)row * N + col] = v;
                    if (Cb) Cb[(size_t)row * N + col] = (ushort_t)rnd16(v);
                    if (Ch) {
                        const size_t p = (((size_t)(col >> 3)) * MP + row) * 8 + (col & 7);
                        Ch[p] = (ushort_t)hi16(v);
                        Cl[p] = (ushort_t)lo16(v);
                    }
                }
            }
        }
    }
}

// ---- x fp32 [N_NODES][F_IN] -> xh/xl bf16 [K8][MP][8], zero-padded ----
__global__ __launch_bounds__(256) void conv_a_kernel(
    const float* __restrict__ x, ushort_t* __restrict__ xh, ushort_t* __restrict__ xl)
{
    const int row = blockIdx.x * 256 + threadIdx.x;
    const int k8 = blockIdx.y;
    if (row >= MP) return;
    float v[8];
    #pragma unroll
    for (int j = 0; j < 8; ++j) {
        const int k = k8 * 8 + j;
        v[j] = (row < N_NODES && k < F_IN) ? x[(size_t)row * F_IN + k] : 0.f;
    }
    unsigned int hp[4], lp[4];
    #pragma unroll
    for (int i = 0; i < 4; ++i) {
        hp[i] = (hi16(v[2*i+1]) << 16) | hi16(v[2*i]);
        lp[i] = (lo16(v[2*i+1]) << 16) | lo16(v[2*i]);
    }
    const size_t p = ((size_t)k8 * MP + row) * 8;
    *(uint4*)(xh + p) = make_uint4(hp[0], hp[1], hp[2], hp[3]);
    *(uint4*)(xl + p) = make_uint4(lp[0], lp[1], lp[2], lp[3]);
}

// ---- weight w[K][N] fp32 -> bh/bl bf16 [K8][N][8] ----
__global__ __launch_bounds__(256) void conv_b_kernel(
    const float* __restrict__ w, ushort_t* __restrict__ bh, ushort_t* __restrict__ bl,
    int K, int N, int total)
{
    const int idx = blockIdx.x * 256 + threadIdx.x;
    if (idx >= total) return;
    const int j = idx & 7;
    const int rem = idx >> 3;
    const int n = rem % N;
    const int k = (rem / N) * 8 + j;
    const float v = (k < K) ? w[(size_t)k * N + n] : 0.f;
    bh[idx] = (ushort_t)hi16(v);
    bl[idx] = (ushort_t)lo16(v);
}

// ---- wa_s/wa_d [H][D]: folded lin @ att ----
__global__ __launch_bounds__(256) void wa_kernel(
    const float* __restrict__ lin, const float* __restrict__ atts,
    const float* __restrict__ attd, float* __restrict__ wa_s, float* __restrict__ wa_d)
{
    const int wrk = blockIdx.x * 256 + threadIdx.x;
    if (wrk >= 1024) return;
    const int sd = wrk >> 9;
    const int p = wrk & 511;
    const int h = p >> 7, d = p & 127;
    const float* av = (sd ? attd : atts) + h * DIM;
    const float* lp = lin + (size_t)d * (NH * DIM) + h * DIM;
    float acc = 0.f;
    #pragma unroll 8
    for (int i = 0; i < DIM; ++i) acc += lp[i] * av[i];
    (sd ? wa_d : wa_s)[h * DIM + d] = acc;
}

// ---- a_s[n,h], a_d[n,h] from xbuf (fp32 [N][128]) ----
__global__ __launch_bounds__(256) void as_ad_kernel(
    const float* __restrict__ xb, const float* __restrict__ wa_s,
    const float* __restrict__ wa_d, float* __restrict__ a_s, float* __restrict__ a_d)
{
    const int gw = blockIdx.x * 4 + (threadIdx.x >> 6);
    const int lane = threadIdx.x & 63;
    if (gw >= N_NODES * NH) return;
    const int n = gw >> 2, h = gw & 3;
    const float* hp = xb + (size_t)n * DIM;
    float2 hv = *(const float2*)(hp + lane * 2);
    float2 sv = *(const float2*)(wa_s + h * DIM + lane * 2);
    float2 dv = *(const float2*)(wa_d + h * DIM + lane * 2);
    float s = hv.x * sv.x + hv.y * sv.y;
    float d = hv.x * dv.x + hv.y * dv.y;
    #pragma unroll
    for (int off = 32; off > 0; off >>= 1) {
        s += __shfl_down(s, off);
        d += __shfl_down(d, off);
    }
    if (lane == 0) { a_s[n * 4 + h] = s; a_d[n * 4 + h] = d; }
}

// ---- rel attention table[r,h] ----
__global__ __launch_bounds__(128) void rel_table_kernel(
    const float* __restrict__ rel_emb, const float* __restrict__ line,
    const float* __restrict__ atte, float* __restrict__ table)
{
    __shared__ float we[32][NH];
    const int tid = threadIdx.x;
    const int k = tid >> 2, h = tid & 3;
    float acc = 0.f;
    for (int d = 0; d < DIM; ++d)
        acc += line[(size_t)k * (NH * DIM) + h * DIM + d] * atte[h * DIM + d];
    we[k][h] = acc;
    __syncthreads();
    if (tid < 26 * NH) {
        int r = tid >> 2, hh = tid & 3;
        float t = 0.f;
        for (int kk = 0; kk < 32; ++kk) t += rel_emb[r * 32 + kk] * we[kk][hh];
        table[r * 4 + hh] = t;
    }
}

// ================= CSR build =================
__global__ __launch_bounds__(256) void hist_kernel(
    const int* __restrict__ dst, int* __restrict__ cnt)
{
    const int e = blockIdx.x * blockDim.x + threadIdx.x;
    if (e >= N_EDGES) return;
    atomicAdd(&cnt[dst[e]], 1);
}

__global__ __launch_bounds__(1024) void scan_kernel(
    const int* __restrict__ cnt, int* __restrict__ ptr, int* __restrict__ ptr_copy)
{
    __shared__ int tsum[1024];
    const int tid = threadIdx.x;
    const int CH = 20;
    const int base = tid * CH;
    int s = 0;
    #pragma unroll
    for (int i = 0; i < CH; ++i) {
        int idx = base + i;
        if (idx < N_NODES) s += cnt[idx];
    }
    tsum[tid] = s;
    __syncthreads();
    for (int off = 1; off < 1024; off <<= 1) {
        int v = (tid >= off) ? tsum[tid - off] : 0;
        __syncthreads();
        tsum[tid] += v;
        __syncthreads();
    }
    int run = (tid == 0) ? 0 : tsum[tid - 1];
    #pragma unroll
    for (int i = 0; i < CH; ++i) {
        int idx = base + i;
        if (idx < N_NODES) {
            ptr[idx] = run;
            ptr_copy[idx] = run;
            run += cnt[idx];
        }
    }
    if (tid == 0) ptr[N_NODES] = N_EDGES;
}

__global__ __launch_bounds__(256) void scatter_kernel(
    const int* __restrict__ src, const int* __restrict__ dst, const int* __restrict__ etype,
    int* __restrict__ ptr_copy, int2* __restrict__ se)
{
    const int e = blockIdx.x * blockDim.x + threadIdx.x;
    if (e >= N_EDGES) return;
    const int d = dst[e];
    const int pos = atomicAdd(&ptr_copy[d], 1);
    se[pos] = make_int2(src[e], etype[e]);
}

// ===== fused per-node GAT aggregate over bf16 hfeat (1 KB/edge gather) =====
// hb: bf16 [n][512] (head-major row). Lane l covers cols l*8..l*8+7, head=l>>4.
// Head-mean reduction via shfl_xor(16,32); lanes 0-15 write 128 cols.
__global__ __launch_bounds__(256) void node_agg_kernel(
    const int* __restrict__ ptr, const int2* __restrict__ se,
    const float* __restrict__ a_s, const float* __restrict__ a_d,
    const float* __restrict__ table, const ushort_t* __restrict__ hb,
    const float* __restrict__ bias,
    float* __restrict__ outf, ushort_t* __restrict__ oh, ushort_t* __restrict__ ol)
{
    const int n = blockIdx.x * 4 + (threadIdx.x >> 6);
    const int lane = threadIdx.x & 63;
    if (n >= N_NODES) return;
    const int beg = ptr[n], end = ptr[n + 1];
    const int head = lane >> 4;
    const int cbase = lane * 8;

    const float4 ad4 = *(const float4*)(a_d + n * 4);
    float acc[8] = {};
    float d0 = 0, d1 = 0, d2 = 0, d3 = 0;
    float e0 = 0, e1 = 0, e2 = 0, e3 = 0;

    int j = beg;
    for (; j + 2 <= end; j += 2) {
        const int2 E0 = se[j], E1 = se[j + 1];
        const uint4 g0 = *(const uint4*)(hb + (size_t)E0.x * 512 + cbase);
        const uint4 g1 = *(const uint4*)(hb + (size_t)E1.x * 512 + cbase);
        const float4 as0 = *(const float4*)(a_s + E0.x * 4);
        const float4 tv0 = *(const float4*)(table + E0.y * 4);
        const float4 as1 = *(const float4*)(a_s + E1.x * 4);
        const float4 tv1 = *(const float4*)(table + E1.y * 4);
        const float p00 = __expf(lrelu02(as0.x + ad4.x + tv0.x));
        const float p01 = __expf(lrelu02(as0.y + ad4.y + tv0.y));
        const float p02 = __expf(lrelu02(as0.z + ad4.z + tv0.z));
        const float p03 = __expf(lrelu02(as0.w + ad4.w + tv0.w));
        const float p10 = __expf(lrelu02(as1.x + ad4.x + tv1.x));
        const float p11 = __expf(lrelu02(as1.y + ad4.y + tv1.y));
        const float p12 = __expf(lrelu02(as1.z + ad4.z + tv1.z));
        const float p13 = __expf(lrelu02(as1.w + ad4.w + tv1.w));
        e0 += tv0.x + tv1.x; e1 += tv0.y + tv1.y;
        e2 += tv0.z + tv1.z; e3 += tv0.w + tv1.w;
        d0 += p00 + p10; d1 += p01 + p11; d2 += p02 + p12; d3 += p03 + p13;
        const float w0 = head < 2 ? (head == 0 ? p00 : p01) : (head == 2 ? p02 : p03);
        const float w1 = head < 2 ? (head == 0 ? p10 : p11) : (head == 2 ? p12 : p13);
        acc[0] += w0 * bfl(g0.x) + w1 * bfl(g1.x);
        acc[1] += w0 * bfh(g0.x) + w1 * bfh(g1.x);
        acc[2] += w0 * bfl(g0.y) + w1 * bfl(g1.y);
        acc[3] += w0 * bfh(g0.y) + w1 * bfh(g1.y);
        acc[4] += w0 * bfl(g0.z) + w1 * bfl(g1.z);
        acc[5] += w0 * bfh(g0.z) + w1 * bfh(g1.z);
        acc[6] += w0 * bfl(g0.w) + w1 * bfl(g1.w);
        acc[7] += w0 * bfh(g0.w) + w1 * bfh(g1.w);
    }
    if (j < end) {
        const int2 E0 = se[j];
        const uint4 g0 = *(const uint4*)(hb + (size_t)E0.x * 512 + cbase);
        const float4 as0 = *(const float4*)(a_s + E0.x * 4);
        const float4 tv0 = *(const float4*)(table + E0.y * 4);
        const float p00 = __expf(lrelu02(as0.x + ad4.x + tv0.x));
        const float p01 = __expf(lrelu02(as0.y + ad4.y + tv0.y));
        const float p02 = __expf(lrelu02(as0.z + ad4.z + tv0.z));
        const float p03 = __expf(lrelu02(as0.w + ad4.w + tv0.w));
        e0 += tv0.x; e1 += tv0.y; e2 += tv0.z; e3 += tv0.w;
        d0 += p00; d1 += p01; d2 += p02; d3 += p03;
        const float w0 = head < 2 ? (head == 0 ? p00 : p01) : (head == 2 ? p02 : p03);
        acc[0] += w0 * bfl(g0.x); acc[1] += w0 * bfh(g0.x);
        acc[2] += w0 * bfl(g0.y); acc[3] += w0 * bfh(g0.y);
        acc[4] += w0 * bfl(g0.z); acc[5] += w0 * bfh(g0.z);
        acc[6] += w0 * bfl(g0.w); acc[7] += w0 * bfh(g0.w);
    }

    // self-loop (fill_value='mean')
    const float inv = 1.0f / fmaxf((float)(end - beg), 1.0f);
    const float4 asn = *(const float4*)(a_s + n * 4);
    {
        const float p0 = __expf(lrelu02(asn.x + ad4.x + e0 * inv));
        const float p1 = __expf(lrelu02(asn.y + ad4.y + e1 * inv));
        const float p2 = __expf(lrelu02(asn.z + ad4.z + e2 * inv));
        const float p3 = __expf(lrelu02(asn.w + ad4.w + e3 * inv));
        d0 += p0; d1 += p1; d2 += p2; d3 += p3;
        const uint4 g0 = *(const uint4*)(hb + (size_t)n * 512 + cbase);
        const float w0 = head < 2 ? (head == 0 ? p0 : p1) : (head == 2 ? p2 : p3);
        acc[0] += w0 * bfl(g0.x); acc[1] += w0 * bfh(g0.x);
        acc[2] += w0 * bfl(g0.y); acc[3] += w0 * bfh(g0.y);
        acc[4] += w0 * bfl(g0.z); acc[5] += w0 * bfh(g0.z);
        acc[6] += w0 * bfl(g0.w); acc[7] += w0 * bfh(g0.w);
    }

    const float i0 = 0.25f / (d0 + 1e-16f);
    const float i1 = 0.25f / (d1 + 1e-16f);
    const float i2 = 0.25f / (d2 + 1e-16f);
    const float i3 = 0.25f / (d3 + 1e-16f);
    const float ih = head < 2 ? (head == 0 ? i0 : i1) : (head == 2 ? i2 : i3);
    float t[8];
    #pragma unroll
    for (int k = 0; k < 8; ++k) {
        t[k] = acc[k] * ih;
        t[k] += __shfl_xor(t[k], 16);
        t[k] += __shfl_xor(t[k], 32);
    }
    if (lane < 16) {
        const float4 b0 = *(const float4*)(bias + cbase);
        const float4 b1 = *(const float4*)(bias + cbase + 4);
        float o[8];
        o[0] = fmaxf(t[0] + b0.x, 0.f); o[1] = fmaxf(t[1] + b0.y, 0.f);
        o[2] = fmaxf(t[2] + b0.z, 0.f); o[3] = fmaxf(t[3] + b0.w, 0.f);
        o[4] = fmaxf(t[4] + b1.x, 0.f); o[5] = fmaxf(t[5] + b1.y, 0.f);
        o[6] = fmaxf(t[6] + b1.z, 0.f); o[7] = fmaxf(t[7] + b1.w, 0.f);
        if (outf) {
            float4 v0 = {o[0], o[1], o[2], o[3]};
            float4 v1 = {o[4], o[5], o[6], o[7]};
            *(float4*)(outf + (size_t)n * DIM + cbase) = v0;
            *(float4*)(outf + (size_t)n * DIM + cbase + 4) = v1;
        }
        if (oh) {
            // split layout [c>>3][n][c&7]: c>>3 == lane here -> contiguous 8
            unsigned int hp[4], lp[4];
            #pragma unroll
            for (int i = 0; i < 4; ++i) {
                hp[i] = (hi16(o[2*i+1]) << 16) | hi16(o[2*i]);
                lp[i] = (lo16(o[2*i+1]) << 16) | lo16(o[2*i]);
            }
            const size_t p = ((size_t)lane * MP + n) * 8;
            *(uint4*)(oh + p) = make_uint4(hp[0], hp[1], hp[2], hp[3]);
            *(uint4*)(ol + p) = make_uint4(lp[0], lp[1], lp[2], lp[3]);
        }
    }
}

extern "C" void kernel_launch(void* const* d_in, const int* in_sizes, int n_in,
                              void* d_out, int out_size, void* d_ws, size_t ws_size,
                              hipStream_t stream)
{
    const float* x       = (const float*)d_in[0];
    const int*   eidx    = (const int*)d_in[1];
    const int*   etype   = (const int*)d_in[2];
    const float* w1      = (const float*)d_in[3];
    const float* b1      = (const float*)d_in[4];
    const float* w2      = (const float*)d_in[5];
    const float* b2      = (const float*)d_in[6];
    const float* rel_emb = (const float*)d_in[7];
    const float* lin[2]  = {(const float*)d_in[8],  (const float*)d_in[14]};
    const float* line[2] = {(const float*)d_in[9],  (const float*)d_in[15]};
    const float* atts[2] = {(const float*)d_in[10], (const float*)d_in[16]};
    const float* attd[2] = {(const float*)d_in[11], (const float*)d_in[17]};
    const float* atte[2] = {(const float*)d_in[12], (const float*)d_in[18]};
    const float* bias[2] = {(const float*)d_in[13], (const float*)d_in[19]};
    const int* src = eidx;
    const int* dst = eidx + N_EDGES;

    // ---- workspace layout ----
    char* base = (char*)d_ws;
    size_t off = 0;
    auto alloc = [&](size_t bytes) -> void* {
        void* p = base + off;
        off = (off + bytes + 255) & ~(size_t)255;
        return p;
    };
    ushort_t* xh  = (ushort_t*)alloc((size_t)68 * MP * 8 * 2);  // hb overlays (dead after enc1)
    ushort_t* xl  = (ushort_t*)alloc((size_t)68 * MP * 8 * 2);
    ushort_t* h1h = (ushort_t*)alloc((size_t)32 * MP * 8 * 2);  // xbuf1 overlays (dead after enc2)
    ushort_t* h1l = (ushort_t*)alloc((size_t)32 * MP * 8 * 2);
    ushort_t* x0h = (ushort_t*)alloc((size_t)16 * MP * 8 * 2);
    ushort_t* x0l = (ushort_t*)alloc((size_t)16 * MP * 8 * 2);
    void* reg1    = alloc((size_t)16 * MP * 8 * 2 * 2);         // xbuf0 fp32 | x1h+x1l
    ushort_t* w1h = (ushort_t*)alloc(68 * 256 * 8 * 2);
    ushort_t* w1l = (ushort_t*)alloc(68 * 256 * 8 * 2);
    ushort_t* w2h = (ushort_t*)alloc(32 * 128 * 8 * 2);
    ushort_t* w2l = (ushort_t*)alloc(32 * 128 * 8 * 2);
    ushort_t* l0h = (ushort_t*)alloc(16 * 512 * 8 * 2);
    ushort_t* l0l = (ushort_t*)alloc(16 * 512 * 8 * 2);
    ushort_t* l1h = (ushort_t*)alloc(16 * 512 * 8 * 2);
    ushort_t* l1l = (ushort_t*)alloc(16 * 512 * 8 * 2);
    float* a_s   = (float*)alloc(N_NODES * 4 * 4);
    float* a_d   = (float*)alloc(N_NODES * 4 * 4);
    float* table = (float*)alloc(128 * 4);
    float* wa_s  = (float*)alloc(512 * 4);
    float* wa_d  = (float*)alloc(512 * 4);
    int*  cnt_i  = (int*)alloc(N_NODES * 4);
    int*  ptr    = (int*)alloc((N_NODES + 4) * 4);
    int*  ptrc   = (int*)alloc(N_NODES * 4);
    int2* se     = (int2*)alloc((size_t)N_EDGES * 8);

    ushort_t* hb = xh;              // bf16 hfeat [MP][512], 20.5 MB (xh dead after enc1)
    float* xbuf1 = (float*)h1h;     // node_agg L0 fp32 out (h1 dead after enc2)
    float* xbuf0 = (float*)reg1;
    ushort_t* x1h = (ushort_t*)reg1;  // node_agg L0 split out (xbuf0 dead after as_ad L0)
    ushort_t* x1l = x1h + (size_t)16 * MP * 8;

    const int mtiles = MP / 64;     // 313

    // ---- input conversions ----
    conv_a_kernel<<<dim3((MP + 255) / 256, 68), 256, 0, stream>>>(x, xh, xl);
    conv_b_kernel<<<(68*256*8 + 255) / 256, 256, 0, stream>>>(w1, w1h, w1l, F_IN, HIDDEN, 68*256*8);
    conv_b_kernel<<<(32*128*8 + 255) / 256, 256, 0, stream>>>(w2, w2h, w2l, HIDDEN, DIM, 32*128*8);
    conv_b_kernel<<<(16*512*8 + 255) / 256, 256, 0, stream>>>(lin[0], l0h, l0l, DIM, NH*DIM, 16*512*8);
    conv_b_kernel<<<(16*512*8 + 255) / 256, 256, 0, stream>>>(lin[1], l1h, l1l, DIM, NH*DIM, 16*512*8);

    // ---- CSR build ----
    hipMemsetAsync(cnt_i, 0, N_NODES * sizeof(int), stream);
    hist_kernel<<<(N_EDGES + 255) / 256, 256, 0, stream>>>(dst, cnt_i);
    scan_kernel<<<1, 1024, 0, stream>>>(cnt_i, ptr, ptrc);
    scatter_kernel<<<(N_EDGES + 255) / 256, 256, 0, stream>>>(src, dst, etype, ptrc, se);

    // ---- node encoder ----
    gemm_mfma_v2<<<dim3(HIDDEN / 128, mtiles), 256, 0, stream>>>(
        xh, xl, w1h, w1l, b1, N_NODES, 68, HIDDEN, 1, nullptr, h1h, h1l, nullptr);
    gemm_mfma_v2<<<dim3(DIM / 128, mtiles), 256, 0, stream>>>(
        h1h, h1l, w2h, w2l, b2, N_NODES, 32, DIM, 0, xbuf0, x0h, x0l, nullptr);

    // ---- layer 0 ----
    gemm_mfma_v2<<<dim3((NH * DIM) / 128, mtiles), 256, 0, stream>>>(
        x0h, x0l, l0h, l0l, nullptr, N_NODES, 16, NH * DIM, 0, nullptr, nullptr, nullptr, hb);
    wa_kernel<<<4, 256, 0, stream>>>(lin[0], atts[0], attd[0], wa_s, wa_d);
    as_ad_kernel<<<N_NODES, 256, 0, stream>>>(xbuf0, wa_s, wa_d, a_s, a_d);
    rel_table_kernel<<<1, 128, 0, stream>>>(rel_emb, line[0], atte[0], table);
    node_agg_kernel<<<(N_NODES + 3) / 4, 256, 0, stream>>>(
        ptr, se, a_s, a_d, table, hb, bias[0], xbuf1, x1h, x1l);

    // ---- layer 1 ----
    gemm_mfma_v2<<<dim3((NH * DIM) / 128, mtiles), 256, 0, stream>>>(
        x1h, x1l, l1h, l1l, nullptr, N_NODES, 16, NH * DIM, 0, nullptr, nullptr, nullptr, hb);
    wa_kernel<<<4, 256, 0, stream>>>(lin[1], atts[1], attd[1], wa_s, wa_d);
    as_ad_kernel<<<N_NODES, 256, 0, stream>>>(xbuf1, wa_s, wa_d, a_s, a_d);
    rel_table_kernel<<<1, 128, 0, stream>>>(rel_emb, line[1], atte[1], table);
    node_agg_kernel<<<(N_NODES + 3) / 4, 256, 0, stream>>>(
        ptr, se, a_s, a_d, table, hb, bias[1], (float*)d_out, nullptr, nullptr);
}

// Round 8
// 473.256 us; speedup vs baseline: 1.5069x; 1.0470x over previous
//
#include <hip/hip_runtime.h>
#include <math.h>

#define N_NODES 20000
#define MP      20032          // M padded to 64
#define N_EDGES 320000
#define F_IN    518
#define HIDDEN  256
#define DIM     128
#define NH      4

typedef __attribute__((ext_vector_type(8))) short bf16x8;
typedef __attribute__((ext_vector_type(4))) float f32x4;
typedef unsigned short ushort_t;

__device__ __forceinline__ float lrelu02(float x) { return x > 0.f ? x : 0.2f * x; }

__device__ __forceinline__ void gl_lds16(const void* g, void* l) {
    __builtin_amdgcn_global_load_lds(
        (const __attribute__((address_space(1))) unsigned int*)g,
        (__attribute__((address_space(3))) unsigned int*)l, 16, 0, 0);
}

__device__ __forceinline__ unsigned int hi16(float v) { return __float_as_uint(v) >> 16; }
__device__ __forceinline__ unsigned int lo16(float v) {
    unsigned int h = __float_as_uint(v) & 0xFFFF0000u;
    return __float_as_uint(v - __uint_as_float(h)) >> 16;
}
// round-to-nearest-even bf16
__device__ __forceinline__ unsigned int rnd16(float v) {
    unsigned int u = __float_as_uint(v);
    return (u + 0x7FFFu + ((u >> 16) & 1u)) >> 16;
}
__device__ __forceinline__ float bfl(unsigned int u) { return __uint_as_float(u << 16); }
__device__ __forceinline__ float bfh(unsigned int u) { return __uint_as_float(u & 0xFFFF0000u); }

// ====== split-bf16 MFMA GEMM, operands pre-split, k-chunk-major ======
// A: [K8][MP][8] bf16 hi (+lo optional). B: [K8][N][8] bf16 hi/lo.
// Al != null: C = Ah*Bh + Ah*Bl + Al*Bh (3-term fp32-split).
// Al == null: C = Ah*Bh + Ah*Bl (A already quantized; exact in A).
// Tile 64x128, 4 waves; LDS 24KB; conflict-free ds_read_b128; global_load_lds x16.
__global__ __launch_bounds__(256, 4) void gemm_mfma_v2(
    const ushort_t* __restrict__ Ah, const ushort_t* __restrict__ Al,
    const ushort_t* __restrict__ Bh, const ushort_t* __restrict__ Bl,
    const float* __restrict__ bias,
    int M, int K8, int N, int act,
    float* __restrict__ Cf,                                      // fp32 [M][N]
    ushort_t* __restrict__ Ch, ushort_t* __restrict__ Cl,        // split A-layout
    ushort_t* __restrict__ Cb,                                   // plain bf16 [M][N]
    ushort_t* __restrict__ Ca)                                   // plain bf16 A-layout
{
    __shared__ __align__(16) ushort_t lds[12288];
    const int tid = threadIdx.x;
    const int w = tid >> 6, lane = tid & 63;
    const int row0 = blockIdx.y * 64, col0 = blockIdx.x * 128;
    const int nkb = K8 >> 2;
    const int m16 = lane & 15, q = lane >> 4;
    const bool use_al = (Al != nullptr);

    f32x4 acc[4][2] = {};

    for (int kb = 0; kb < nkb; ++kb) {
        const size_t kc = (size_t)(kb * 4 + w);
        const size_t aoff = (kc * MP + row0) * 8 + lane * 8;
        const size_t boff = (kc * N + col0) * 8 + lane * 8;
        gl_lds16(Ah + aoff, &lds[w * 512]);
        if (use_al) gl_lds16(Al + aoff, &lds[2048 + w * 512]);
        gl_lds16(Bh + boff,       &lds[4096 + w * 1024]);
        gl_lds16(Bh + boff + 512, &lds[4096 + w * 1024 + 512]);
        gl_lds16(Bl + boff,       &lds[8192 + w * 1024]);
        gl_lds16(Bl + boff + 512, &lds[8192 + w * 1024 + 512]);
        __syncthreads();

        bf16x8 fah[4], fal[4], fbh[2], fbl[2];
        const int fa = q * 512 + m16 * 8;
        #pragma unroll
        for (int mi = 0; mi < 4; ++mi) {
            fah[mi] = *(const bf16x8*)&lds[fa + mi * 128];
            if (use_al) fal[mi] = *(const bf16x8*)&lds[2048 + fa + mi * 128];
        }
        const int fb = q * 1024 + (w * 32 + m16) * 8;
        #pragma unroll
        for (int ni = 0; ni < 2; ++ni) {
            fbh[ni] = *(const bf16x8*)&lds[4096 + fb + ni * 128];
            fbl[ni] = *(const bf16x8*)&lds[8192 + fb + ni * 128];
        }
        #pragma unroll
        for (int mi = 0; mi < 4; ++mi)
            #pragma unroll
            for (int ni = 0; ni < 2; ++ni) {
                acc[mi][ni] = __builtin_amdgcn_mfma_f32_16x16x32_bf16(fah[mi], fbh[ni], acc[mi][ni], 0, 0, 0);
                acc[mi][ni] = __builtin_amdgcn_mfma_f32_16x16x32_bf16(fah[mi], fbl[ni], acc[mi][ni], 0, 0, 0);
            }
        if (use_al) {
            #pragma unroll
            for (int mi = 0; mi < 4; ++mi)
                #pragma unroll
                for (int ni = 0; ni < 2; ++ni)
                    acc[mi][ni] = __builtin_amdgcn_mfma_f32_16x16x32_bf16(fal[mi], fbh[ni], acc[mi][ni], 0, 0, 0);
        }
        __syncthreads();
    }

    // epilogue: C/D row=(lane>>4)*4+reg, col=lane&15
    #pragma unroll
    for (int ni = 0; ni < 2; ++ni) {
        const int col = col0 + w * 32 + ni * 16 + m16;
        const float bb = bias ? bias[col] : 0.f;
        #pragma unroll
        for (int mi = 0; mi < 4; ++mi) {
            #pragma unroll
            for (int r = 0; r < 4; ++r) {
                const int row = row0 + mi * 16 + q * 4 + r;
                if (row < M) {
                    float v = acc[mi][ni][r] + bb;
                    if (act) v = fmaxf(v, 0.f);
                    if (Cf) Cf[(size_t)row * N + col] = v;
                    if (Cb) Cb[(size_t)row * N + col] = (ushort_t)rnd16(v);
                    const size_t p = (((size_t)(col >> 3)) * MP + row) * 8 + (col & 7);
                    if (Ch) { Ch[p] = (ushort_t)hi16(v); Cl[p] = (ushort_t)lo16(v); }
                    if (Ca) Ca[p] = (ushort_t)rnd16(v);
                }
            }
        }
    }
}

// ---- x fp32 [N_NODES][F_IN] -> xh/xl bf16 [K8][MP][8], zero-padded ----
__global__ __launch_bounds__(256) void conv_a_kernel(
    const float* __restrict__ x, ushort_t* __restrict__ xh, ushort_t* __restrict__ xl)
{
    const int row = blockIdx.x * 256 + threadIdx.x;
    const int k8 = blockIdx.y;
    if (row >= MP) return;
    float v[8];
    #pragma unroll
    for (int j = 0; j < 8; ++j) {
        const int k = k8 * 8 + j;
        v[j] = (row < N_NODES && k < F_IN) ? x[(size_t)row * F_IN + k] : 0.f;
    }
    unsigned int hp[4], lp[4];
    #pragma unroll
    for (int i = 0; i < 4; ++i) {
        hp[i] = (hi16(v[2*i+1]) << 16) | hi16(v[2*i]);
        lp[i] = (lo16(v[2*i+1]) << 16) | lo16(v[2*i]);
    }
    const size_t p = ((size_t)k8 * MP + row) * 8;
    *(uint4*)(xh + p) = make_uint4(hp[0], hp[1], hp[2], hp[3]);
    *(uint4*)(xl + p) = make_uint4(lp[0], lp[1], lp[2], lp[3]);
}

// ---- weight w[K][N] fp32 -> bh/bl bf16 [K8][N][8] ----
__global__ __launch_bounds__(256) void conv_b_kernel(
    const float* __restrict__ w, ushort_t* __restrict__ bh, ushort_t* __restrict__ bl,
    int K, int N, int total)
{
    const int idx = blockIdx.x * 256 + threadIdx.x;
    if (idx >= total) return;
    const int j = idx & 7;
    const int rem = idx >> 3;
    const int n = rem % N;
    const int k = (rem / N) * 8 + j;
    const float v = (k < K) ? w[(size_t)k * N + n] : 0.f;
    bh[idx] = (ushort_t)hi16(v);
    bl[idx] = (ushort_t)lo16(v);
}

// ---- wa_s/wa_d [H][D]: folded lin @ att ----
__global__ __launch_bounds__(256) void wa_kernel(
    const float* __restrict__ lin, const float* __restrict__ atts,
    const float* __restrict__ attd, float* __restrict__ wa_s, float* __restrict__ wa_d)
{
    const int wrk = blockIdx.x * 256 + threadIdx.x;
    if (wrk >= 1024) return;
    const int sd = wrk >> 9;
    const int p = wrk & 511;
    const int h = p >> 7, d = p & 127;
    const float* av = (sd ? attd : atts) + h * DIM;
    const float* lp = lin + (size_t)d * (NH * DIM) + h * DIM;
    float acc = 0.f;
    #pragma unroll 8
    for (int i = 0; i < DIM; ++i) acc += lp[i] * av[i];
    (sd ? wa_d : wa_s)[h * DIM + d] = acc;
}

// ---- a_s[n,h], a_d[n,h] from xbuf (fp32 [N][128]) ----
__global__ __launch_bounds__(256) void as_ad_kernel(
    const float* __restrict__ xb, const float* __restrict__ wa_s,
    const float* __restrict__ wa_d, float* __restrict__ a_s, float* __restrict__ a_d)
{
    const int gw = blockIdx.x * 4 + (threadIdx.x >> 6);
    const int lane = threadIdx.x & 63;
    if (gw >= N_NODES * NH) return;
    const int n = gw >> 2, h = gw & 3;
    const float* hp = xb + (size_t)n * DIM;
    float2 hv = *(const float2*)(hp + lane * 2);
    float2 sv = *(const float2*)(wa_s + h * DIM + lane * 2);
    float2 dv = *(const float2*)(wa_d + h * DIM + lane * 2);
    float s = hv.x * sv.x + hv.y * sv.y;
    float d = hv.x * dv.x + hv.y * dv.y;
    #pragma unroll
    for (int off = 32; off > 0; off >>= 1) {
        s += __shfl_down(s, off);
        d += __shfl_down(d, off);
    }
    if (lane == 0) { a_s[n * 4 + h] = s; a_d[n * 4 + h] = d; }
}

// ---- rel attention table[r,h] ----
__global__ __launch_bounds__(128) void rel_table_kernel(
    const float* __restrict__ rel_emb, const float* __restrict__ line,
    const float* __restrict__ atte, float* __restrict__ table)
{
    __shared__ float we[32][NH];
    const int tid = threadIdx.x;
    const int k = tid >> 2, h = tid & 3;
    float acc = 0.f;
    for (int d = 0; d < DIM; ++d)
        acc += line[(size_t)k * (NH * DIM) + h * DIM + d] * atte[h * DIM + d];
    we[k][h] = acc;
    __syncthreads();
    if (tid < 26 * NH) {
        int r = tid >> 2, hh = tid & 3;
        float t = 0.f;
        for (int kk = 0; kk < 32; ++kk) t += rel_emb[r * 32 + kk] * we[kk][hh];
        table[r * 4 + hh] = t;
    }
}

// ================= CSR build =================
__global__ __launch_bounds__(256) void hist_kernel(
    const int* __restrict__ dst, int* __restrict__ cnt)
{
    const int e = blockIdx.x * blockDim.x + threadIdx.x;
    if (e >= N_EDGES) return;
    atomicAdd(&cnt[dst[e]], 1);
}

__global__ __launch_bounds__(1024) void scan_kernel(
    const int* __restrict__ cnt, int* __restrict__ ptr, int* __restrict__ ptr_copy)
{
    __shared__ int tsum[1024];
    const int tid = threadIdx.x;
    const int CH = 20;
    const int base = tid * CH;
    int s = 0;
    #pragma unroll
    for (int i = 0; i < CH; ++i) {
        int idx = base + i;
        if (idx < N_NODES) s += cnt[idx];
    }
    tsum[tid] = s;
    __syncthreads();
    for (int off = 1; off < 1024; off <<= 1) {
        int v = (tid >= off) ? tsum[tid - off] : 0;
        __syncthreads();
        tsum[tid] += v;
        __syncthreads();
    }
    int run = (tid == 0) ? 0 : tsum[tid - 1];
    #pragma unroll
    for (int i = 0; i < CH; ++i) {
        int idx = base + i;
        if (idx < N_NODES) {
            ptr[idx] = run;
            ptr_copy[idx] = run;
            run += cnt[idx];
        }
    }
    if (tid == 0) ptr[N_NODES] = N_EDGES;
}

__global__ __launch_bounds__(256) void scatter_kernel(
    const int* __restrict__ src, const int* __restrict__ dst, const int* __restrict__ etype,
    int* __restrict__ ptr_copy, int2* __restrict__ se)
{
    const int e = blockIdx.x * blockDim.x + threadIdx.x;
    if (e >= N_EDGES) return;
    const int d = dst[e];
    const int pos = atomicAdd(&ptr_copy[d], 1);
    se[pos] = make_int2(src[e], etype[e]);
}

// ===== fused per-node GAT aggregate; own-head math only =====
// hb: bf16 [n][512]. Lane l covers cols l*8..l*8+7, head = l>>4 — each lane
// computes exp/denominator for ITS head only (shfl_xor(16,32) sums heads).
__global__ __launch_bounds__(256) void node_agg_kernel(
    const int* __restrict__ ptr, const int2* __restrict__ se,
    const float* __restrict__ a_s, const float* __restrict__ a_d,
    const float* __restrict__ table, const ushort_t* __restrict__ hb,
    const float* __restrict__ bias,
    float* __restrict__ outf, ushort_t* __restrict__ oa)
{
    const int n = blockIdx.x * 4 + (threadIdx.x >> 6);
    const int lane = threadIdx.x & 63;
    if (n >= N_NODES) return;
    const int beg = ptr[n], end = ptr[n + 1];
    const int head = lane >> 4;
    const int cbase = lane * 8;
    const float adh = a_d[n * 4 + head];

    float acc[8] = {};
    float dh = 0.f, eh = 0.f;

    int j = beg;
    for (; j + 2 <= end; j += 2) {
        const int2 E0 = se[j], E1 = se[j + 1];
        const uint4 g0 = *(const uint4*)(hb + (size_t)E0.x * 512 + cbase);
        const uint4 g1 = *(const uint4*)(hb + (size_t)E1.x * 512 + cbase);
        const float a0 = a_s[E0.x * 4 + head];
        const float t0 = table[E0.y * 4 + head];
        const float a1 = a_s[E1.x * 4 + head];
        const float t1 = table[E1.y * 4 + head];
        const float p0 = __expf(lrelu02(a0 + adh + t0));
        const float p1 = __expf(lrelu02(a1 + adh + t1));
        eh += t0 + t1;
        dh += p0 + p1;
        acc[0] += p0 * bfl(g0.x) + p1 * bfl(g1.x);
        acc[1] += p0 * bfh(g0.x) + p1 * bfh(g1.x);
        acc[2] += p0 * bfl(g0.y) + p1 * bfl(g1.y);
        acc[3] += p0 * bfh(g0.y) + p1 * bfh(g1.y);
        acc[4] += p0 * bfl(g0.z) + p1 * bfl(g1.z);
        acc[5] += p0 * bfh(g0.z) + p1 * bfh(g1.z);
        acc[6] += p0 * bfl(g0.w) + p1 * bfl(g1.w);
        acc[7] += p0 * bfh(g0.w) + p1 * bfh(g1.w);
    }
    if (j < end) {
        const int2 E0 = se[j];
        const uint4 g0 = *(const uint4*)(hb + (size_t)E0.x * 512 + cbase);
        const float a0 = a_s[E0.x * 4 + head];
        const float t0 = table[E0.y * 4 + head];
        const float p0 = __expf(lrelu02(a0 + adh + t0));
        eh += t0;
        dh += p0;
        acc[0] += p0 * bfl(g0.x); acc[1] += p0 * bfh(g0.x);
        acc[2] += p0 * bfl(g0.y); acc[3] += p0 * bfh(g0.y);
        acc[4] += p0 * bfl(g0.z); acc[5] += p0 * bfh(g0.z);
        acc[6] += p0 * bfl(g0.w); acc[7] += p0 * bfh(g0.w);
    }

    // self-loop (fill_value='mean')
    const float inv = 1.0f / fmaxf((float)(end - beg), 1.0f);
    const float ps = __expf(lrelu02(a_s[n * 4 + head] + adh + eh * inv));
    dh += ps;
    {
        const uint4 gs = *(const uint4*)(hb + (size_t)n * 512 + cbase);
        acc[0] += ps * bfl(gs.x); acc[1] += ps * bfh(gs.x);
        acc[2] += ps * bfl(gs.y); acc[3] += ps * bfh(gs.y);
        acc[4] += ps * bfl(gs.z); acc[5] += ps * bfh(gs.z);
        acc[6] += ps * bfl(gs.w); acc[7] += ps * bfh(gs.w);
    }

    const float ih = 0.25f / (dh + 1e-16f);
    float t[8];
    #pragma unroll
    for (int k = 0; k < 8; ++k) {
        t[k] = acc[k] * ih;
        t[k] += __shfl_xor(t[k], 16);
        t[k] += __shfl_xor(t[k], 32);
    }
    if (lane < 16) {
        const float4 b0 = *(const float4*)(bias + cbase);
        const float4 b1 = *(const float4*)(bias + cbase + 4);
        float o[8];
        o[0] = fmaxf(t[0] + b0.x, 0.f); o[1] = fmaxf(t[1] + b0.y, 0.f);
        o[2] = fmaxf(t[2] + b0.z, 0.f); o[3] = fmaxf(t[3] + b0.w, 0.f);
        o[4] = fmaxf(t[4] + b1.x, 0.f); o[5] = fmaxf(t[5] + b1.y, 0.f);
        o[6] = fmaxf(t[6] + b1.z, 0.f); o[7] = fmaxf(t[7] + b1.w, 0.f);
        if (outf) {
            float4 v0 = {o[0], o[1], o[2], o[3]};
            float4 v1 = {o[4], o[5], o[6], o[7]};
            *(float4*)(outf + (size_t)n * DIM + cbase) = v0;
            *(float4*)(outf + (size_t)n * DIM + cbase + 4) = v1;
        }
        if (oa) {
            // A-layout [c>>3][n][c&7]: c>>3 == lane -> one contiguous uint4
            unsigned int up[4];
            #pragma unroll
            for (int i = 0; i < 4; ++i)
                up[i] = (rnd16(o[2*i+1]) << 16) | rnd16(o[2*i]);
            *(uint4*)(oa + ((size_t)lane * MP + n) * 8) = make_uint4(up[0], up[1], up[2], up[3]);
        }
    }
}

extern "C" void kernel_launch(void* const* d_in, const int* in_sizes, int n_in,
                              void* d_out, int out_size, void* d_ws, size_t ws_size,
                              hipStream_t stream)
{
    const float* x       = (const float*)d_in[0];
    const int*   eidx    = (const int*)d_in[1];
    const int*   etype   = (const int*)d_in[2];
    const float* w1      = (const float*)d_in[3];
    const float* b1      = (const float*)d_in[4];
    const float* w2      = (const float*)d_in[5];
    const float* b2      = (const float*)d_in[6];
    const float* rel_emb = (const float*)d_in[7];
    const float* lin[2]  = {(const float*)d_in[8],  (const float*)d_in[14]};
    const float* line[2] = {(const float*)d_in[9],  (const float*)d_in[15]};
    const float* atts[2] = {(const float*)d_in[10], (const float*)d_in[16]};
    const float* attd[2] = {(const float*)d_in[11], (const float*)d_in[17]};
    const float* atte[2] = {(const float*)d_in[12], (const float*)d_in[18]};
    const float* bias[2] = {(const float*)d_in[13], (const float*)d_in[19]};
    const int* src = eidx;
    const int* dst = eidx + N_EDGES;

    // ---- workspace layout ----
    char* base = (char*)d_ws;
    size_t off = 0;
    auto alloc = [&](size_t bytes) -> void* {
        void* p = base + off;
        off = (off + bytes + 255) & ~(size_t)255;
        return p;
    };
    ushort_t* xh  = (ushort_t*)alloc((size_t)68 * MP * 8 * 2);  // hb overlays (dead after enc1)
    ushort_t* xl  = (ushort_t*)alloc((size_t)68 * MP * 8 * 2);
    ushort_t* h1h = (ushort_t*)alloc((size_t)32 * MP * 8 * 2);  // xbuf1 overlays (dead after enc2)
    ushort_t* h1l = (ushort_t*)alloc((size_t)32 * MP * 8 * 2);
    ushort_t* x0a = (ushort_t*)alloc((size_t)16 * MP * 8 * 2);
    void* reg1    = alloc((size_t)16 * MP * 8 * 4);             // xbuf0 fp32 | x1a
    ushort_t* w1h = (ushort_t*)alloc(68 * 256 * 8 * 2);
    ushort_t* w1l = (ushort_t*)alloc(68 * 256 * 8 * 2);
    ushort_t* w2h = (ushort_t*)alloc(32 * 128 * 8 * 2);
    ushort_t* w2l = (ushort_t*)alloc(32 * 128 * 8 * 2);
    ushort_t* l0h = (ushort_t*)alloc(16 * 512 * 8 * 2);
    ushort_t* l0l = (ushort_t*)alloc(16 * 512 * 8 * 2);
    ushort_t* l1h = (ushort_t*)alloc(16 * 512 * 8 * 2);
    ushort_t* l1l = (ushort_t*)alloc(16 * 512 * 8 * 2);
    float* a_s   = (float*)alloc(N_NODES * 4 * 4);
    float* a_d   = (float*)alloc(N_NODES * 4 * 4);
    float* table = (float*)alloc(128 * 4);
    float* wa_s  = (float*)alloc(512 * 4);
    float* wa_d  = (float*)alloc(512 * 4);
    int*  cnt_i  = (int*)alloc(N_NODES * 4);
    int*  ptr    = (int*)alloc((N_NODES + 4) * 4);
    int*  ptrc   = (int*)alloc(N_NODES * 4);
    int2* se     = (int2*)alloc((size_t)N_EDGES * 8);

    ushort_t* hb = xh;              // bf16 hfeat [MP][512], 20.5 MB (xh dead after enc1)
    float* xbuf1 = (float*)h1h;     // node_agg L0 fp32 out (h1 dead after enc2)
    float* xbuf0 = (float*)reg1;
    ushort_t* x1a = (ushort_t*)reg1;  // node_agg L0 bf16 A-layout out (xbuf0 dead after as_ad L0)

    const int mtiles = MP / 64;     // 313

    // ---- input conversions ----
    conv_a_kernel<<<dim3((MP + 255) / 256, 68), 256, 0, stream>>>(x, xh, xl);
    conv_b_kernel<<<(68*256*8 + 255) / 256, 256, 0, stream>>>(w1, w1h, w1l, F_IN, HIDDEN, 68*256*8);
    conv_b_kernel<<<(32*128*8 + 255) / 256, 256, 0, stream>>>(w2, w2h, w2l, HIDDEN, DIM, 32*128*8);
    conv_b_kernel<<<(16*512*8 + 255) / 256, 256, 0, stream>>>(lin[0], l0h, l0l, DIM, NH*DIM, 16*512*8);
    conv_b_kernel<<<(16*512*8 + 255) / 256, 256, 0, stream>>>(lin[1], l1h, l1l, DIM, NH*DIM, 16*512*8);

    // ---- CSR build ----
    hipMemsetAsync(cnt_i, 0, N_NODES * sizeof(int), stream);
    hist_kernel<<<(N_EDGES + 255) / 256, 256, 0, stream>>>(dst, cnt_i);
    scan_kernel<<<1, 1024, 0, stream>>>(cnt_i, ptr, ptrc);
    scatter_kernel<<<(N_EDGES + 255) / 256, 256, 0, stream>>>(src, dst, etype, ptrc, se);

    // ---- node encoder (3-term split) ----
    gemm_mfma_v2<<<dim3(HIDDEN / 128, mtiles), 256, 0, stream>>>(
        xh, xl, w1h, w1l, b1, N_NODES, 68, HIDDEN, 1, nullptr, h1h, h1l, nullptr, nullptr);
    gemm_mfma_v2<<<dim3(DIM / 128, mtiles), 256, 0, stream>>>(
        h1h, h1l, w2h, w2l, b2, N_NODES, 32, DIM, 0, xbuf0, nullptr, nullptr, nullptr, x0a);

    // ---- layer 0 (2-term: A quantized bf16) ----
    gemm_mfma_v2<<<dim3((NH * DIM) / 128, mtiles), 256, 0, stream>>>(
        x0a, nullptr, l0h, l0l, nullptr, N_NODES, 16, NH * DIM, 0, nullptr, nullptr, nullptr, hb, nullptr);
    wa_kernel<<<4, 256, 0, stream>>>(lin[0], atts[0], attd[0], wa_s, wa_d);
    as_ad_kernel<<<N_NODES, 256, 0, stream>>>(xbuf0, wa_s, wa_d, a_s, a_d);
    rel_table_kernel<<<1, 128, 0, stream>>>(rel_emb, line[0], atte[0], table);
    node_agg_kernel<<<(N_NODES + 3) / 4, 256, 0, stream>>>(
        ptr, se, a_s, a_d, table, hb, bias[0], xbuf1, x1a);

    // ---- layer 1 (2-term) ----
    gemm_mfma_v2<<<dim3((NH * DIM) / 128, mtiles), 256, 0, stream>>>(
        x1a, nullptr, l1h, l1l, nullptr, N_NODES, 16, NH * DIM, 0, nullptr, nullptr, nullptr, hb, nullptr);
    wa_kernel<<<4, 256, 0, stream>>>(lin[1], atts[1], attd[1], wa_s, wa_d);
    as_ad_kernel<<<N_NODES, 256, 0, stream>>>(xbuf1, wa_s, wa_d, a_s, a_d);
    rel_table_kernel<<<1, 128, 0, stream>>>(rel_emb, line[1], atte[1], table);
    node_agg_kernel<<<(N_NODES + 3) / 4, 256, 0, stream>>>(
        ptr, se, a_s, a_d, table, hb, bias[1], (float*)d_out, nullptr);
}

// Round 9
// 444.388 us; speedup vs baseline: 1.6047x; 1.0650x over previous
//
#include <hip/hip_runtime.h>
#include <math.h>

#define N_NODES 20000
#define MP      20032          // M padded to 64
#define N_EDGES 320000
#define F_IN    518
#define HIDDEN  256
#define DIM     128
#define NH      4

typedef __attribute__((ext_vector_type(8))) short bf16x8;
typedef __attribute__((ext_vector_type(4))) float f32x4;
typedef unsigned short ushort_t;

__device__ __forceinline__ float lrelu02(float x) { return x > 0.f ? x : 0.2f * x; }

__device__ __forceinline__ void gl_lds16(const void* g, void* l) {
    __builtin_amdgcn_global_load_lds(
        (const __attribute__((address_space(1))) unsigned int*)g,
        (__attribute__((address_space(3))) unsigned int*)l, 16, 0, 0);
}

__device__ __forceinline__ unsigned int hi16(float v) { return __float_as_uint(v) >> 16; }
__device__ __forceinline__ unsigned int lo16(float v) {
    unsigned int h = __float_as_uint(v) & 0xFFFF0000u;
    return __float_as_uint(v - __uint_as_float(h)) >> 16;
}
// round-to-nearest-even bf16
__device__ __forceinline__ unsigned int rnd16(float v) {
    unsigned int u = __float_as_uint(v);
    return (u + 0x7FFFu + ((u >> 16) & 1u)) >> 16;
}
__device__ __forceinline__ float bfl(unsigned int u) { return __uint_as_float(u << 16); }
__device__ __forceinline__ float bfh(unsigned int u) { return __uint_as_float(u & 0xFFFF0000u); }

// ====== split-bf16 MFMA GEMM, operands pre-split, k-chunk-major ======
// A: [K8][MP][8] bf16 hi (+lo optional). B: [K8][N][8] bf16 hi/lo.
// Al != null: C = Ah*Bh + Ah*Bl + Al*Bh (3-term fp32-split).
// Al == null: C = Ah*Bh + Ah*Bl (A already quantized; exact in A).
// Tile 64x128, 4 waves; LDS 24KB; conflict-free ds_read_b128; global_load_lds x16.
__global__ __launch_bounds__(256, 4) void gemm_mfma_v2(
    const ushort_t* __restrict__ Ah, const ushort_t* __restrict__ Al,
    const ushort_t* __restrict__ Bh, const ushort_t* __restrict__ Bl,
    const float* __restrict__ bias,
    int M, int K8, int N, int act,
    float* __restrict__ Cf,                                      // fp32 [M][N]
    ushort_t* __restrict__ Ch, ushort_t* __restrict__ Cl,        // split A-layout
    ushort_t* __restrict__ Cb,                                   // plain bf16 [M][N]
    ushort_t* __restrict__ Ca)                                   // plain bf16 A-layout
{
    __shared__ __align__(16) ushort_t lds[12288];
    const int tid = threadIdx.x;
    const int w = tid >> 6, lane = tid & 63;
    const int row0 = blockIdx.y * 64, col0 = blockIdx.x * 128;
    const int nkb = K8 >> 2;
    const int m16 = lane & 15, q = lane >> 4;
    const bool use_al = (Al != nullptr);

    f32x4 acc[4][2] = {};

    for (int kb = 0; kb < nkb; ++kb) {
        const size_t kc = (size_t)(kb * 4 + w);
        const size_t aoff = (kc * MP + row0) * 8 + lane * 8;
        const size_t boff = (kc * N + col0) * 8 + lane * 8;
        gl_lds16(Ah + aoff, &lds[w * 512]);
        if (use_al) gl_lds16(Al + aoff, &lds[2048 + w * 512]);
        gl_lds16(Bh + boff,       &lds[4096 + w * 1024]);
        gl_lds16(Bh + boff + 512, &lds[4096 + w * 1024 + 512]);
        gl_lds16(Bl + boff,       &lds[8192 + w * 1024]);
        gl_lds16(Bl + boff + 512, &lds[8192 + w * 1024 + 512]);
        __syncthreads();

        bf16x8 fah[4], fal[4], fbh[2], fbl[2];
        const int fa = q * 512 + m16 * 8;
        #pragma unroll
        for (int mi = 0; mi < 4; ++mi) {
            fah[mi] = *(const bf16x8*)&lds[fa + mi * 128];
            if (use_al) fal[mi] = *(const bf16x8*)&lds[2048 + fa + mi * 128];
        }
        const int fb = q * 1024 + (w * 32 + m16) * 8;
        #pragma unroll
        for (int ni = 0; ni < 2; ++ni) {
            fbh[ni] = *(const bf16x8*)&lds[4096 + fb + ni * 128];
            fbl[ni] = *(const bf16x8*)&lds[8192 + fb + ni * 128];
        }
        #pragma unroll
        for (int mi = 0; mi < 4; ++mi)
            #pragma unroll
            for (int ni = 0; ni < 2; ++ni) {
                acc[mi][ni] = __builtin_amdgcn_mfma_f32_16x16x32_bf16(fah[mi], fbh[ni], acc[mi][ni], 0, 0, 0);
                acc[mi][ni] = __builtin_amdgcn_mfma_f32_16x16x32_bf16(fah[mi], fbl[ni], acc[mi][ni], 0, 0, 0);
            }
        if (use_al) {
            #pragma unroll
            for (int mi = 0; mi < 4; ++mi)
                #pragma unroll
                for (int ni = 0; ni < 2; ++ni)
                    acc[mi][ni] = __builtin_amdgcn_mfma_f32_16x16x32_bf16(fal[mi], fbh[ni], acc[mi][ni], 0, 0, 0);
        }
        __syncthreads();
    }

    // epilogue: C/D row=(lane>>4)*4+reg, col=lane&15
    #pragma unroll
    for (int ni = 0; ni < 2; ++ni) {
        const int col = col0 + w * 32 + ni * 16 + m16;
        const float bb = bias ? bias[col] : 0.f;
        #pragma unroll
        for (int mi = 0; mi < 4; ++mi) {
            #pragma unroll
            for (int r = 0; r < 4; ++r) {
                const int row = row0 + mi * 16 + q * 4 + r;
                if (row < M) {
                    float v = acc[mi][ni][r] + bb;
                    if (act) v = fmaxf(v, 0.f);
                    if (Cf) Cf[(size_t)row * N + col] = v;
                    if (Cb) Cb[(size_t)row * N + col] = (ushort_t)rnd16(v);
                    const size_t p = (((size_t)(col >> 3)) * MP + row) * 8 + (col & 7);
                    if (Ch) { Ch[p] = (ushort_t)hi16(v); Cl[p] = (ushort_t)lo16(v); }
                    if (Ca) Ca[p] = (ushort_t)rnd16(v);
                }
            }
        }
    }
}

// ---- x fp32 [N_NODES][F_IN] -> xh/xl bf16 [K8][MP][8], coalesced via LDS tile ----
// Block: 64 rows x 64 k. Load: float4 row-contiguous (coalesced). Store: per
// k8-chunk, 64 rows x 8 k = 1 KB contiguous runs (coalesced). Pads with zeros.
__global__ __launch_bounds__(256) void conv_a_t_kernel(
    const float* __restrict__ x, ushort_t* __restrict__ xh, ushort_t* __restrict__ xl)
{
    __shared__ float tile[64][68];
    const int tid = threadIdx.x;
    const int r0 = blockIdx.x * 64;
    const int c0 = blockIdx.y * 64;

    #pragma unroll
    for (int it = 0; it < 4; ++it) {
        const int r = (tid >> 4) + it * 16;
        const int c = (tid & 15) * 4;
        const int gr = r0 + r, gc = c0 + c;
        float4 v = {0.f, 0.f, 0.f, 0.f};
        if (gr < N_NODES) {
            if (gc + 3 < F_IN) {
                v = *(const float4*)(x + (size_t)gr * F_IN + gc);
            } else {
                float tmp[4] = {0.f, 0.f, 0.f, 0.f};
                #pragma unroll
                for (int u = 0; u < 4; ++u)
                    if (gc + u < F_IN) tmp[u] = x[(size_t)gr * F_IN + gc + u];
                v.x = tmp[0]; v.y = tmp[1]; v.z = tmp[2]; v.w = tmp[3];
            }
        }
        tile[r][c] = v.x; tile[r][c+1] = v.y; tile[r][c+2] = v.z; tile[r][c+3] = v.w;
    }
    __syncthreads();

    const int k8l = tid >> 5;           // 0..7
    const int k8 = (c0 >> 3) + k8l;
    if (k8 >= 68) return;               // K padded to 544 (68 chunks)
    const int rr = (tid & 31) * 2;
    #pragma unroll
    for (int u = 0; u < 2; ++u) {
        const int r = rr + u;
        unsigned int hp[4], lp[4];
        #pragma unroll
        for (int i = 0; i < 4; ++i) {
            const float v0 = tile[r][k8l * 8 + 2 * i];
            const float v1 = tile[r][k8l * 8 + 2 * i + 1];
            hp[i] = (hi16(v1) << 16) | hi16(v0);
            lp[i] = (lo16(v1) << 16) | lo16(v0);
        }
        const size_t p = ((size_t)k8 * MP + r0 + r) * 8;
        *(uint4*)(xh + p) = make_uint4(hp[0], hp[1], hp[2], hp[3]);
        *(uint4*)(xl + p) = make_uint4(lp[0], lp[1], lp[2], lp[3]);
    }
}

// ---- weight w[K][N] fp32 -> bh/bl bf16 [K8][N][8] ----
__global__ __launch_bounds__(256) void conv_b_kernel(
    const float* __restrict__ w, ushort_t* __restrict__ bh, ushort_t* __restrict__ bl,
    int K, int N, int total)
{
    const int idx = blockIdx.x * 256 + threadIdx.x;
    if (idx >= total) return;
    const int j = idx & 7;
    const int rem = idx >> 3;
    const int n = rem % N;
    const int k = (rem / N) * 8 + j;
    const float v = (k < K) ? w[(size_t)k * N + n] : 0.f;
    bh[idx] = (ushort_t)hi16(v);
    bl[idx] = (ushort_t)lo16(v);
}

// ---- wa_s/wa_d [H][D]: folded lin @ att ----
__global__ __launch_bounds__(256) void wa_kernel(
    const float* __restrict__ lin, const float* __restrict__ atts,
    const float* __restrict__ attd, float* __restrict__ wa_s, float* __restrict__ wa_d)
{
    const int wrk = blockIdx.x * 256 + threadIdx.x;
    if (wrk >= 1024) return;
    const int sd = wrk >> 9;
    const int p = wrk & 511;
    const int h = p >> 7, d = p & 127;
    const float* av = (sd ? attd : atts) + h * DIM;
    const float* lp = lin + (size_t)d * (NH * DIM) + h * DIM;
    float acc = 0.f;
    #pragma unroll 8
    for (int i = 0; i < DIM; ++i) acc += lp[i] * av[i];
    (sd ? wa_d : wa_s)[h * DIM + d] = acc;
}

// ---- a_s[n,h], a_d[n,h] from xbuf (fp32 [N][128]) ----
__global__ __launch_bounds__(256) void as_ad_kernel(
    const float* __restrict__ xb, const float* __restrict__ wa_s,
    const float* __restrict__ wa_d, float* __restrict__ a_s, float* __restrict__ a_d)
{
    const int gw = blockIdx.x * 4 + (threadIdx.x >> 6);
    const int lane = threadIdx.x & 63;
    if (gw >= N_NODES * NH) return;
    const int n = gw >> 2, h = gw & 3;
    const float* hp = xb + (size_t)n * DIM;
    float2 hv = *(const float2*)(hp + lane * 2);
    float2 sv = *(const float2*)(wa_s + h * DIM + lane * 2);
    float2 dv = *(const float2*)(wa_d + h * DIM + lane * 2);
    float s = hv.x * sv.x + hv.y * sv.y;
    float d = hv.x * dv.x + hv.y * dv.y;
    #pragma unroll
    for (int off = 32; off > 0; off >>= 1) {
        s += __shfl_down(s, off);
        d += __shfl_down(d, off);
    }
    if (lane == 0) { a_s[n * 4 + h] = s; a_d[n * 4 + h] = d; }
}

// ---- rel attention table[r,h] ----
__global__ __launch_bounds__(128) void rel_table_kernel(
    const float* __restrict__ rel_emb, const float* __restrict__ line,
    const float* __restrict__ atte, float* __restrict__ table)
{
    __shared__ float we[32][NH];
    const int tid = threadIdx.x;
    const int k = tid >> 2, h = tid & 3;
    float acc = 0.f;
    for (int d = 0; d < DIM; ++d)
        acc += line[(size_t)k * (NH * DIM) + h * DIM + d] * atte[h * DIM + d];
    we[k][h] = acc;
    __syncthreads();
    if (tid < 26 * NH) {
        int r = tid >> 2, hh = tid & 3;
        float t = 0.f;
        for (int kk = 0; kk < 32; ++kk) t += rel_emb[r * 32 + kk] * we[kk][hh];
        table[r * 4 + hh] = t;
    }
}

// ================= CSR build =================
__global__ __launch_bounds__(256) void hist_kernel(
    const int* __restrict__ dst, int* __restrict__ cnt)
{
    const int e = blockIdx.x * blockDim.x + threadIdx.x;
    if (e >= N_EDGES) return;
    atomicAdd(&cnt[dst[e]], 1);
}

__global__ __launch_bounds__(1024) void scan_kernel(
    const int* __restrict__ cnt, int* __restrict__ ptr, int* __restrict__ ptr_copy)
{
    __shared__ int tsum[1024];
    const int tid = threadIdx.x;
    const int CH = 20;
    const int base = tid * CH;
    int s = 0;
    #pragma unroll
    for (int i = 0; i < CH; ++i) {
        int idx = base + i;
        if (idx < N_NODES) s += cnt[idx];
    }
    tsum[tid] = s;
    __syncthreads();
    for (int off = 1; off < 1024; off <<= 1) {
        int v = (tid >= off) ? tsum[tid - off] : 0;
        __syncthreads();
        tsum[tid] += v;
        __syncthreads();
    }
    int run = (tid == 0) ? 0 : tsum[tid - 1];
    #pragma unroll
    for (int i = 0; i < CH; ++i) {
        int idx = base + i;
        if (idx < N_NODES) {
            ptr[idx] = run;
            ptr_copy[idx] = run;
            run += cnt[idx];
        }
    }
    if (tid == 0) ptr[N_NODES] = N_EDGES;
}

__global__ __launch_bounds__(256) void scatter_kernel(
    const int* __restrict__ src, const int* __restrict__ dst, const int* __restrict__ etype,
    int* __restrict__ ptr_copy, int2* __restrict__ se)
{
    const int e = blockIdx.x * blockDim.x + threadIdx.x;
    if (e >= N_EDGES) return;
    const int d = dst[e];
    const int pos = atomicAdd(&ptr_copy[d], 1);
    se[pos] = make_int2(src[e], etype[e]);
}

// ===== fused per-node GAT aggregate; own-head math only =====
// hb: bf16 [n][512]. Lane l covers cols l*8..l*8+7, head = l>>4 — each lane
// computes exp/denominator for ITS head only (shfl_xor(16,32) sums heads).
__global__ __launch_bounds__(256) void node_agg_kernel(
    const int* __restrict__ ptr, const int2* __restrict__ se,
    const float* __restrict__ a_s, const float* __restrict__ a_d,
    const float* __restrict__ table, const ushort_t* __restrict__ hb,
    const float* __restrict__ bias,
    float* __restrict__ outf, ushort_t* __restrict__ oa)
{
    const int n = blockIdx.x * 4 + (threadIdx.x >> 6);
    const int lane = threadIdx.x & 63;
    if (n >= N_NODES) return;
    const int beg = ptr[n], end = ptr[n + 1];
    const int head = lane >> 4;
    const int cbase = lane * 8;
    const float adh = a_d[n * 4 + head];

    float acc[8] = {};
    float dh = 0.f, eh = 0.f;

    int j = beg;
    for (; j + 2 <= end; j += 2) {
        const int2 E0 = se[j], E1 = se[j + 1];
        const uint4 g0 = *(const uint4*)(hb + (size_t)E0.x * 512 + cbase);
        const uint4 g1 = *(const uint4*)(hb + (size_t)E1.x * 512 + cbase);
        const float a0 = a_s[E0.x * 4 + head];
        const float t0 = table[E0.y * 4 + head];
        const float a1 = a_s[E1.x * 4 + head];
        const float t1 = table[E1.y * 4 + head];
        const float p0 = __expf(lrelu02(a0 + adh + t0));
        const float p1 = __expf(lrelu02(a1 + adh + t1));
        eh += t0 + t1;
        dh += p0 + p1;
        acc[0] += p0 * bfl(g0.x) + p1 * bfl(g1.x);
        acc[1] += p0 * bfh(g0.x) + p1 * bfh(g1.x);
        acc[2] += p0 * bfl(g0.y) + p1 * bfl(g1.y);
        acc[3] += p0 * bfh(g0.y) + p1 * bfh(g1.y);
        acc[4] += p0 * bfl(g0.z) + p1 * bfl(g1.z);
        acc[5] += p0 * bfh(g0.z) + p1 * bfh(g1.z);
        acc[6] += p0 * bfl(g0.w) + p1 * bfl(g1.w);
        acc[7] += p0 * bfh(g0.w) + p1 * bfh(g1.w);
    }
    if (j < end) {
        const int2 E0 = se[j];
        const uint4 g0 = *(const uint4*)(hb + (size_t)E0.x * 512 + cbase);
        const float a0 = a_s[E0.x * 4 + head];
        const float t0 = table[E0.y * 4 + head];
        const float p0 = __expf(lrelu02(a0 + adh + t0));
        eh += t0;
        dh += p0;
        acc[0] += p0 * bfl(g0.x); acc[1] += p0 * bfh(g0.x);
        acc[2] += p0 * bfl(g0.y); acc[3] += p0 * bfh(g0.y);
        acc[4] += p0 * bfl(g0.z); acc[5] += p0 * bfh(g0.z);
        acc[6] += p0 * bfl(g0.w); acc[7] += p0 * bfh(g0.w);
    }

    // self-loop (fill_value='mean')
    const float inv = 1.0f / fmaxf((float)(end - beg), 1.0f);
    const float ps = __expf(lrelu02(a_s[n * 4 + head] + adh + eh * inv));
    dh += ps;
    {
        const uint4 gs = *(const uint4*)(hb + (size_t)n * 512 + cbase);
        acc[0] += ps * bfl(gs.x); acc[1] += ps * bfh(gs.x);
        acc[2] += ps * bfl(gs.y); acc[3] += ps * bfh(gs.y);
        acc[4] += ps * bfl(gs.z); acc[5] += ps * bfh(gs.z);
        acc[6] += ps * bfl(gs.w); acc[7] += ps * bfh(gs.w);
    }

    const float ih = 0.25f / (dh + 1e-16f);
    float t[8];
    #pragma unroll
    for (int k = 0; k < 8; ++k) {
        t[k] = acc[k] * ih;
        t[k] += __shfl_xor(t[k], 16);
        t[k] += __shfl_xor(t[k], 32);
    }
    if (lane < 16) {
        const float4 b0 = *(const float4*)(bias + cbase);
        const float4 b1 = *(const float4*)(bias + cbase + 4);
        float o[8];
        o[0] = fmaxf(t[0] + b0.x, 0.f); o[1] = fmaxf(t[1] + b0.y, 0.f);
        o[2] = fmaxf(t[2] + b0.z, 0.f); o[3] = fmaxf(t[3] + b0.w, 0.f);
        o[4] = fmaxf(t[4] + b1.x, 0.f); o[5] = fmaxf(t[5] + b1.y, 0.f);
        o[6] = fmaxf(t[6] + b1.z, 0.f); o[7] = fmaxf(t[7] + b1.w, 0.f);
        if (outf) {
            float4 v0 = {o[0], o[1], o[2], o[3]};
            float4 v1 = {o[4], o[5], o[6], o[7]};
            *(float4*)(outf + (size_t)n * DIM + cbase) = v0;
            *(float4*)(outf + (size_t)n * DIM + cbase + 4) = v1;
        }
        if (oa) {
            // A-layout [c>>3][n][c&7]: c>>3 == lane -> one contiguous uint4
            unsigned int up[4];
            #pragma unroll
            for (int i = 0; i < 4; ++i)
                up[i] = (rnd16(o[2*i+1]) << 16) | rnd16(o[2*i]);
            *(uint4*)(oa + ((size_t)lane * MP + n) * 8) = make_uint4(up[0], up[1], up[2], up[3]);
        }
    }
}

extern "C" void kernel_launch(void* const* d_in, const int* in_sizes, int n_in,
                              void* d_out, int out_size, void* d_ws, size_t ws_size,
                              hipStream_t stream)
{
    const float* x       = (const float*)d_in[0];
    const int*   eidx    = (const int*)d_in[1];
    const int*   etype   = (const int*)d_in[2];
    const float* w1      = (const float*)d_in[3];
    const float* b1      = (const float*)d_in[4];
    const float* w2      = (const float*)d_in[5];
    const float* b2      = (const float*)d_in[6];
    const float* rel_emb = (const float*)d_in[7];
    const float* lin[2]  = {(const float*)d_in[8],  (const float*)d_in[14]};
    const float* line[2] = {(const float*)d_in[9],  (const float*)d_in[15]};
    const float* atts[2] = {(const float*)d_in[10], (const float*)d_in[16]};
    const float* attd[2] = {(const float*)d_in[11], (const float*)d_in[17]};
    const float* atte[2] = {(const float*)d_in[12], (const float*)d_in[18]};
    const float* bias[2] = {(const float*)d_in[13], (const float*)d_in[19]};
    const int* src = eidx;
    const int* dst = eidx + N_EDGES;

    // ---- workspace layout ----
    char* base = (char*)d_ws;
    size_t off = 0;
    auto alloc = [&](size_t bytes) -> void* {
        void* p = base + off;
        off = (off + bytes + 255) & ~(size_t)255;
        return p;
    };
    ushort_t* xh  = (ushort_t*)alloc((size_t)68 * MP * 8 * 2);  // hb overlays (dead after enc1)
    ushort_t* xl  = (ushort_t*)alloc((size_t)68 * MP * 8 * 2);
    ushort_t* h1h = (ushort_t*)alloc((size_t)32 * MP * 8 * 2);  // xbuf1 overlays (dead after enc2)
    ushort_t* h1l = (ushort_t*)alloc((size_t)32 * MP * 8 * 2);
    ushort_t* x0a = (ushort_t*)alloc((size_t)16 * MP * 8 * 2);
    void* reg1    = alloc((size_t)16 * MP * 8 * 4);             // xbuf0 fp32 | x1a
    ushort_t* w1h = (ushort_t*)alloc(68 * 256 * 8 * 2);
    ushort_t* w1l = (ushort_t*)alloc(68 * 256 * 8 * 2);
    ushort_t* w2h = (ushort_t*)alloc(32 * 128 * 8 * 2);
    ushort_t* w2l = (ushort_t*)alloc(32 * 128 * 8 * 2);
    ushort_t* l0h = (ushort_t*)alloc(16 * 512 * 8 * 2);
    ushort_t* l0l = (ushort_t*)alloc(16 * 512 * 8 * 2);
    ushort_t* l1h = (ushort_t*)alloc(16 * 512 * 8 * 2);
    ushort_t* l1l = (ushort_t*)alloc(16 * 512 * 8 * 2);
    float* a_s   = (float*)alloc(N_NODES * 4 * 4);
    float* a_d   = (float*)alloc(N_NODES * 4 * 4);
    float* table = (float*)alloc(128 * 4);
    float* wa_s  = (float*)alloc(512 * 4);
    float* wa_d  = (float*)alloc(512 * 4);
    int*  cnt_i  = (int*)alloc(N_NODES * 4);
    int*  ptr    = (int*)alloc((N_NODES + 4) * 4);
    int*  ptrc   = (int*)alloc(N_NODES * 4);
    int2* se     = (int2*)alloc((size_t)N_EDGES * 8);

    ushort_t* hb = xh;              // bf16 hfeat [MP][512], 20.5 MB (xh dead after enc1)
    float* xbuf1 = (float*)h1h;     // node_agg L0 fp32 out (h1 dead after enc2)
    float* xbuf0 = (float*)reg1;
    ushort_t* x1a = (ushort_t*)reg1;  // node_agg L0 bf16 A-layout out (xbuf0 dead after as_ad L0)

    const int mtiles = MP / 64;     // 313

    // ---- input conversions ----
    conv_a_t_kernel<<<dim3(MP / 64, 9), 256, 0, stream>>>(x, xh, xl);
    conv_b_kernel<<<(68*256*8 + 255) / 256, 256, 0, stream>>>(w1, w1h, w1l, F_IN, HIDDEN, 68*256*8);
    conv_b_kernel<<<(32*128*8 + 255) / 256, 256, 0, stream>>>(w2, w2h, w2l, HIDDEN, DIM, 32*128*8);
    conv_b_kernel<<<(16*512*8 + 255) / 256, 256, 0, stream>>>(lin[0], l0h, l0l, DIM, NH*DIM, 16*512*8);
    conv_b_kernel<<<(16*512*8 + 255) / 256, 256, 0, stream>>>(lin[1], l1h, l1l, DIM, NH*DIM, 16*512*8);

    // ---- CSR build ----
    hipMemsetAsync(cnt_i, 0, N_NODES * sizeof(int), stream);
    hist_kernel<<<(N_EDGES + 255) / 256, 256, 0, stream>>>(dst, cnt_i);
    scan_kernel<<<1, 1024, 0, stream>>>(cnt_i, ptr, ptrc);
    scatter_kernel<<<(N_EDGES + 255) / 256, 256, 0, stream>>>(src, dst, etype, ptrc, se);

    // ---- node encoder (3-term split) ----
    gemm_mfma_v2<<<dim3(HIDDEN / 128, mtiles), 256, 0, stream>>>(
        xh, xl, w1h, w1l, b1, N_NODES, 68, HIDDEN, 1, nullptr, h1h, h1l, nullptr, nullptr);
    gemm_mfma_v2<<<dim3(DIM / 128, mtiles), 256, 0, stream>>>(
        h1h, h1l, w2h, w2l, b2, N_NODES, 32, DIM, 0, xbuf0, nullptr, nullptr, nullptr, x0a);

    // ---- layer 0 (2-term: A quantized bf16) ----
    gemm_mfma_v2<<<dim3((NH * DIM) / 128, mtiles), 256, 0, stream>>>(
        x0a, nullptr, l0h, l0l, nullptr, N_NODES, 16, NH * DIM, 0, nullptr, nullptr, nullptr, hb, nullptr);
    wa_kernel<<<4, 256, 0, stream>>>(lin[0], atts[0], attd[0], wa_s, wa_d);
    as_ad_kernel<<<N_NODES, 256, 0, stream>>>(xbuf0, wa_s, wa_d, a_s, a_d);
    rel_table_kernel<<<1, 128, 0, stream>>>(rel_emb, line[0], atte[0], table);
    node_agg_kernel<<<(N_NODES + 3) / 4, 256, 0, stream>>>(
        ptr, se, a_s, a_d, table, hb, bias[0], xbuf1, x1a);

    // ---- layer 1 (2-term) ----
    gemm_mfma_v2<<<dim3((NH * DIM) / 128, mtiles), 256, 0, stream>>>(
        x1a, nullptr, l1h, l1l, nullptr, N_NODES, 16, NH * DIM, 0, nullptr, nullptr, nullptr, hb, nullptr);
    wa_kernel<<<4, 256, 0, stream>>>(lin[1], atts[1], attd[1], wa_s, wa_d);
    as_ad_kernel<<<N_NODES, 256, 0, stream>>>(xbuf1, wa_s, wa_d, a_s, a_d);
    rel_table_kernel<<<1, 128, 0, stream>>>(rel_emb, line[1], atte[1], table);
    node_agg_kernel<<<(N_NODES + 3) / 4, 256, 0, stream>>>(
        ptr, se, a_s, a_d, table, hb, bias[1], (float*)d_out, nullptr);
}

// Round 10
// 440.238 us; speedup vs baseline: 1.6199x; 1.0094x over previous
//
#include <hip/hip_runtime.h>
#include <math.h>

#define N_NODES 20000
#define MP      20032          // M padded to 64
#define N_EDGES 320000
#define F_IN    518
#define HIDDEN  256
#define DIM     128
#define NH      4

typedef __attribute__((ext_vector_type(8))) short bf16x8;
typedef __attribute__((ext_vector_type(4))) float f32x4;
typedef unsigned short ushort_t;

__device__ __forceinline__ float lrelu02(float x) { return x > 0.f ? x : 0.2f * x; }

__device__ __forceinline__ void gl_lds16(const void* g, void* l) {
    __builtin_amdgcn_global_load_lds(
        (const __attribute__((address_space(1))) unsigned int*)g,
        (__attribute__((address_space(3))) unsigned int*)l, 16, 0, 0);
}

__device__ __forceinline__ unsigned int hi16(float v) { return __float_as_uint(v) >> 16; }
__device__ __forceinline__ unsigned int lo16(float v) {
    unsigned int h = __float_as_uint(v) & 0xFFFF0000u;
    return __float_as_uint(v - __uint_as_float(h)) >> 16;
}
// round-to-nearest-even bf16
__device__ __forceinline__ unsigned int rnd16(float v) {
    unsigned int u = __float_as_uint(v);
    return (u + 0x7FFFu + ((u >> 16) & 1u)) >> 16;
}
__device__ __forceinline__ float bfl(unsigned int u) { return __uint_as_float(u << 16); }
__device__ __forceinline__ float bfh(unsigned int u) { return __uint_as_float(u & 0xFFFF0000u); }

// ====== split-bf16 MFMA GEMM, operands pre-split, k-chunk-major ======
// A: [K8][MP][8] bf16 hi (+lo optional). B: [K8][N][8] bf16 hi/lo.
// Al != null: C = Ah*Bh + Ah*Bl + Al*Bh (3-term fp32-split).
// Al == null: C = Ah*Bh + Ah*Bl (A already quantized; exact in A).
// Tile 64x128, 4 waves; LDS 24KB; conflict-free ds_read_b128; global_load_lds x16.
__global__ __launch_bounds__(256, 4) void gemm_mfma_v2(
    const ushort_t* __restrict__ Ah, const ushort_t* __restrict__ Al,
    const ushort_t* __restrict__ Bh, const ushort_t* __restrict__ Bl,
    const float* __restrict__ bias,
    int M, int K8, int N, int act,
    float* __restrict__ Cf,                                      // fp32 [M][N]
    ushort_t* __restrict__ Ch, ushort_t* __restrict__ Cl,        // split A-layout
    ushort_t* __restrict__ Cb,                                   // plain bf16 [M][N]
    ushort_t* __restrict__ Ca)                                   // plain bf16 A-layout
{
    __shared__ __align__(16) ushort_t lds[12288];
    const int tid = threadIdx.x;
    const int w = tid >> 6, lane = tid & 63;
    const int row0 = blockIdx.y * 64, col0 = blockIdx.x * 128;
    const int nkb = K8 >> 2;
    const int m16 = lane & 15, q = lane >> 4;
    const bool use_al = (Al != nullptr);

    f32x4 acc[4][2] = {};

    for (int kb = 0; kb < nkb; ++kb) {
        const size_t kc = (size_t)(kb * 4 + w);
        const size_t aoff = (kc * MP + row0) * 8 + lane * 8;
        const size_t boff = (kc * N + col0) * 8 + lane * 8;
        gl_lds16(Ah + aoff, &lds[w * 512]);
        if (use_al) gl_lds16(Al + aoff, &lds[2048 + w * 512]);
        gl_lds16(Bh + boff,       &lds[4096 + w * 1024]);
        gl_lds16(Bh + boff + 512, &lds[4096 + w * 1024 + 512]);
        gl_lds16(Bl + boff,       &lds[8192 + w * 1024]);
        gl_lds16(Bl + boff + 512, &lds[8192 + w * 1024 + 512]);
        __syncthreads();

        bf16x8 fah[4], fal[4], fbh[2], fbl[2];
        const int fa = q * 512 + m16 * 8;
        #pragma unroll
        for (int mi = 0; mi < 4; ++mi) {
            fah[mi] = *(const bf16x8*)&lds[fa + mi * 128];
            if (use_al) fal[mi] = *(const bf16x8*)&lds[2048 + fa + mi * 128];
        }
        const int fb = q * 1024 + (w * 32 + m16) * 8;
        #pragma unroll
        for (int ni = 0; ni < 2; ++ni) {
            fbh[ni] = *(const bf16x8*)&lds[4096 + fb + ni * 128];
            fbl[ni] = *(const bf16x8*)&lds[8192 + fb + ni * 128];
        }
        #pragma unroll
        for (int mi = 0; mi < 4; ++mi)
            #pragma unroll
            for (int ni = 0; ni < 2; ++ni) {
                acc[mi][ni] = __builtin_amdgcn_mfma_f32_16x16x32_bf16(fah[mi], fbh[ni], acc[mi][ni], 0, 0, 0);
                acc[mi][ni] = __builtin_amdgcn_mfma_f32_16x16x32_bf16(fah[mi], fbl[ni], acc[mi][ni], 0, 0, 0);
            }
        if (use_al) {
            #pragma unroll
            for (int mi = 0; mi < 4; ++mi)
                #pragma unroll
                for (int ni = 0; ni < 2; ++ni)
                    acc[mi][ni] = __builtin_amdgcn_mfma_f32_16x16x32_bf16(fal[mi], fbh[ni], acc[mi][ni], 0, 0, 0);
        }
        __syncthreads();
    }

    // epilogue: C/D row=(lane>>4)*4+reg, col=lane&15
    #pragma unroll
    for (int ni = 0; ni < 2; ++ni) {
        const int col = col0 + w * 32 + ni * 16 + m16;
        const float bb = bias ? bias[col] : 0.f;
        #pragma unroll
        for (int mi = 0; mi < 4; ++mi) {
            #pragma unroll
            for (int r = 0; r < 4; ++r) {
                const int row = row0 + mi * 16 + q * 4 + r;
                if (row < M) {
                    float v = acc[mi][ni][r] + bb;
                    if (act) v = fmaxf(v, 0.f);
                    if (Cf) Cf[(size_t)row * N + col] = v;
                    if (Cb) Cb[(size_t)row * N + col] = (ushort_t)rnd16(v);
                    const size_t p = (((size_t)(col >> 3)) * MP + row) * 8 + (col & 7);
                    if (Ch) { Ch[p] = (ushort_t)hi16(v); Cl[p] = (ushort_t)lo16(v); }
                    if (Ca) Ca[p] = (ushort_t)rnd16(v);
                }
            }
        }
    }
}

// ---- x fp32 [N_NODES][F_IN] -> xh/xl bf16 [K8][MP][8], coalesced via LDS tile ----
__global__ __launch_bounds__(256) void conv_a_t_kernel(
    const float* __restrict__ x, ushort_t* __restrict__ xh, ushort_t* __restrict__ xl)
{
    __shared__ float tile[64][68];
    const int tid = threadIdx.x;
    const int r0 = blockIdx.x * 64;
    const int c0 = blockIdx.y * 64;

    #pragma unroll
    for (int it = 0; it < 4; ++it) {
        const int r = (tid >> 4) + it * 16;
        const int c = (tid & 15) * 4;
        const int gr = r0 + r, gc = c0 + c;
        float4 v = {0.f, 0.f, 0.f, 0.f};
        if (gr < N_NODES) {
            if (gc + 3 < F_IN) {
                v = *(const float4*)(x + (size_t)gr * F_IN + gc);
            } else {
                float tmp[4] = {0.f, 0.f, 0.f, 0.f};
                #pragma unroll
                for (int u = 0; u < 4; ++u)
                    if (gc + u < F_IN) tmp[u] = x[(size_t)gr * F_IN + gc + u];
                v.x = tmp[0]; v.y = tmp[1]; v.z = tmp[2]; v.w = tmp[3];
            }
        }
        tile[r][c] = v.x; tile[r][c+1] = v.y; tile[r][c+2] = v.z; tile[r][c+3] = v.w;
    }
    __syncthreads();

    const int k8l = tid >> 5;           // 0..7
    const int k8 = (c0 >> 3) + k8l;
    if (k8 >= 68) return;
    const int rr = (tid & 31) * 2;
    #pragma unroll
    for (int u = 0; u < 2; ++u) {
        const int r = rr + u;
        unsigned int hp[4], lp[4];
        #pragma unroll
        for (int i = 0; i < 4; ++i) {
            const float v0 = tile[r][k8l * 8 + 2 * i];
            const float v1 = tile[r][k8l * 8 + 2 * i + 1];
            hp[i] = (hi16(v1) << 16) | hi16(v0);
            lp[i] = (lo16(v1) << 16) | lo16(v0);
        }
        const size_t p = ((size_t)k8 * MP + r0 + r) * 8;
        *(uint4*)(xh + p) = make_uint4(hp[0], hp[1], hp[2], hp[3]);
        *(uint4*)(xl + p) = make_uint4(lp[0], lp[1], lp[2], lp[3]);
    }
}

// ---- weight w[K][N] fp32 -> bh/bl bf16 [K8][N][8] ----
__global__ __launch_bounds__(256) void conv_b_kernel(
    const float* __restrict__ w, ushort_t* __restrict__ bh, ushort_t* __restrict__ bl,
    int K, int N, int total)
{
    const int idx = blockIdx.x * 256 + threadIdx.x;
    if (idx >= total) return;
    const int j = idx & 7;
    const int rem = idx >> 3;
    const int n = rem % N;
    const int k = (rem / N) * 8 + j;
    const float v = (k < K) ? w[(size_t)k * N + n] : 0.f;
    bh[idx] = (ushort_t)hi16(v);
    bl[idx] = (ushort_t)lo16(v);
}

// ---- wa_s/wa_d [H][D]: folded lin @ att ----
__global__ __launch_bounds__(256) void wa_kernel(
    const float* __restrict__ lin, const float* __restrict__ atts,
    const float* __restrict__ attd, float* __restrict__ wa_s, float* __restrict__ wa_d)
{
    const int wrk = blockIdx.x * 256 + threadIdx.x;
    if (wrk >= 1024) return;
    const int sd = wrk >> 9;
    const int p = wrk & 511;
    const int h = p >> 7, d = p & 127;
    const float* av = (sd ? attd : atts) + h * DIM;
    const float* lp = lin + (size_t)d * (NH * DIM) + h * DIM;
    float acc = 0.f;
    #pragma unroll 8
    for (int i = 0; i < DIM; ++i) acc += lp[i] * av[i];
    (sd ? wa_d : wa_s)[h * DIM + d] = acc;
}

// ---- a_s[n,h], a_d[n,h] from xbuf (fp32 [N][128]) ----
__global__ __launch_bounds__(256) void as_ad_kernel(
    const float* __restrict__ xb, const float* __restrict__ wa_s,
    const float* __restrict__ wa_d, float* __restrict__ a_s, float* __restrict__ a_d)
{
    const int gw = blockIdx.x * 4 + (threadIdx.x >> 6);
    const int lane = threadIdx.x & 63;
    if (gw >= N_NODES * NH) return;
    const int n = gw >> 2, h = gw & 3;
    const float* hp = xb + (size_t)n * DIM;
    float2 hv = *(const float2*)(hp + lane * 2);
    float2 sv = *(const float2*)(wa_s + h * DIM + lane * 2);
    float2 dv = *(const float2*)(wa_d + h * DIM + lane * 2);
    float s = hv.x * sv.x + hv.y * sv.y;
    float d = hv.x * dv.x + hv.y * dv.y;
    #pragma unroll
    for (int off = 32; off > 0; off >>= 1) {
        s += __shfl_down(s, off);
        d += __shfl_down(d, off);
    }
    if (lane == 0) { a_s[n * 4 + h] = s; a_d[n * 4 + h] = d; }
}

// ---- rel attention table[r,h] ----
__global__ __launch_bounds__(128) void rel_table_kernel(
    const float* __restrict__ rel_emb, const float* __restrict__ line,
    const float* __restrict__ atte, float* __restrict__ table)
{
    __shared__ float we[32][NH];
    const int tid = threadIdx.x;
    const int k = tid >> 2, h = tid & 3;
    float acc = 0.f;
    for (int d = 0; d < DIM; ++d)
        acc += line[(size_t)k * (NH * DIM) + h * DIM + d] * atte[h * DIM + d];
    we[k][h] = acc;
    __syncthreads();
    if (tid < 26 * NH) {
        int r = tid >> 2, hh = tid & 3;
        float t = 0.f;
        for (int kk = 0; kk < 32; ++kk) t += rel_emb[r * 32 + kk] * we[kk][hh];
        table[r * 4 + hh] = t;
    }
}

// ================= CSR build =================
__global__ __launch_bounds__(256) void hist_kernel(
    const int* __restrict__ dst, int* __restrict__ cnt)
{
    const int e = blockIdx.x * blockDim.x + threadIdx.x;
    if (e >= N_EDGES) return;
    atomicAdd(&cnt[dst[e]], 1);
}

__global__ __launch_bounds__(1024) void scan_kernel(
    const int* __restrict__ cnt, int* __restrict__ ptr, int* __restrict__ ptr_copy)
{
    __shared__ int tsum[1024];
    const int tid = threadIdx.x;
    const int CH = 20;
    const int base = tid * CH;
    int s = 0;
    #pragma unroll
    for (int i = 0; i < CH; ++i) {
        int idx = base + i;
        if (idx < N_NODES) s += cnt[idx];
    }
    tsum[tid] = s;
    __syncthreads();
    for (int off = 1; off < 1024; off <<= 1) {
        int v = (tid >= off) ? tsum[tid - off] : 0;
        __syncthreads();
        tsum[tid] += v;
        __syncthreads();
    }
    int run = (tid == 0) ? 0 : tsum[tid - 1];
    #pragma unroll
    for (int i = 0; i < CH; ++i) {
        int idx = base + i;
        if (idx < N_NODES) {
            ptr[idx] = run;
            ptr_copy[idx] = run;
            run += cnt[idx];
        }
    }
    if (tid == 0) ptr[N_NODES] = N_EDGES;
}

__global__ __launch_bounds__(256) void scatter_kernel(
    const int* __restrict__ src, const int* __restrict__ dst, const int* __restrict__ etype,
    int* __restrict__ ptr_copy, int2* __restrict__ se)
{
    const int e = blockIdx.x * blockDim.x + threadIdx.x;
    if (e >= N_EDGES) return;
    const int d = dst[e];
    const int pos = atomicAdd(&ptr_copy[d], 1);
    se[pos] = make_int2(src[e], etype[e]);
}

// ===== fused per-node GAT aggregate; own-head math; x4 edge unroll =====
// hb: bf16 [n][512]. Lane l covers cols l*8..l*8+7, head = l>>4.
// Optionally computes next layer's a_s/a_d from the output row in-register.
__global__ __launch_bounds__(256) void node_agg_kernel(
    const int* __restrict__ ptr, const int2* __restrict__ se,
    const float* __restrict__ a_s, const float* __restrict__ a_d,
    const float* __restrict__ table, const ushort_t* __restrict__ hb,
    const float* __restrict__ bias,
    float* __restrict__ outf, ushort_t* __restrict__ oa,
    const float* __restrict__ wa_s2, const float* __restrict__ wa_d2,
    float* __restrict__ a_s2, float* __restrict__ a_d2)
{
    const int n = blockIdx.x * 4 + (threadIdx.x >> 6);
    const int lane = threadIdx.x & 63;
    if (n >= N_NODES) return;
    const int beg = ptr[n], end = ptr[n + 1];
    const int head = lane >> 4;
    const int cbase = lane * 8;
    const float adh = a_d[n * 4 + head];

    float acc[8] = {};
    float dh = 0.f, eh = 0.f;

    int j = beg;
    for (; j + 4 <= end; j += 4) {
        int2 E[4];
        E[0] = se[j]; E[1] = se[j + 1]; E[2] = se[j + 2]; E[3] = se[j + 3];
        uint4 g[4];
        float av[4], tv[4];
        #pragma unroll
        for (int u = 0; u < 4; ++u) {
            g[u] = *(const uint4*)(hb + (size_t)E[u].x * 512 + cbase);
            av[u] = a_s[E[u].x * 4 + head];
            tv[u] = table[E[u].y * 4 + head];
        }
        #pragma unroll
        for (int u = 0; u < 4; ++u) {
            const float p = __expf(lrelu02(av[u] + adh + tv[u]));
            eh += tv[u]; dh += p;
            acc[0] += p * bfl(g[u].x); acc[1] += p * bfh(g[u].x);
            acc[2] += p * bfl(g[u].y); acc[3] += p * bfh(g[u].y);
            acc[4] += p * bfl(g[u].z); acc[5] += p * bfh(g[u].z);
            acc[6] += p * bfl(g[u].w); acc[7] += p * bfh(g[u].w);
        }
    }
    for (; j < end; ++j) {
        const int2 E0 = se[j];
        const uint4 g0 = *(const uint4*)(hb + (size_t)E0.x * 512 + cbase);
        const float a0 = a_s[E0.x * 4 + head];
        const float t0 = table[E0.y * 4 + head];
        const float p0 = __expf(lrelu02(a0 + adh + t0));
        eh += t0; dh += p0;
        acc[0] += p0 * bfl(g0.x); acc[1] += p0 * bfh(g0.x);
        acc[2] += p0 * bfl(g0.y); acc[3] += p0 * bfh(g0.y);
        acc[4] += p0 * bfl(g0.z); acc[5] += p0 * bfh(g0.z);
        acc[6] += p0 * bfl(g0.w); acc[7] += p0 * bfh(g0.w);
    }

    // self-loop (fill_value='mean')
    const float inv = 1.0f / fmaxf((float)(end - beg), 1.0f);
    const float ps = __expf(lrelu02(a_s[n * 4 + head] + adh + eh * inv));
    dh += ps;
    {
        const uint4 gs = *(const uint4*)(hb + (size_t)n * 512 + cbase);
        acc[0] += ps * bfl(gs.x); acc[1] += ps * bfh(gs.x);
        acc[2] += ps * bfl(gs.y); acc[3] += ps * bfh(gs.y);
        acc[4] += ps * bfl(gs.z); acc[5] += ps * bfh(gs.z);
        acc[6] += ps * bfl(gs.w); acc[7] += ps * bfh(gs.w);
    }

    const float ih = 0.25f / (dh + 1e-16f);
    float t[8];
    #pragma unroll
    for (int k = 0; k < 8; ++k) {
        t[k] = acc[k] * ih;
        t[k] += __shfl_xor(t[k], 16);
        t[k] += __shfl_xor(t[k], 32);
    }
    if (lane < 16) {
        const float4 b0 = *(const float4*)(bias + cbase);
        const float4 b1 = *(const float4*)(bias + cbase + 4);
        float o[8];
        o[0] = fmaxf(t[0] + b0.x, 0.f); o[1] = fmaxf(t[1] + b0.y, 0.f);
        o[2] = fmaxf(t[2] + b0.z, 0.f); o[3] = fmaxf(t[3] + b0.w, 0.f);
        o[4] = fmaxf(t[4] + b1.x, 0.f); o[5] = fmaxf(t[5] + b1.y, 0.f);
        o[6] = fmaxf(t[6] + b1.z, 0.f); o[7] = fmaxf(t[7] + b1.w, 0.f);
        if (outf) {
            float4 v0 = {o[0], o[1], o[2], o[3]};
            float4 v1 = {o[4], o[5], o[6], o[7]};
            *(float4*)(outf + (size_t)n * DIM + cbase) = v0;
            *(float4*)(outf + (size_t)n * DIM + cbase + 4) = v1;
        }
        if (oa) {
            unsigned int up[4];
            #pragma unroll
            for (int i = 0; i < 4; ++i)
                up[i] = (rnd16(o[2*i+1]) << 16) | rnd16(o[2*i]);
            *(uint4*)(oa + ((size_t)lane * MP + n) * 8) = make_uint4(up[0], up[1], up[2], up[3]);
        }
        // fused next-layer a_s/a_d: per-head 128-dot over the output row
        if (wa_s2) {
            float pss[4] = {0,0,0,0}, pdd[4] = {0,0,0,0};
            #pragma unroll
            for (int h = 0; h < NH; ++h) {
                const float* ws = wa_s2 + h * DIM + cbase;
                const float* wd = wa_d2 + h * DIM + cbase;
                #pragma unroll
                for (int i = 0; i < 8; ++i) {
                    pss[h] += o[i] * ws[i];
                    pdd[h] += o[i] * wd[i];
                }
            }
            #pragma unroll
            for (int m = 1; m < 16; m <<= 1) {
                #pragma unroll
                for (int h = 0; h < NH; ++h) {
                    pss[h] += __shfl_xor(pss[h], m);
                    pdd[h] += __shfl_xor(pdd[h], m);
                }
            }
            if (lane == 0) {
                float4 vs = {pss[0], pss[1], pss[2], pss[3]};
                float4 vd = {pdd[0], pdd[1], pdd[2], pdd[3]};
                *(float4*)(a_s2 + n * 4) = vs;
                *(float4*)(a_d2 + n * 4) = vd;
            }
        }
    }
}

extern "C" void kernel_launch(void* const* d_in, const int* in_sizes, int n_in,
                              void* d_out, int out_size, void* d_ws, size_t ws_size,
                              hipStream_t stream)
{
    const float* x       = (const float*)d_in[0];
    const int*   eidx    = (const int*)d_in[1];
    const int*   etype   = (const int*)d_in[2];
    const float* w1      = (const float*)d_in[3];
    const float* b1      = (const float*)d_in[4];
    const float* w2      = (const float*)d_in[5];
    const float* b2      = (const float*)d_in[6];
    const float* rel_emb = (const float*)d_in[7];
    const float* lin[2]  = {(const float*)d_in[8],  (const float*)d_in[14]};
    const float* line[2] = {(const float*)d_in[9],  (const float*)d_in[15]};
    const float* atts[2] = {(const float*)d_in[10], (const float*)d_in[16]};
    const float* attd[2] = {(const float*)d_in[11], (const float*)d_in[17]};
    const float* atte[2] = {(const float*)d_in[12], (const float*)d_in[18]};
    const float* bias[2] = {(const float*)d_in[13], (const float*)d_in[19]};
    const int* src = eidx;
    const int* dst = eidx + N_EDGES;

    // ---- workspace layout ----
    char* base = (char*)d_ws;
    size_t off = 0;
    auto alloc = [&](size_t bytes) -> void* {
        void* p = base + off;
        off = (off + bytes + 255) & ~(size_t)255;
        return p;
    };
    ushort_t* xh  = (ushort_t*)alloc((size_t)68 * MP * 8 * 2);  // hb overlays (dead after enc1)
    ushort_t* xl  = (ushort_t*)alloc((size_t)68 * MP * 8 * 2);
    ushort_t* h1h = (ushort_t*)alloc((size_t)32 * MP * 8 * 2);
    ushort_t* h1l = (ushort_t*)alloc((size_t)32 * MP * 8 * 2);
    ushort_t* x0a = (ushort_t*)alloc((size_t)16 * MP * 8 * 2);
    void* reg1    = alloc((size_t)16 * MP * 8 * 4);             // xbuf0 fp32 | x1a
    ushort_t* w1h = (ushort_t*)alloc(68 * 256 * 8 * 2);
    ushort_t* w1l = (ushort_t*)alloc(68 * 256 * 8 * 2);
    ushort_t* w2h = (ushort_t*)alloc(32 * 128 * 8 * 2);
    ushort_t* w2l = (ushort_t*)alloc(32 * 128 * 8 * 2);
    ushort_t* l0h = (ushort_t*)alloc(16 * 512 * 8 * 2);
    ushort_t* l0l = (ushort_t*)alloc(16 * 512 * 8 * 2);
    ushort_t* l1h = (ushort_t*)alloc(16 * 512 * 8 * 2);
    ushort_t* l1l = (ushort_t*)alloc(16 * 512 * 8 * 2);
    float* a_s0  = (float*)alloc(N_NODES * 4 * 4);
    float* a_d0  = (float*)alloc(N_NODES * 4 * 4);
    float* a_s1  = (float*)alloc(N_NODES * 4 * 4);
    float* a_d1  = (float*)alloc(N_NODES * 4 * 4);
    float* table = (float*)alloc(128 * 4);
    float* wa_s0 = (float*)alloc(512 * 4);
    float* wa_d0 = (float*)alloc(512 * 4);
    float* wa_s1 = (float*)alloc(512 * 4);
    float* wa_d1 = (float*)alloc(512 * 4);
    int*  cnt_i  = (int*)alloc(N_NODES * 4);
    int*  ptr    = (int*)alloc((N_NODES + 4) * 4);
    int*  ptrc   = (int*)alloc(N_NODES * 4);
    int2* se     = (int2*)alloc((size_t)N_EDGES * 8);

    ushort_t* hb = xh;              // bf16 hfeat [MP][512], 20.5 MB (xh dead after enc1)
    float* xbuf0 = (float*)reg1;
    ushort_t* x1a = (ushort_t*)reg1;  // node_agg L0 bf16 A-layout out (xbuf0 dead after as_ad L0)

    const int mtiles = MP / 64;     // 313

    // ---- input conversions ----
    conv_a_t_kernel<<<dim3(MP / 64, 9), 256, 0, stream>>>(x, xh, xl);
    conv_b_kernel<<<(68*256*8 + 255) / 256, 256, 0, stream>>>(w1, w1h, w1l, F_IN, HIDDEN, 68*256*8);
    conv_b_kernel<<<(32*128*8 + 255) / 256, 256, 0, stream>>>(w2, w2h, w2l, HIDDEN, DIM, 32*128*8);
    conv_b_kernel<<<(16*512*8 + 255) / 256, 256, 0, stream>>>(lin[0], l0h, l0l, DIM, NH*DIM, 16*512*8);
    conv_b_kernel<<<(16*512*8 + 255) / 256, 256, 0, stream>>>(lin[1], l1h, l1l, DIM, NH*DIM, 16*512*8);
    wa_kernel<<<4, 256, 0, stream>>>(lin[0], atts[0], attd[0], wa_s0, wa_d0);
    wa_kernel<<<4, 256, 0, stream>>>(lin[1], atts[1], attd[1], wa_s1, wa_d1);

    // ---- CSR build ----
    hipMemsetAsync(cnt_i, 0, N_NODES * sizeof(int), stream);
    hist_kernel<<<(N_EDGES + 255) / 256, 256, 0, stream>>>(dst, cnt_i);
    scan_kernel<<<1, 1024, 0, stream>>>(cnt_i, ptr, ptrc);
    scatter_kernel<<<(N_EDGES + 255) / 256, 256, 0, stream>>>(src, dst, etype, ptrc, se);

    // ---- node encoder (3-term split) ----
    gemm_mfma_v2<<<dim3(HIDDEN / 128, mtiles), 256, 0, stream>>>(
        xh, xl, w1h, w1l, b1, N_NODES, 68, HIDDEN, 1, nullptr, h1h, h1l, nullptr, nullptr);
    gemm_mfma_v2<<<dim3(DIM / 128, mtiles), 256, 0, stream>>>(
        h1h, h1l, w2h, w2l, b2, N_NODES, 32, DIM, 0, xbuf0, nullptr, nullptr, nullptr, x0a);

    // ---- layer 0 (2-term: A quantized bf16) ----
    gemm_mfma_v2<<<dim3((NH * DIM) / 128, mtiles), 256, 0, stream>>>(
        x0a, nullptr, l0h, l0l, nullptr, N_NODES, 16, NH * DIM, 0, nullptr, nullptr, nullptr, hb, nullptr);
    as_ad_kernel<<<N_NODES, 256, 0, stream>>>(xbuf0, wa_s0, wa_d0, a_s0, a_d0);
    rel_table_kernel<<<1, 128, 0, stream>>>(rel_emb, line[0], atte[0], table);
    node_agg_kernel<<<(N_NODES + 3) / 4, 256, 0, stream>>>(
        ptr, se, a_s0, a_d0, table, hb, bias[0], nullptr, x1a,
        wa_s1, wa_d1, a_s1, a_d1);

    // ---- layer 1 (2-term; a_s/a_d already computed by node_agg L0) ----
    gemm_mfma_v2<<<dim3((NH * DIM) / 128, mtiles), 256, 0, stream>>>(
        x1a, nullptr, l1h, l1l, nullptr, N_NODES, 16, NH * DIM, 0, nullptr, nullptr, nullptr, hb, nullptr);
    rel_table_kernel<<<1, 128, 0, stream>>>(rel_emb, line[1], atte[1], table);
    node_agg_kernel<<<(N_NODES + 3) / 4, 256, 0, stream>>>(
        ptr, se, a_s1, a_d1, table, hb, bias[1], (float*)d_out, nullptr,
        nullptr, nullptr, nullptr, nullptr);
}

// Round 11
// 425.957 us; speedup vs baseline: 1.6742x; 1.0335x over previous
//
#include <hip/hip_runtime.h>
#include <math.h>

#define N_NODES 20000
#define MP      20032          // M padded to 64
#define N_EDGES 320000
#define F_IN    518
#define HIDDEN  256
#define DIM     128
#define NH      4

typedef __attribute__((ext_vector_type(8))) short bf16x8;
typedef __attribute__((ext_vector_type(4))) float f32x4;
typedef unsigned short ushort_t;

__device__ __forceinline__ float lrelu02(float x) { return x > 0.f ? x : 0.2f * x; }

__device__ __forceinline__ void gl_lds16(const void* g, void* l) {
    __builtin_amdgcn_global_load_lds(
        (const __attribute__((address_space(1))) unsigned int*)g,
        (__attribute__((address_space(3))) unsigned int*)l, 16, 0, 0);
}

__device__ __forceinline__ unsigned int hi16(float v) { return __float_as_uint(v) >> 16; }
__device__ __forceinline__ unsigned int lo16(float v) {
    unsigned int h = __float_as_uint(v) & 0xFFFF0000u;
    return __float_as_uint(v - __uint_as_float(h)) >> 16;
}
// round-to-nearest-even bf16
__device__ __forceinline__ unsigned int rnd16(float v) {
    unsigned int u = __float_as_uint(v);
    return (u + 0x7FFFu + ((u >> 16) & 1u)) >> 16;
}
__device__ __forceinline__ float bfl(unsigned int u) { return __uint_as_float(u << 16); }
__device__ __forceinline__ float bfh(unsigned int u) { return __uint_as_float(u & 0xFFFF0000u); }

// ====== split-bf16 MFMA GEMM, operands pre-split, k-chunk-major ======
// A: [K8][MP][8] bf16 hi (+lo optional). B: [K8][N][8] bf16 hi/lo.
// Al != null: C = Ah*Bh + Ah*Bl + Al*Bh. Al == null: C = Ah*Bh + Ah*Bl.
__global__ __launch_bounds__(256, 4) void gemm_mfma_v2(
    const ushort_t* __restrict__ Ah, const ushort_t* __restrict__ Al,
    const ushort_t* __restrict__ Bh, const ushort_t* __restrict__ Bl,
    const float* __restrict__ bias,
    int M, int K8, int N, int act,
    float* __restrict__ Cf,                                      // fp32 [M][N]
    ushort_t* __restrict__ Ch, ushort_t* __restrict__ Cl,        // split A-layout
    ushort_t* __restrict__ Cb,                                   // plain bf16 [M][N]
    ushort_t* __restrict__ Ca)                                   // plain bf16 A-layout
{
    __shared__ __align__(16) ushort_t lds[12288];
    const int tid = threadIdx.x;
    const int w = tid >> 6, lane = tid & 63;
    const int row0 = blockIdx.y * 64, col0 = blockIdx.x * 128;
    const int nkb = K8 >> 2;
    const int m16 = lane & 15, q = lane >> 4;
    const bool use_al = (Al != nullptr);

    f32x4 acc[4][2] = {};

    for (int kb = 0; kb < nkb; ++kb) {
        const size_t kc = (size_t)(kb * 4 + w);
        const size_t aoff = (kc * MP + row0) * 8 + lane * 8;
        const size_t boff = (kc * N + col0) * 8 + lane * 8;
        gl_lds16(Ah + aoff, &lds[w * 512]);
        if (use_al) gl_lds16(Al + aoff, &lds[2048 + w * 512]);
        gl_lds16(Bh + boff,       &lds[4096 + w * 1024]);
        gl_lds16(Bh + boff + 512, &lds[4096 + w * 1024 + 512]);
        gl_lds16(Bl + boff,       &lds[8192 + w * 1024]);
        gl_lds16(Bl + boff + 512, &lds[8192 + w * 1024 + 512]);
        __syncthreads();

        bf16x8 fah[4], fal[4], fbh[2], fbl[2];
        const int fa = q * 512 + m16 * 8;
        #pragma unroll
        for (int mi = 0; mi < 4; ++mi) {
            fah[mi] = *(const bf16x8*)&lds[fa + mi * 128];
            if (use_al) fal[mi] = *(const bf16x8*)&lds[2048 + fa + mi * 128];
        }
        const int fb = q * 1024 + (w * 32 + m16) * 8;
        #pragma unroll
        for (int ni = 0; ni < 2; ++ni) {
            fbh[ni] = *(const bf16x8*)&lds[4096 + fb + ni * 128];
            fbl[ni] = *(const bf16x8*)&lds[8192 + fb + ni * 128];
        }
        #pragma unroll
        for (int mi = 0; mi < 4; ++mi)
            #pragma unroll
            for (int ni = 0; ni < 2; ++ni) {
                acc[mi][ni] = __builtin_amdgcn_mfma_f32_16x16x32_bf16(fah[mi], fbh[ni], acc[mi][ni], 0, 0, 0);
                acc[mi][ni] = __builtin_amdgcn_mfma_f32_16x16x32_bf16(fah[mi], fbl[ni], acc[mi][ni], 0, 0, 0);
            }
        if (use_al) {
            #pragma unroll
            for (int mi = 0; mi < 4; ++mi)
                #pragma unroll
                for (int ni = 0; ni < 2; ++ni)
                    acc[mi][ni] = __builtin_amdgcn_mfma_f32_16x16x32_bf16(fal[mi], fbh[ni], acc[mi][ni], 0, 0, 0);
        }
        __syncthreads();
    }

    // epilogue: C/D row=(lane>>4)*4+reg, col=lane&15
    #pragma unroll
    for (int ni = 0; ni < 2; ++ni) {
        const int col = col0 + w * 32 + ni * 16 + m16;
        const float bb = bias ? bias[col] : 0.f;
        #pragma unroll
        for (int mi = 0; mi < 4; ++mi) {
            #pragma unroll
            for (int r = 0; r < 4; ++r) {
                const int row = row0 + mi * 16 + q * 4 + r;
                if (row < M) {
                    float v = acc[mi][ni][r] + bb;
                    if (act) v = fmaxf(v, 0.f);
                    if (Cf) Cf[(size_t)row * N + col] = v;
                    if (Cb) Cb[(size_t)row * N + col] = (ushort_t)rnd16(v);
                    const size_t p = (((size_t)(col >> 3)) * MP + row) * 8 + (col & 7);
                    if (Ch) { Ch[p] = (ushort_t)hi16(v); Cl[p] = (ushort_t)lo16(v); }
                    if (Ca) Ca[p] = (ushort_t)rnd16(v);
                }
            }
        }
    }
}

// ---- x fp32 [N_NODES][F_IN] -> xh/xl bf16 [K8][MP][8], coalesced via LDS tile ----
__global__ __launch_bounds__(256) void conv_a_t_kernel(
    const float* __restrict__ x, ushort_t* __restrict__ xh, ushort_t* __restrict__ xl)
{
    __shared__ float tile[64][68];
    const int tid = threadIdx.x;
    const int r0 = blockIdx.x * 64;
    const int c0 = blockIdx.y * 64;

    #pragma unroll
    for (int it = 0; it < 4; ++it) {
        const int r = (tid >> 4) + it * 16;
        const int c = (tid & 15) * 4;
        const int gr = r0 + r, gc = c0 + c;
        float4 v = {0.f, 0.f, 0.f, 0.f};
        if (gr < N_NODES) {
            if (gc + 3 < F_IN) {
                v = *(const float4*)(x + (size_t)gr * F_IN + gc);
            } else {
                float tmp[4] = {0.f, 0.f, 0.f, 0.f};
                #pragma unroll
                for (int u = 0; u < 4; ++u)
                    if (gc + u < F_IN) tmp[u] = x[(size_t)gr * F_IN + gc + u];
                v.x = tmp[0]; v.y = tmp[1]; v.z = tmp[2]; v.w = tmp[3];
            }
        }
        tile[r][c] = v.x; tile[r][c+1] = v.y; tile[r][c+2] = v.z; tile[r][c+3] = v.w;
    }
    __syncthreads();

    const int k8l = tid >> 5;
    const int k8 = (c0 >> 3) + k8l;
    if (k8 >= 68) return;
    const int rr = (tid & 31) * 2;
    #pragma unroll
    for (int u = 0; u < 2; ++u) {
        const int r = rr + u;
        unsigned int hp[4], lp[4];
        #pragma unroll
        for (int i = 0; i < 4; ++i) {
            const float v0 = tile[r][k8l * 8 + 2 * i];
            const float v1 = tile[r][k8l * 8 + 2 * i + 1];
            hp[i] = (hi16(v1) << 16) | hi16(v0);
            lp[i] = (lo16(v1) << 16) | lo16(v0);
        }
        const size_t p = ((size_t)k8 * MP + r0 + r) * 8;
        *(uint4*)(xh + p) = make_uint4(hp[0], hp[1], hp[2], hp[3]);
        *(uint4*)(xl + p) = make_uint4(lp[0], lp[1], lp[2], lp[3]);
    }
}

// ---- all 4 weights fp32 -> bf16 hi/lo [K8][N][8] in ONE launch ----
#define W1_T (68 * 256 * 8)
#define W2_T (32 * 128 * 8)
#define L_T  (16 * 512 * 8)
__global__ __launch_bounds__(256) void conv_w_all_kernel(
    const float* __restrict__ w1, const float* __restrict__ w2,
    const float* __restrict__ l0, const float* __restrict__ l1,
    ushort_t* __restrict__ w1h, ushort_t* __restrict__ w1l,
    ushort_t* __restrict__ w2h, ushort_t* __restrict__ w2l,
    ushort_t* __restrict__ l0h, ushort_t* __restrict__ l0l,
    ushort_t* __restrict__ l1h, ushort_t* __restrict__ l1l)
{
    int idx = blockIdx.x * 256 + threadIdx.x;
    const float* w; ushort_t *bh, *bl; int K, N, local;
    if (idx < W1_T) { w = w1; bh = w1h; bl = w1l; K = F_IN; N = HIDDEN; local = idx; }
    else if (idx < W1_T + W2_T) { w = w2; bh = w2h; bl = w2l; K = HIDDEN; N = DIM; local = idx - W1_T; }
    else if (idx < W1_T + W2_T + L_T) { w = l0; bh = l0h; bl = l0l; K = DIM; N = 512; local = idx - W1_T - W2_T; }
    else if (idx < W1_T + W2_T + 2 * L_T) { w = l1; bh = l1h; bl = l1l; K = DIM; N = 512; local = idx - W1_T - W2_T - L_T; }
    else return;
    const int j = local & 7;
    const int rem = local >> 3;
    const int n = rem % N;
    const int k = (rem / N) * 8 + j;
    const float v = (k < K) ? w[(size_t)k * N + n] : 0.f;
    bh[local] = (ushort_t)hi16(v);
    bl[local] = (ushort_t)lo16(v);
}

// ---- wa for BOTH layers in one launch: item = L*1024 + sd*512 + h*128 + d ----
__global__ __launch_bounds__(256) void wa2_kernel(
    const float* __restrict__ lin0, const float* __restrict__ lin1,
    const float* __restrict__ atts0, const float* __restrict__ attd0,
    const float* __restrict__ atts1, const float* __restrict__ attd1,
    float* __restrict__ wa_s0, float* __restrict__ wa_d0,
    float* __restrict__ wa_s1, float* __restrict__ wa_d1)
{
    const int wrk = blockIdx.x * 256 + threadIdx.x;
    if (wrk >= 2048) return;
    const int L = wrk >> 10;
    const int sd = (wrk >> 9) & 1;
    const int p = wrk & 511;
    const int h = p >> 7, d = p & 127;
    const float* lin = L ? lin1 : lin0;
    const float* av = L ? (sd ? attd1 : atts1) : (sd ? attd0 : atts0);
    float* out = L ? (sd ? wa_d1 : wa_s1) : (sd ? wa_d0 : wa_s0);
    const float* lp = lin + (size_t)d * (NH * DIM) + h * DIM;
    const float* ap = av + h * DIM;
    float acc = 0.f;
    #pragma unroll 8
    for (int i = 0; i < DIM; ++i) acc += lp[i] * ap[i];
    out[h * DIM + d] = acc;
}

// ---- a_s[n,h], a_d[n,h] from xbuf (fp32 [N][128]) ----
__global__ __launch_bounds__(256) void as_ad_kernel(
    const float* __restrict__ xb, const float* __restrict__ wa_s,
    const float* __restrict__ wa_d, float* __restrict__ a_s, float* __restrict__ a_d)
{
    const int gw = blockIdx.x * 4 + (threadIdx.x >> 6);
    const int lane = threadIdx.x & 63;
    if (gw >= N_NODES * NH) return;
    const int n = gw >> 2, h = gw & 3;
    const float* hp = xb + (size_t)n * DIM;
    float2 hv = *(const float2*)(hp + lane * 2);
    float2 sv = *(const float2*)(wa_s + h * DIM + lane * 2);
    float2 dv = *(const float2*)(wa_d + h * DIM + lane * 2);
    float s = hv.x * sv.x + hv.y * sv.y;
    float d = hv.x * dv.x + hv.y * dv.y;
    #pragma unroll
    for (int off = 32; off > 0; off >>= 1) {
        s += __shfl_down(s, off);
        d += __shfl_down(d, off);
    }
    if (lane == 0) { a_s[n * 4 + h] = s; a_d[n * 4 + h] = d; }
}

// ---- rel attention tables for BOTH layers: blockIdx.x = layer ----
__global__ __launch_bounds__(128) void rel_table2_kernel(
    const float* __restrict__ rel_emb,
    const float* __restrict__ line0, const float* __restrict__ atte0,
    const float* __restrict__ line1, const float* __restrict__ atte1,
    float* __restrict__ table)          // [2][128]
{
    __shared__ float we[32][NH];
    const int L = blockIdx.x;
    const float* line = L ? line1 : line0;
    const float* atte = L ? atte1 : atte0;
    float* tab = table + L * 128;
    const int tid = threadIdx.x;
    const int k = tid >> 2, h = tid & 3;
    float acc = 0.f;
    for (int d = 0; d < DIM; ++d)
        acc += line[(size_t)k * (NH * DIM) + h * DIM + d] * atte[h * DIM + d];
    we[k][h] = acc;
    __syncthreads();
    if (tid < 26 * NH) {
        int r = tid >> 2, hh = tid & 3;
        float t = 0.f;
        for (int kk = 0; kk < 32; ++kk) t += rel_emb[r * 32 + kk] * we[kk][hh];
        tab[r * 4 + hh] = t;
    }
}

// ================= CSR build =================
__global__ __launch_bounds__(256) void hist_kernel(
    const int* __restrict__ dst, int* __restrict__ cnt)
{
    const int e = blockIdx.x * blockDim.x + threadIdx.x;
    if (e >= N_EDGES) return;
    atomicAdd(&cnt[dst[e]], 1);
}

__global__ __launch_bounds__(1024) void scan_kernel(
    const int* __restrict__ cnt, int* __restrict__ ptr, int* __restrict__ ptr_copy)
{
    __shared__ int tsum[1024];
    const int tid = threadIdx.x;
    const int CH = 20;
    const int base = tid * CH;
    int s = 0;
    #pragma unroll
    for (int i = 0; i < CH; ++i) {
        int idx = base + i;
        if (idx < N_NODES) s += cnt[idx];
    }
    tsum[tid] = s;
    __syncthreads();
    for (int off = 1; off < 1024; off <<= 1) {
        int v = (tid >= off) ? tsum[tid - off] : 0;
        __syncthreads();
        tsum[tid] += v;
        __syncthreads();
    }
    int run = (tid == 0) ? 0 : tsum[tid - 1];
    #pragma unroll
    for (int i = 0; i < CH; ++i) {
        int idx = base + i;
        if (idx < N_NODES) {
            ptr[idx] = run;
            ptr_copy[idx] = run;
            run += cnt[idx];
        }
    }
    if (tid == 0) ptr[N_NODES] = N_EDGES;
}

__global__ __launch_bounds__(256) void scatter_kernel(
    const int* __restrict__ src, const int* __restrict__ dst, const int* __restrict__ etype,
    int* __restrict__ ptr_copy, int2* __restrict__ se)
{
    const int e = blockIdx.x * blockDim.x + threadIdx.x;
    if (e >= N_EDGES) return;
    const int d = dst[e];
    const int pos = atomicAdd(&ptr_copy[d], 1);
    se[pos] = make_int2(src[e], etype[e]);
}

// ===== fused per-node GAT aggregate; 2 WAVES PER NODE (halved serial chain) =====
// Block = 256 thr = 4 waves = 2 nodes. Wave pair splits the CSR segment;
// LDS-combine; wave 0 does self-loop + epilogue (+ fused next-layer a_s/a_d).
// hb: bf16 [n][512]. Lane l covers cols l*8..l*8+7, head = l>>4.
__global__ __launch_bounds__(256) void node_agg2_kernel(
    const int* __restrict__ ptr, const int2* __restrict__ se,
    const float* __restrict__ a_s, const float* __restrict__ a_d,
    const float* __restrict__ table, const ushort_t* __restrict__ hb,
    const float* __restrict__ bias,
    float* __restrict__ outf, ushort_t* __restrict__ oa,
    const float* __restrict__ wa_s2, const float* __restrict__ wa_d2,
    float* __restrict__ a_s2, float* __restrict__ a_d2)
{
    __shared__ float red[2][64][11];   // [slot][lane][acc8 + dh + eh], +pad
    const int tid = threadIdx.x;
    const int wave = tid >> 6, lane = tid & 63;
    const int slot = wave >> 1, half = wave & 1;
    const int n = blockIdx.x * 2 + slot;     // grid = N_NODES/2 exactly
    const int head = lane >> 4;
    const int cbase = lane * 8;
    const int beg = ptr[n], end = ptr[n + 1];
    const int mid = beg + ((end - beg + 1) >> 1);
    const int lo = half ? mid : beg;
    const int hi = half ? end : mid;
    const float adh = a_d[n * 4 + head];

    float acc[8] = {};
    float dh = 0.f, eh = 0.f;

    int j = lo;
    for (; j + 2 <= hi; j += 2) {
        const int2 E0 = se[j], E1 = se[j + 1];
        const uint4 g0 = *(const uint4*)(hb + (size_t)E0.x * 512 + cbase);
        const uint4 g1 = *(const uint4*)(hb + (size_t)E1.x * 512 + cbase);
        const float a0 = a_s[E0.x * 4 + head];
        const float t0 = table[E0.y * 4 + head];
        const float a1 = a_s[E1.x * 4 + head];
        const float t1 = table[E1.y * 4 + head];
        const float p0 = __expf(lrelu02(a0 + adh + t0));
        const float p1 = __expf(lrelu02(a1 + adh + t1));
        eh += t0 + t1;
        dh += p0 + p1;
        acc[0] += p0 * bfl(g0.x) + p1 * bfl(g1.x);
        acc[1] += p0 * bfh(g0.x) + p1 * bfh(g1.x);
        acc[2] += p0 * bfl(g0.y) + p1 * bfl(g1.y);
        acc[3] += p0 * bfh(g0.y) + p1 * bfh(g1.y);
        acc[4] += p0 * bfl(g0.z) + p1 * bfl(g1.z);
        acc[5] += p0 * bfh(g0.z) + p1 * bfh(g1.z);
        acc[6] += p0 * bfl(g0.w) + p1 * bfl(g1.w);
        acc[7] += p0 * bfh(g0.w) + p1 * bfh(g1.w);
    }
    if (j < hi) {
        const int2 E0 = se[j];
        const uint4 g0 = *(const uint4*)(hb + (size_t)E0.x * 512 + cbase);
        const float a0 = a_s[E0.x * 4 + head];
        const float t0 = table[E0.y * 4 + head];
        const float p0 = __expf(lrelu02(a0 + adh + t0));
        eh += t0; dh += p0;
        acc[0] += p0 * bfl(g0.x); acc[1] += p0 * bfh(g0.x);
        acc[2] += p0 * bfl(g0.y); acc[3] += p0 * bfh(g0.y);
        acc[4] += p0 * bfl(g0.z); acc[5] += p0 * bfh(g0.z);
        acc[6] += p0 * bfl(g0.w); acc[7] += p0 * bfh(g0.w);
    }

    if (half == 1) {
        #pragma unroll
        for (int k = 0; k < 8; ++k) red[slot][lane][k] = acc[k];
        red[slot][lane][8] = dh;
        red[slot][lane][9] = eh;
    }
    __syncthreads();
    if (half == 1) return;

    #pragma unroll
    for (int k = 0; k < 8; ++k) acc[k] += red[slot][lane][k];
    dh += red[slot][lane][8];
    eh += red[slot][lane][9];

    // self-loop (fill_value='mean')
    const float inv = 1.0f / fmaxf((float)(end - beg), 1.0f);
    const float ps = __expf(lrelu02(a_s[n * 4 + head] + adh + eh * inv));
    dh += ps;
    {
        const uint4 gs = *(const uint4*)(hb + (size_t)n * 512 + cbase);
        acc[0] += ps * bfl(gs.x); acc[1] += ps * bfh(gs.x);
        acc[2] += ps * bfl(gs.y); acc[3] += ps * bfh(gs.y);
        acc[4] += ps * bfl(gs.z); acc[5] += ps * bfh(gs.z);
        acc[6] += ps * bfl(gs.w); acc[7] += ps * bfh(gs.w);
    }

    const float ih = 0.25f / (dh + 1e-16f);
    float t[8];
    #pragma unroll
    for (int k = 0; k < 8; ++k) {
        t[k] = acc[k] * ih;
        t[k] += __shfl_xor(t[k], 16);
        t[k] += __shfl_xor(t[k], 32);
    }
    if (lane < 16) {
        const float4 b0 = *(const float4*)(bias + cbase);
        const float4 b1 = *(const float4*)(bias + cbase + 4);
        float o[8];
        o[0] = fmaxf(t[0] + b0.x, 0.f); o[1] = fmaxf(t[1] + b0.y, 0.f);
        o[2] = fmaxf(t[2] + b0.z, 0.f); o[3] = fmaxf(t[3] + b0.w, 0.f);
        o[4] = fmaxf(t[4] + b1.x, 0.f); o[5] = fmaxf(t[5] + b1.y, 0.f);
        o[6] = fmaxf(t[6] + b1.z, 0.f); o[7] = fmaxf(t[7] + b1.w, 0.f);
        if (outf) {
            float4 v0 = {o[0], o[1], o[2], o[3]};
            float4 v1 = {o[4], o[5], o[6], o[7]};
            *(float4*)(outf + (size_t)n * DIM + cbase) = v0;
            *(float4*)(outf + (size_t)n * DIM + cbase + 4) = v1;
        }
        if (oa) {
            unsigned int up[4];
            #pragma unroll
            for (int i = 0; i < 4; ++i)
                up[i] = (rnd16(o[2*i+1]) << 16) | rnd16(o[2*i]);
            *(uint4*)(oa + ((size_t)lane * MP + n) * 8) = make_uint4(up[0], up[1], up[2], up[3]);
        }
        // fused next-layer a_s/a_d: per-head 128-dot over the output row
        if (wa_s2) {
            float pss[4] = {0,0,0,0}, pdd[4] = {0,0,0,0};
            #pragma unroll
            for (int h = 0; h < NH; ++h) {
                const float* ws = wa_s2 + h * DIM + cbase;
                const float* wd = wa_d2 + h * DIM + cbase;
                #pragma unroll
                for (int i = 0; i < 8; ++i) {
                    pss[h] += o[i] * ws[i];
                    pdd[h] += o[i] * wd[i];
                }
            }
            #pragma unroll
            for (int m = 1; m < 16; m <<= 1) {
                #pragma unroll
                for (int h = 0; h < NH; ++h) {
                    pss[h] += __shfl_xor(pss[h], m);
                    pdd[h] += __shfl_xor(pdd[h], m);
                }
            }
            if (lane == 0) {
                float4 vs = {pss[0], pss[1], pss[2], pss[3]};
                float4 vd = {pdd[0], pdd[1], pdd[2], pdd[3]};
                *(float4*)(a_s2 + n * 4) = vs;
                *(float4*)(a_d2 + n * 4) = vd;
            }
        }
    }
}

extern "C" void kernel_launch(void* const* d_in, const int* in_sizes, int n_in,
                              void* d_out, int out_size, void* d_ws, size_t ws_size,
                              hipStream_t stream)
{
    const float* x       = (const float*)d_in[0];
    const int*   eidx    = (const int*)d_in[1];
    const int*   etype   = (const int*)d_in[2];
    const float* w1      = (const float*)d_in[3];
    const float* b1      = (const float*)d_in[4];
    const float* w2      = (const float*)d_in[5];
    const float* b2      = (const float*)d_in[6];
    const float* rel_emb = (const float*)d_in[7];
    const float* lin[2]  = {(const float*)d_in[8],  (const float*)d_in[14]};
    const float* line[2] = {(const float*)d_in[9],  (const float*)d_in[15]};
    const float* atts[2] = {(const float*)d_in[10], (const float*)d_in[16]};
    const float* attd[2] = {(const float*)d_in[11], (const float*)d_in[17]};
    const float* atte[2] = {(const float*)d_in[12], (const float*)d_in[18]};
    const float* bias[2] = {(const float*)d_in[13], (const float*)d_in[19]};
    const int* src = eidx;
    const int* dst = eidx + N_EDGES;

    // ---- workspace layout ----
    char* base = (char*)d_ws;
    size_t off = 0;
    auto alloc = [&](size_t bytes) -> void* {
        void* p = base + off;
        off = (off + bytes + 255) & ~(size_t)255;
        return p;
    };
    ushort_t* xh  = (ushort_t*)alloc((size_t)68 * MP * 8 * 2);  // hb overlays (dead after enc1)
    ushort_t* xl  = (ushort_t*)alloc((size_t)68 * MP * 8 * 2);
    ushort_t* h1h = (ushort_t*)alloc((size_t)32 * MP * 8 * 2);
    ushort_t* h1l = (ushort_t*)alloc((size_t)32 * MP * 8 * 2);
    ushort_t* x0a = (ushort_t*)alloc((size_t)16 * MP * 8 * 2);
    void* reg1    = alloc((size_t)16 * MP * 8 * 4);             // xbuf0 fp32 | x1a
    ushort_t* w1h = (ushort_t*)alloc(W1_T * 2);
    ushort_t* w1l = (ushort_t*)alloc(W1_T * 2);
    ushort_t* w2h = (ushort_t*)alloc(W2_T * 2);
    ushort_t* w2l = (ushort_t*)alloc(W2_T * 2);
    ushort_t* l0h = (ushort_t*)alloc(L_T * 2);
    ushort_t* l0l = (ushort_t*)alloc(L_T * 2);
    ushort_t* l1h = (ushort_t*)alloc(L_T * 2);
    ushort_t* l1l = (ushort_t*)alloc(L_T * 2);
    float* a_s0  = (float*)alloc(N_NODES * 4 * 4);
    float* a_d0  = (float*)alloc(N_NODES * 4 * 4);
    float* a_s1  = (float*)alloc(N_NODES * 4 * 4);
    float* a_d1  = (float*)alloc(N_NODES * 4 * 4);
    float* table = (float*)alloc(2 * 128 * 4);
    float* wa_s0 = (float*)alloc(512 * 4);
    float* wa_d0 = (float*)alloc(512 * 4);
    float* wa_s1 = (float*)alloc(512 * 4);
    float* wa_d1 = (float*)alloc(512 * 4);
    int*  cnt_i  = (int*)alloc(N_NODES * 4);
    int*  ptr    = (int*)alloc((N_NODES + 4) * 4);
    int*  ptrc   = (int*)alloc(N_NODES * 4);
    int2* se     = (int2*)alloc((size_t)N_EDGES * 8);

    ushort_t* hb = xh;              // bf16 hfeat [MP][512], 20.5 MB (xh dead after enc1)
    float* xbuf0 = (float*)reg1;
    ushort_t* x1a = (ushort_t*)reg1;  // node_agg L0 bf16 A-layout out (xbuf0 dead after as_ad L0)

    const int mtiles = MP / 64;     // 313

    // ---- input conversions (merged launches) ----
    conv_a_t_kernel<<<dim3(MP / 64, 9), 256, 0, stream>>>(x, xh, xl);
    conv_w_all_kernel<<<(W1_T + W2_T + 2 * L_T + 255) / 256, 256, 0, stream>>>(
        w1, w2, lin[0], lin[1], w1h, w1l, w2h, w2l, l0h, l0l, l1h, l1l);
    wa2_kernel<<<8, 256, 0, stream>>>(lin[0], lin[1], atts[0], attd[0], atts[1], attd[1],
                                      wa_s0, wa_d0, wa_s1, wa_d1);
    rel_table2_kernel<<<2, 128, 0, stream>>>(rel_emb, line[0], atte[0], line[1], atte[1], table);

    // ---- CSR build ----
    hipMemsetAsync(cnt_i, 0, N_NODES * sizeof(int), stream);
    hist_kernel<<<(N_EDGES + 255) / 256, 256, 0, stream>>>(dst, cnt_i);
    scan_kernel<<<1, 1024, 0, stream>>>(cnt_i, ptr, ptrc);
    scatter_kernel<<<(N_EDGES + 255) / 256, 256, 0, stream>>>(src, dst, etype, ptrc, se);

    // ---- node encoder (3-term split) ----
    gemm_mfma_v2<<<dim3(HIDDEN / 128, mtiles), 256, 0, stream>>>(
        xh, xl, w1h, w1l, b1, N_NODES, 68, HIDDEN, 1, nullptr, h1h, h1l, nullptr, nullptr);
    gemm_mfma_v2<<<dim3(DIM / 128, mtiles), 256, 0, stream>>>(
        h1h, h1l, w2h, w2l, b2, N_NODES, 32, DIM, 0, xbuf0, nullptr, nullptr, nullptr, x0a);

    // ---- layer 0 (2-term: A quantized bf16) ----
    gemm_mfma_v2<<<dim3((NH * DIM) / 128, mtiles), 256, 0, stream>>>(
        x0a, nullptr, l0h, l0l, nullptr, N_NODES, 16, NH * DIM, 0, nullptr, nullptr, nullptr, hb, nullptr);
    as_ad_kernel<<<N_NODES, 256, 0, stream>>>(xbuf0, wa_s0, wa_d0, a_s0, a_d0);
    node_agg2_kernel<<<N_NODES / 2, 256, 0, stream>>>(
        ptr, se, a_s0, a_d0, table, hb, bias[0], nullptr, x1a,
        wa_s1, wa_d1, a_s1, a_d1);

    // ---- layer 1 (2-term; a_s/a_d computed by node_agg L0) ----
    gemm_mfma_v2<<<dim3((NH * DIM) / 128, mtiles), 256, 0, stream>>>(
        x1a, nullptr, l1h, l1l, nullptr, N_NODES, 16, NH * DIM, 0, nullptr, nullptr, nullptr, hb, nullptr);
    node_agg2_kernel<<<N_NODES / 2, 256, 0, stream>>>(
        ptr, se, a_s1, a_d1, table + 128, hb, bias[1], (float*)d_out, nullptr,
        nullptr, nullptr, nullptr, nullptr);
}

// Round 12
// 425.622 us; speedup vs baseline: 1.6755x; 1.0008x over previous
//
#include <hip/hip_runtime.h>
#include <math.h>

#define N_NODES 20000
#define MP      20032          // M padded to 64
#define N_EDGES 320000
#define F_IN    518
#define HIDDEN  256
#define DIM     128
#define NH      4

typedef __attribute__((ext_vector_type(8))) short bf16x8;
typedef __attribute__((ext_vector_type(4))) float f32x4;
typedef unsigned short ushort_t;

__device__ __forceinline__ float lrelu02(float x) { return x > 0.f ? x : 0.2f * x; }

__device__ __forceinline__ void gl_lds16(const void* g, void* l) {
    __builtin_amdgcn_global_load_lds(
        (const __attribute__((address_space(1))) unsigned int*)g,
        (__attribute__((address_space(3))) unsigned int*)l, 16, 0, 0);
}

__device__ __forceinline__ unsigned int hi16(float v) { return __float_as_uint(v) >> 16; }
__device__ __forceinline__ unsigned int lo16(float v) {
    unsigned int h = __float_as_uint(v) & 0xFFFF0000u;
    return __float_as_uint(v - __uint_as_float(h)) >> 16;
}
// round-to-nearest-even bf16
__device__ __forceinline__ unsigned int rnd16(float v) {
    unsigned int u = __float_as_uint(v);
    return (u + 0x7FFFu + ((u >> 16) & 1u)) >> 16;
}
__device__ __forceinline__ float bfl(unsigned int u) { return __uint_as_float(u << 16); }
__device__ __forceinline__ float bfh(unsigned int u) { return __uint_as_float(u & 0xFFFF0000u); }

// ====== split-bf16 MFMA GEMM, operands pre-split, k-chunk-major ======
__global__ __launch_bounds__(256, 4) void gemm_mfma_v2(
    const ushort_t* __restrict__ Ah, const ushort_t* __restrict__ Al,
    const ushort_t* __restrict__ Bh, const ushort_t* __restrict__ Bl,
    const float* __restrict__ bias,
    int M, int K8, int N, int act,
    float* __restrict__ Cf,                                      // fp32 [M][N]
    ushort_t* __restrict__ Ch, ushort_t* __restrict__ Cl,        // split A-layout
    ushort_t* __restrict__ Cb,                                   // plain bf16 [M][N]
    ushort_t* __restrict__ Ca)                                   // plain bf16 A-layout
{
    __shared__ __align__(16) ushort_t lds[12288];
    const int tid = threadIdx.x;
    const int w = tid >> 6, lane = tid & 63;
    const int row0 = blockIdx.y * 64, col0 = blockIdx.x * 128;
    const int nkb = K8 >> 2;
    const int m16 = lane & 15, q = lane >> 4;
    const bool use_al = (Al != nullptr);

    f32x4 acc[4][2] = {};

    for (int kb = 0; kb < nkb; ++kb) {
        const size_t kc = (size_t)(kb * 4 + w);
        const size_t aoff = (kc * MP + row0) * 8 + lane * 8;
        const size_t boff = (kc * N + col0) * 8 + lane * 8;
        gl_lds16(Ah + aoff, &lds[w * 512]);
        if (use_al) gl_lds16(Al + aoff, &lds[2048 + w * 512]);
        gl_lds16(Bh + boff,       &lds[4096 + w * 1024]);
        gl_lds16(Bh + boff + 512, &lds[4096 + w * 1024 + 512]);
        gl_lds16(Bl + boff,       &lds[8192 + w * 1024]);
        gl_lds16(Bl + boff + 512, &lds[8192 + w * 1024 + 512]);
        __syncthreads();

        bf16x8 fah[4], fal[4], fbh[2], fbl[2];
        const int fa = q * 512 + m16 * 8;
        #pragma unroll
        for (int mi = 0; mi < 4; ++mi) {
            fah[mi] = *(const bf16x8*)&lds[fa + mi * 128];
            if (use_al) fal[mi] = *(const bf16x8*)&lds[2048 + fa + mi * 128];
        }
        const int fb = q * 1024 + (w * 32 + m16) * 8;
        #pragma unroll
        for (int ni = 0; ni < 2; ++ni) {
            fbh[ni] = *(const bf16x8*)&lds[4096 + fb + ni * 128];
            fbl[ni] = *(const bf16x8*)&lds[8192 + fb + ni * 128];
        }
        #pragma unroll
        for (int mi = 0; mi < 4; ++mi)
            #pragma unroll
            for (int ni = 0; ni < 2; ++ni) {
                acc[mi][ni] = __builtin_amdgcn_mfma_f32_16x16x32_bf16(fah[mi], fbh[ni], acc[mi][ni], 0, 0, 0);
                acc[mi][ni] = __builtin_amdgcn_mfma_f32_16x16x32_bf16(fah[mi], fbl[ni], acc[mi][ni], 0, 0, 0);
            }
        if (use_al) {
            #pragma unroll
            for (int mi = 0; mi < 4; ++mi)
                #pragma unroll
                for (int ni = 0; ni < 2; ++ni)
                    acc[mi][ni] = __builtin_amdgcn_mfma_f32_16x16x32_bf16(fal[mi], fbh[ni], acc[mi][ni], 0, 0, 0);
        }
        __syncthreads();
    }

    // epilogue: C/D row=(lane>>4)*4+reg, col=lane&15
    #pragma unroll
    for (int ni = 0; ni < 2; ++ni) {
        const int col = col0 + w * 32 + ni * 16 + m16;
        const float bb = bias ? bias[col] : 0.f;
        #pragma unroll
        for (int mi = 0; mi < 4; ++mi) {
            #pragma unroll
            for (int r = 0; r < 4; ++r) {
                const int row = row0 + mi * 16 + q * 4 + r;
                if (row < M) {
                    float v = acc[mi][ni][r] + bb;
                    if (act) v = fmaxf(v, 0.f);
                    if (Cf) Cf[(size_t)row * N + col] = v;
                    if (Cb) Cb[(size_t)row * N + col] = (ushort_t)rnd16(v);
                    const size_t p = (((size_t)(col >> 3)) * MP + row) * 8 + (col & 7);
                    if (Ch) { Ch[p] = (ushort_t)hi16(v); Cl[p] = (ushort_t)lo16(v); }
                    if (Ca) Ca[p] = (ushort_t)rnd16(v);
                }
            }
        }
    }
}

// ---- x fp32 [N_NODES][F_IN] -> xh/xl bf16 [K8][MP][8], coalesced via LDS tile ----
__global__ __launch_bounds__(256) void conv_a_t_kernel(
    const float* __restrict__ x, ushort_t* __restrict__ xh, ushort_t* __restrict__ xl)
{
    __shared__ float tile[64][68];
    const int tid = threadIdx.x;
    const int r0 = blockIdx.x * 64;
    const int c0 = blockIdx.y * 64;

    #pragma unroll
    for (int it = 0; it < 4; ++it) {
        const int r = (tid >> 4) + it * 16;
        const int c = (tid & 15) * 4;
        const int gr = r0 + r, gc = c0 + c;
        float4 v = {0.f, 0.f, 0.f, 0.f};
        if (gr < N_NODES) {
            if (gc + 3 < F_IN) {
                v = *(const float4*)(x + (size_t)gr * F_IN + gc);
            } else {
                float tmp[4] = {0.f, 0.f, 0.f, 0.f};
                #pragma unroll
                for (int u = 0; u < 4; ++u)
                    if (gc + u < F_IN) tmp[u] = x[(size_t)gr * F_IN + gc + u];
                v.x = tmp[0]; v.y = tmp[1]; v.z = tmp[2]; v.w = tmp[3];
            }
        }
        tile[r][c] = v.x; tile[r][c+1] = v.y; tile[r][c+2] = v.z; tile[r][c+3] = v.w;
    }
    __syncthreads();

    const int k8l = tid >> 5;
    const int k8 = (c0 >> 3) + k8l;
    if (k8 >= 68) return;
    const int rr = (tid & 31) * 2;
    #pragma unroll
    for (int u = 0; u < 2; ++u) {
        const int r = rr + u;
        unsigned int hp[4], lp[4];
        #pragma unroll
        for (int i = 0; i < 4; ++i) {
            const float v0 = tile[r][k8l * 8 + 2 * i];
            const float v1 = tile[r][k8l * 8 + 2 * i + 1];
            hp[i] = (hi16(v1) << 16) | hi16(v0);
            lp[i] = (lo16(v1) << 16) | lo16(v0);
        }
        const size_t p = ((size_t)k8 * MP + r0 + r) * 8;
        *(uint4*)(xh + p) = make_uint4(hp[0], hp[1], hp[2], hp[3]);
        *(uint4*)(xl + p) = make_uint4(lp[0], lp[1], lp[2], lp[3]);
    }
}

// ---- all 4 weights fp32 -> bf16 hi/lo [K8][N][8] in ONE launch ----
#define W1_T (68 * 256 * 8)
#define W2_T (32 * 128 * 8)
#define L_T  (16 * 512 * 8)
__global__ __launch_bounds__(256) void conv_w_all_kernel(
    const float* __restrict__ w1, const float* __restrict__ w2,
    const float* __restrict__ l0, const float* __restrict__ l1,
    ushort_t* __restrict__ w1h, ushort_t* __restrict__ w1l,
    ushort_t* __restrict__ w2h, ushort_t* __restrict__ w2l,
    ushort_t* __restrict__ l0h, ushort_t* __restrict__ l0l,
    ushort_t* __restrict__ l1h, ushort_t* __restrict__ l1l)
{
    int idx = blockIdx.x * 256 + threadIdx.x;
    const float* w; ushort_t *bh, *bl; int K, N, local;
    if (idx < W1_T) { w = w1; bh = w1h; bl = w1l; K = F_IN; N = HIDDEN; local = idx; }
    else if (idx < W1_T + W2_T) { w = w2; bh = w2h; bl = w2l; K = HIDDEN; N = DIM; local = idx - W1_T; }
    else if (idx < W1_T + W2_T + L_T) { w = l0; bh = l0h; bl = l0l; K = DIM; N = 512; local = idx - W1_T - W2_T; }
    else if (idx < W1_T + W2_T + 2 * L_T) { w = l1; bh = l1h; bl = l1l; K = DIM; N = 512; local = idx - W1_T - W2_T - L_T; }
    else return;
    const int j = local & 7;
    const int rem = local >> 3;
    const int n = rem % N;
    const int k = (rem / N) * 8 + j;
    const float v = (k < K) ? w[(size_t)k * N + n] : 0.f;
    bh[local] = (ushort_t)hi16(v);
    bl[local] = (ushort_t)lo16(v);
}

// ---- wa for BOTH layers in one launch ----
__global__ __launch_bounds__(256) void wa2_kernel(
    const float* __restrict__ lin0, const float* __restrict__ lin1,
    const float* __restrict__ atts0, const float* __restrict__ attd0,
    const float* __restrict__ atts1, const float* __restrict__ attd1,
    float* __restrict__ wa_s0, float* __restrict__ wa_d0,
    float* __restrict__ wa_s1, float* __restrict__ wa_d1)
{
    const int wrk = blockIdx.x * 256 + threadIdx.x;
    if (wrk >= 2048) return;
    const int L = wrk >> 10;
    const int sd = (wrk >> 9) & 1;
    const int p = wrk & 511;
    const int h = p >> 7, d = p & 127;
    const float* lin = L ? lin1 : lin0;
    const float* av = L ? (sd ? attd1 : atts1) : (sd ? attd0 : atts0);
    float* out = L ? (sd ? wa_d1 : wa_s1) : (sd ? wa_d0 : wa_s0);
    const float* lp = lin + (size_t)d * (NH * DIM) + h * DIM;
    const float* ap = av + h * DIM;
    float acc = 0.f;
    #pragma unroll 8
    for (int i = 0; i < DIM; ++i) acc += lp[i] * ap[i];
    out[h * DIM + d] = acc;
}

// ---- a_s[n,h], a_d[n,h] from xbuf (fp32 [N][128]) ----
__global__ __launch_bounds__(256) void as_ad_kernel(
    const float* __restrict__ xb, const float* __restrict__ wa_s,
    const float* __restrict__ wa_d, float* __restrict__ a_s, float* __restrict__ a_d)
{
    const int gw = blockIdx.x * 4 + (threadIdx.x >> 6);
    const int lane = threadIdx.x & 63;
    if (gw >= N_NODES * NH) return;
    const int n = gw >> 2, h = gw & 3;
    const float* hp = xb + (size_t)n * DIM;
    float2 hv = *(const float2*)(hp + lane * 2);
    float2 sv = *(const float2*)(wa_s + h * DIM + lane * 2);
    float2 dv = *(const float2*)(wa_d + h * DIM + lane * 2);
    float s = hv.x * sv.x + hv.y * sv.y;
    float d = hv.x * dv.x + hv.y * dv.y;
    #pragma unroll
    for (int off = 32; off > 0; off >>= 1) {
        s += __shfl_down(s, off);
        d += __shfl_down(d, off);
    }
    if (lane == 0) { a_s[n * 4 + h] = s; a_d[n * 4 + h] = d; }
}

// ---- rel attention tables for BOTH layers: blockIdx.x = layer ----
__global__ __launch_bounds__(128) void rel_table2_kernel(
    const float* __restrict__ rel_emb,
    const float* __restrict__ line0, const float* __restrict__ atte0,
    const float* __restrict__ line1, const float* __restrict__ atte1,
    float* __restrict__ table)          // [2][128]
{
    __shared__ float we[32][NH];
    const int L = blockIdx.x;
    const float* line = L ? line1 : line0;
    const float* atte = L ? atte1 : atte0;
    float* tab = table + L * 128;
    const int tid = threadIdx.x;
    const int k = tid >> 2, h = tid & 3;
    float acc = 0.f;
    for (int d = 0; d < DIM; ++d)
        acc += line[(size_t)k * (NH * DIM) + h * DIM + d] * atte[h * DIM + d];
    we[k][h] = acc;
    __syncthreads();
    if (tid < 26 * NH) {
        int r = tid >> 2, hh = tid & 3;
        float t = 0.f;
        for (int kk = 0; kk < 32; ++kk) t += rel_emb[r * 32 + kk] * we[kk][hh];
        tab[r * 4 + hh] = t;
    }
}

// ================= CSR build =================
__global__ __launch_bounds__(256) void hist_kernel(
    const int* __restrict__ dst, int* __restrict__ cnt)
{
    const int e = blockIdx.x * blockDim.x + threadIdx.x;
    if (e >= N_EDGES) return;
    atomicAdd(&cnt[dst[e]], 1);
}

__global__ __launch_bounds__(1024) void scan_kernel(
    const int* __restrict__ cnt, int* __restrict__ ptr, int* __restrict__ ptr_copy)
{
    __shared__ int tsum[1024];
    const int tid = threadIdx.x;
    const int CH = 20;
    const int base = tid * CH;
    int s = 0;
    #pragma unroll
    for (int i = 0; i < CH; ++i) {
        int idx = base + i;
        if (idx < N_NODES) s += cnt[idx];
    }
    tsum[tid] = s;
    __syncthreads();
    for (int off = 1; off < 1024; off <<= 1) {
        int v = (tid >= off) ? tsum[tid - off] : 0;
        __syncthreads();
        tsum[tid] += v;
        __syncthreads();
    }
    int run = (tid == 0) ? 0 : tsum[tid - 1];
    #pragma unroll
    for (int i = 0; i < CH; ++i) {
        int idx = base + i;
        if (idx < N_NODES) {
            ptr[idx] = run;
            ptr_copy[idx] = run;
            run += cnt[idx];
        }
    }
    if (tid == 0) ptr[N_NODES] = N_EDGES;
}

__global__ __launch_bounds__(256) void scatter_kernel(
    const int* __restrict__ src, const int* __restrict__ dst, const int* __restrict__ etype,
    int* __restrict__ ptr_copy, int2* __restrict__ se)
{
    const int e = blockIdx.x * blockDim.x + threadIdx.x;
    if (e >= N_EDGES) return;
    const int d = dst[e];
    const int pos = atomicAdd(&ptr_copy[d], 1);
    se[pos] = make_int2(src[e], etype[e]);
}

// ===== fused per-node GAT aggregate; 1 wave/node; SW-PIPELINED edge pairs =====
// hb: bf16 [n][512]. Lane l covers cols l*8..l*8+7, head = l>>4.
// Next pair's records + gathers prefetched into registers before computing
// the current pair (breaks the load->use serial chain).
__global__ __launch_bounds__(256) void node_agg_p_kernel(
    const int* __restrict__ ptr, const int2* __restrict__ se,
    const float* __restrict__ a_s, const float* __restrict__ a_d,
    const float* __restrict__ table, const ushort_t* __restrict__ hb,
    const float* __restrict__ bias,
    float* __restrict__ outf, ushort_t* __restrict__ oa,
    const float* __restrict__ wa_s2, const float* __restrict__ wa_d2,
    float* __restrict__ a_s2, float* __restrict__ a_d2)
{
    const int n = blockIdx.x * 4 + (threadIdx.x >> 6);
    const int lane = threadIdx.x & 63;
    if (n >= N_NODES) return;
    const int beg = ptr[n], end = ptr[n + 1];
    const int head = lane >> 4;
    const int cbase = lane * 8;
    const float adh = a_d[n * 4 + head];

    float acc[8] = {};
    float dh = 0.f, eh = 0.f;

    int j = beg;
    uint4 ga, gb;
    float aa, ta, ab, tb;
    bool have = (j + 2 <= end);
    if (have) {
        const int2 Ea = se[j], Eb = se[j + 1];
        ga = *(const uint4*)(hb + (size_t)Ea.x * 512 + cbase);
        gb = *(const uint4*)(hb + (size_t)Eb.x * 512 + cbase);
        aa = a_s[Ea.x * 4 + head]; ta = table[Ea.y * 4 + head];
        ab = a_s[Eb.x * 4 + head]; tb = table[Eb.y * 4 + head];
    }
    while (have) {
        const uint4 g0 = ga, g1 = gb;
        const float a0 = aa, t0 = ta, a1 = ab, t1 = tb;
        j += 2;
        have = (j + 2 <= end);
        if (have) {                      // prefetch next pair before computing
            const int2 Ea = se[j], Eb = se[j + 1];
            ga = *(const uint4*)(hb + (size_t)Ea.x * 512 + cbase);
            gb = *(const uint4*)(hb + (size_t)Eb.x * 512 + cbase);
            aa = a_s[Ea.x * 4 + head]; ta = table[Ea.y * 4 + head];
            ab = a_s[Eb.x * 4 + head]; tb = table[Eb.y * 4 + head];
        }
        const float p0 = __expf(lrelu02(a0 + adh + t0));
        const float p1 = __expf(lrelu02(a1 + adh + t1));
        eh += t0 + t1;
        dh += p0 + p1;
        acc[0] += p0 * bfl(g0.x) + p1 * bfl(g1.x);
        acc[1] += p0 * bfh(g0.x) + p1 * bfh(g1.x);
        acc[2] += p0 * bfl(g0.y) + p1 * bfl(g1.y);
        acc[3] += p0 * bfh(g0.y) + p1 * bfh(g1.y);
        acc[4] += p0 * bfl(g0.z) + p1 * bfl(g1.z);
        acc[5] += p0 * bfh(g0.z) + p1 * bfh(g1.z);
        acc[6] += p0 * bfl(g0.w) + p1 * bfl(g1.w);
        acc[7] += p0 * bfh(g0.w) + p1 * bfh(g1.w);
    }
    for (; j < end; ++j) {               // tail (0 or 1 edge; whole loop if deg<2)
        const int2 E0 = se[j];
        const uint4 g0 = *(const uint4*)(hb + (size_t)E0.x * 512 + cbase);
        const float a0 = a_s[E0.x * 4 + head];
        const float t0 = table[E0.y * 4 + head];
        const float p0 = __expf(lrelu02(a0 + adh + t0));
        eh += t0; dh += p0;
        acc[0] += p0 * bfl(g0.x); acc[1] += p0 * bfh(g0.x);
        acc[2] += p0 * bfl(g0.y); acc[3] += p0 * bfh(g0.y);
        acc[4] += p0 * bfl(g0.z); acc[5] += p0 * bfh(g0.z);
        acc[6] += p0 * bfl(g0.w); acc[7] += p0 * bfh(g0.w);
    }

    // self-loop (fill_value='mean')
    const float inv = 1.0f / fmaxf((float)(end - beg), 1.0f);
    const float ps = __expf(lrelu02(a_s[n * 4 + head] + adh + eh * inv));
    dh += ps;
    {
        const uint4 gs = *(const uint4*)(hb + (size_t)n * 512 + cbase);
        acc[0] += ps * bfl(gs.x); acc[1] += ps * bfh(gs.x);
        acc[2] += ps * bfl(gs.y); acc[3] += ps * bfh(gs.y);
        acc[4] += ps * bfl(gs.z); acc[5] += ps * bfh(gs.z);
        acc[6] += ps * bfl(gs.w); acc[7] += ps * bfh(gs.w);
    }

    const float ih = 0.25f / (dh + 1e-16f);
    float t[8];
    #pragma unroll
    for (int k = 0; k < 8; ++k) {
        t[k] = acc[k] * ih;
        t[k] += __shfl_xor(t[k], 16);
        t[k] += __shfl_xor(t[k], 32);
    }
    if (lane < 16) {
        const float4 b0 = *(const float4*)(bias + cbase);
        const float4 b1 = *(const float4*)(bias + cbase + 4);
        float o[8];
        o[0] = fmaxf(t[0] + b0.x, 0.f); o[1] = fmaxf(t[1] + b0.y, 0.f);
        o[2] = fmaxf(t[2] + b0.z, 0.f); o[3] = fmaxf(t[3] + b0.w, 0.f);
        o[4] = fmaxf(t[4] + b1.x, 0.f); o[5] = fmaxf(t[5] + b1.y, 0.f);
        o[6] = fmaxf(t[6] + b1.z, 0.f); o[7] = fmaxf(t[7] + b1.w, 0.f);
        if (outf) {
            float4 v0 = {o[0], o[1], o[2], o[3]};
            float4 v1 = {o[4], o[5], o[6], o[7]};
            *(float4*)(outf + (size_t)n * DIM + cbase) = v0;
            *(float4*)(outf + (size_t)n * DIM + cbase + 4) = v1;
        }
        if (oa) {
            unsigned int up[4];
            #pragma unroll
            for (int i = 0; i < 4; ++i)
                up[i] = (rnd16(o[2*i+1]) << 16) | rnd16(o[2*i]);
            *(uint4*)(oa + ((size_t)lane * MP + n) * 8) = make_uint4(up[0], up[1], up[2], up[3]);
        }
        // fused next-layer a_s/a_d: per-head 128-dot over the output row
        if (wa_s2) {
            float pss[4] = {0,0,0,0}, pdd[4] = {0,0,0,0};
            #pragma unroll
            for (int h = 0; h < NH; ++h) {
                const float* ws = wa_s2 + h * DIM + cbase;
                const float* wd = wa_d2 + h * DIM + cbase;
                #pragma unroll
                for (int i = 0; i < 8; ++i) {
                    pss[h] += o[i] * ws[i];
                    pdd[h] += o[i] * wd[i];
                }
            }
            #pragma unroll
            for (int m = 1; m < 16; m <<= 1) {
                #pragma unroll
                for (int h = 0; h < NH; ++h) {
                    pss[h] += __shfl_xor(pss[h], m);
                    pdd[h] += __shfl_xor(pdd[h], m);
                }
            }
            if (lane == 0) {
                float4 vs = {pss[0], pss[1], pss[2], pss[3]};
                float4 vd = {pdd[0], pdd[1], pdd[2], pdd[3]};
                *(float4*)(a_s2 + n * 4) = vs;
                *(float4*)(a_d2 + n * 4) = vd;
            }
        }
    }
}

extern "C" void kernel_launch(void* const* d_in, const int* in_sizes, int n_in,
                              void* d_out, int out_size, void* d_ws, size_t ws_size,
                              hipStream_t stream)
{
    const float* x       = (const float*)d_in[0];
    const int*   eidx    = (const int*)d_in[1];
    const int*   etype   = (const int*)d_in[2];
    const float* w1      = (const float*)d_in[3];
    const float* b1      = (const float*)d_in[4];
    const float* w2      = (const float*)d_in[5];
    const float* b2      = (const float*)d_in[6];
    const float* rel_emb = (const float*)d_in[7];
    const float* lin[2]  = {(const float*)d_in[8],  (const float*)d_in[14]};
    const float* line[2] = {(const float*)d_in[9],  (const float*)d_in[15]};
    const float* atts[2] = {(const float*)d_in[10], (const float*)d_in[16]};
    const float* attd[2] = {(const float*)d_in[11], (const float*)d_in[17]};
    const float* atte[2] = {(const float*)d_in[12], (const float*)d_in[18]};
    const float* bias[2] = {(const float*)d_in[13], (const float*)d_in[19]};
    const int* src = eidx;
    const int* dst = eidx + N_EDGES;

    // ---- workspace layout ----
    char* base = (char*)d_ws;
    size_t off = 0;
    auto alloc = [&](size_t bytes) -> void* {
        void* p = base + off;
        off = (off + bytes + 255) & ~(size_t)255;
        return p;
    };
    ushort_t* xh  = (ushort_t*)alloc((size_t)68 * MP * 8 * 2);  // hb overlays (dead after enc1)
    ushort_t* xl  = (ushort_t*)alloc((size_t)68 * MP * 8 * 2);
    ushort_t* h1h = (ushort_t*)alloc((size_t)32 * MP * 8 * 2);
    ushort_t* h1l = (ushort_t*)alloc((size_t)32 * MP * 8 * 2);
    ushort_t* x0a = (ushort_t*)alloc((size_t)16 * MP * 8 * 2);
    void* reg1    = alloc((size_t)16 * MP * 8 * 4);             // xbuf0 fp32 | x1a
    ushort_t* w1h = (ushort_t*)alloc(W1_T * 2);
    ushort_t* w1l = (ushort_t*)alloc(W1_T * 2);
    ushort_t* w2h = (ushort_t*)alloc(W2_T * 2);
    ushort_t* w2l = (ushort_t*)alloc(W2_T * 2);
    ushort_t* l0h = (ushort_t*)alloc(L_T * 2);
    ushort_t* l0l = (ushort_t*)alloc(L_T * 2);
    ushort_t* l1h = (ushort_t*)alloc(L_T * 2);
    ushort_t* l1l = (ushort_t*)alloc(L_T * 2);
    float* a_s0  = (float*)alloc(N_NODES * 4 * 4);
    float* a_d0  = (float*)alloc(N_NODES * 4 * 4);
    float* a_s1  = (float*)alloc(N_NODES * 4 * 4);
    float* a_d1  = (float*)alloc(N_NODES * 4 * 4);
    float* table = (float*)alloc(2 * 128 * 4);
    float* wa_s0 = (float*)alloc(512 * 4);
    float* wa_d0 = (float*)alloc(512 * 4);
    float* wa_s1 = (float*)alloc(512 * 4);
    float* wa_d1 = (float*)alloc(512 * 4);
    int*  cnt_i  = (int*)alloc(N_NODES * 4);
    int*  ptr    = (int*)alloc((N_NODES + 4) * 4);
    int*  ptrc   = (int*)alloc(N_NODES * 4);
    int2* se     = (int2*)alloc((size_t)N_EDGES * 8);

    ushort_t* hb = xh;              // bf16 hfeat [MP][512], 20.5 MB (xh dead after enc1)
    float* xbuf0 = (float*)reg1;
    ushort_t* x1a = (ushort_t*)reg1;  // node_agg L0 bf16 A-layout out (xbuf0 dead after as_ad L0)

    const int mtiles = MP / 64;     // 313

    // ---- input conversions (merged launches) ----
    conv_a_t_kernel<<<dim3(MP / 64, 9), 256, 0, stream>>>(x, xh, xl);
    conv_w_all_kernel<<<(W1_T + W2_T + 2 * L_T + 255) / 256, 256, 0, stream>>>(
        w1, w2, lin[0], lin[1], w1h, w1l, w2h, w2l, l0h, l0l, l1h, l1l);
    wa2_kernel<<<8, 256, 0, stream>>>(lin[0], lin[1], atts[0], attd[0], atts[1], attd[1],
                                      wa_s0, wa_d0, wa_s1, wa_d1);
    rel_table2_kernel<<<2, 128, 0, stream>>>(rel_emb, line[0], atte[0], line[1], atte[1], table);

    // ---- CSR build ----
    hipMemsetAsync(cnt_i, 0, N_NODES * sizeof(int), stream);
    hist_kernel<<<(N_EDGES + 255) / 256, 256, 0, stream>>>(dst, cnt_i);
    scan_kernel<<<1, 1024, 0, stream>>>(cnt_i, ptr, ptrc);
    scatter_kernel<<<(N_EDGES + 255) / 256, 256, 0, stream>>>(src, dst, etype, ptrc, se);

    // ---- node encoder (3-term split) ----
    gemm_mfma_v2<<<dim3(HIDDEN / 128, mtiles), 256, 0, stream>>>(
        xh, xl, w1h, w1l, b1, N_NODES, 68, HIDDEN, 1, nullptr, h1h, h1l, nullptr, nullptr);
    gemm_mfma_v2<<<dim3(DIM / 128, mtiles), 256, 0, stream>>>(
        h1h, h1l, w2h, w2l, b2, N_NODES, 32, DIM, 0, xbuf0, nullptr, nullptr, nullptr, x0a);

    // ---- layer 0 (2-term: A quantized bf16) ----
    gemm_mfma_v2<<<dim3((NH * DIM) / 128, mtiles), 256, 0, stream>>>(
        x0a, nullptr, l0h, l0l, nullptr, N_NODES, 16, NH * DIM, 0, nullptr, nullptr, nullptr, hb, nullptr);
    as_ad_kernel<<<N_NODES, 256, 0, stream>>>(xbuf0, wa_s0, wa_d0, a_s0, a_d0);
    node_agg_p_kernel<<<(N_NODES + 3) / 4, 256, 0, stream>>>(
        ptr, se, a_s0, a_d0, table, hb, bias[0], nullptr, x1a,
        wa_s1, wa_d1, a_s1, a_d1);

    // ---- layer 1 (2-term; a_s/a_d computed by node_agg L0) ----
    gemm_mfma_v2<<<dim3((NH * DIM) / 128, mtiles), 256, 0, stream>>>(
        x1a, nullptr, l1h, l1l, nullptr, N_NODES, 16, NH * DIM, 0, nullptr, nullptr, nullptr, hb, nullptr);
    node_agg_p_kernel<<<(N_NODES + 3) / 4, 256, 0, stream>>>(
        ptr, se, a_s1, a_d1, table + 128, hb, bias[1], (float*)d_out, nullptr,
        nullptr, nullptr, nullptr, nullptr);
}

// Round 13
// 424.657 us; speedup vs baseline: 1.6793x; 1.0023x over previous
//
#include <hip/hip_runtime.h>
#include <math.h>

#define N_NODES 20000
#define MP      20032          // M padded to 64
#define N_EDGES 320000
#define F_IN    518
#define HIDDEN  256
#define DIM     128
#define NH      4

typedef __attribute__((ext_vector_type(8))) short bf16x8;
typedef __attribute__((ext_vector_type(4))) float f32x4;
typedef unsigned short ushort_t;

__device__ __forceinline__ float lrelu02(float x) { return x > 0.f ? x : 0.2f * x; }

__device__ __forceinline__ void gl_lds16(const void* g, void* l) {
    __builtin_amdgcn_global_load_lds(
        (const __attribute__((address_space(1))) unsigned int*)g,
        (__attribute__((address_space(3))) unsigned int*)l, 16, 0, 0);
}

__device__ __forceinline__ unsigned int hi16(float v) { return __float_as_uint(v) >> 16; }
__device__ __forceinline__ unsigned int lo16(float v) {
    unsigned int h = __float_as_uint(v) & 0xFFFF0000u;
    return __float_as_uint(v - __uint_as_float(h)) >> 16;
}
// round-to-nearest-even bf16
__device__ __forceinline__ unsigned int rnd16(float v) {
    unsigned int u = __float_as_uint(v);
    return (u + 0x7FFFu + ((u >> 16) & 1u)) >> 16;
}
__device__ __forceinline__ float bfl(unsigned int u) { return __uint_as_float(u << 16); }
__device__ __forceinline__ float bfh(unsigned int u) { return __uint_as_float(u & 0xFFFF0000u); }

// ====== split-bf16 MFMA GEMM, operands pre-split, k-chunk-major ======
__global__ __launch_bounds__(256, 4) void gemm_mfma_v2(
    const ushort_t* __restrict__ Ah, const ushort_t* __restrict__ Al,
    const ushort_t* __restrict__ Bh, const ushort_t* __restrict__ Bl,
    const float* __restrict__ bias,
    int M, int K8, int N, int act,
    float* __restrict__ Cf,                                      // fp32 [M][N]
    ushort_t* __restrict__ Ch, ushort_t* __restrict__ Cl,        // split A-layout
    ushort_t* __restrict__ Cb,                                   // plain bf16 [M][N]
    ushort_t* __restrict__ Ca)                                   // plain bf16 A-layout
{
    __shared__ __align__(16) ushort_t lds[12288];
    const int tid = threadIdx.x;
    const int w = tid >> 6, lane = tid & 63;
    const int row0 = blockIdx.y * 64, col0 = blockIdx.x * 128;
    const int nkb = K8 >> 2;
    const int m16 = lane & 15, q = lane >> 4;
    const bool use_al = (Al != nullptr);

    f32x4 acc[4][2] = {};

    for (int kb = 0; kb < nkb; ++kb) {
        const size_t kc = (size_t)(kb * 4 + w);
        const size_t aoff = (kc * MP + row0) * 8 + lane * 8;
        const size_t boff = (kc * N + col0) * 8 + lane * 8;
        gl_lds16(Ah + aoff, &lds[w * 512]);
        if (use_al) gl_lds16(Al + aoff, &lds[2048 + w * 512]);
        gl_lds16(Bh + boff,       &lds[4096 + w * 1024]);
        gl_lds16(Bh + boff + 512, &lds[4096 + w * 1024 + 512]);
        gl_lds16(Bl + boff,       &lds[8192 + w * 1024]);
        gl_lds16(Bl + boff + 512, &lds[8192 + w * 1024 + 512]);
        __syncthreads();

        bf16x8 fah[4], fal[4], fbh[2], fbl[2];
        const int fa = q * 512 + m16 * 8;
        #pragma unroll
        for (int mi = 0; mi < 4; ++mi) {
            fah[mi] = *(const bf16x8*)&lds[fa + mi * 128];
            if (use_al) fal[mi] = *(const bf16x8*)&lds[2048 + fa + mi * 128];
        }
        const int fb = q * 1024 + (w * 32 + m16) * 8;
        #pragma unroll
        for (int ni = 0; ni < 2; ++ni) {
            fbh[ni] = *(const bf16x8*)&lds[4096 + fb + ni * 128];
            fbl[ni] = *(const bf16x8*)&lds[8192 + fb + ni * 128];
        }
        #pragma unroll
        for (int mi = 0; mi < 4; ++mi)
            #pragma unroll
            for (int ni = 0; ni < 2; ++ni) {
                acc[mi][ni] = __builtin_amdgcn_mfma_f32_16x16x32_bf16(fah[mi], fbh[ni], acc[mi][ni], 0, 0, 0);
                acc[mi][ni] = __builtin_amdgcn_mfma_f32_16x16x32_bf16(fah[mi], fbl[ni], acc[mi][ni], 0, 0, 0);
            }
        if (use_al) {
            #pragma unroll
            for (int mi = 0; mi < 4; ++mi)
                #pragma unroll
                for (int ni = 0; ni < 2; ++ni)
                    acc[mi][ni] = __builtin_amdgcn_mfma_f32_16x16x32_bf16(fal[mi], fbh[ni], acc[mi][ni], 0, 0, 0);
        }
        __syncthreads();
    }

    // epilogue: C/D row=(lane>>4)*4+reg, col=lane&15
    #pragma unroll
    for (int ni = 0; ni < 2; ++ni) {
        const int col = col0 + w * 32 + ni * 16 + m16;
        const float bb = bias ? bias[col] : 0.f;
        #pragma unroll
        for (int mi = 0; mi < 4; ++mi) {
            #pragma unroll
            for (int r = 0; r < 4; ++r) {
                const int row = row0 + mi * 16 + q * 4 + r;
                if (row < M) {
                    float v = acc[mi][ni][r] + bb;
                    if (act) v = fmaxf(v, 0.f);
                    if (Cf) Cf[(size_t)row * N + col] = v;
                    if (Cb) Cb[(size_t)row * N + col] = (ushort_t)rnd16(v);
                    const size_t p = (((size_t)(col >> 3)) * MP + row) * 8 + (col & 7);
                    if (Ch) { Ch[p] = (ushort_t)hi16(v); Cl[p] = (ushort_t)lo16(v); }
                    if (Ca) Ca[p] = (ushort_t)rnd16(v);
                }
            }
        }
    }
}

// ---- x fp32 [N_NODES][F_IN] -> xh/xl bf16 [K8][MP][8], coalesced via LDS tile ----
__global__ __launch_bounds__(256) void conv_a_t_kernel(
    const float* __restrict__ x, ushort_t* __restrict__ xh, ushort_t* __restrict__ xl)
{
    __shared__ float tile[64][68];
    const int tid = threadIdx.x;
    const int r0 = blockIdx.x * 64;
    const int c0 = blockIdx.y * 64;

    #pragma unroll
    for (int it = 0; it < 4; ++it) {
        const int r = (tid >> 4) + it * 16;
        const int c = (tid & 15) * 4;
        const int gr = r0 + r, gc = c0 + c;
        float4 v = {0.f, 0.f, 0.f, 0.f};
        if (gr < N_NODES) {
            if (gc + 3 < F_IN) {
                v = *(const float4*)(x + (size_t)gr * F_IN + gc);
            } else {
                float tmp[4] = {0.f, 0.f, 0.f, 0.f};
                #pragma unroll
                for (int u = 0; u < 4; ++u)
                    if (gc + u < F_IN) tmp[u] = x[(size_t)gr * F_IN + gc + u];
                v.x = tmp[0]; v.y = tmp[1]; v.z = tmp[2]; v.w = tmp[3];
            }
        }
        tile[r][c] = v.x; tile[r][c+1] = v.y; tile[r][c+2] = v.z; tile[r][c+3] = v.w;
    }
    __syncthreads();

    const int k8l = tid >> 5;
    const int k8 = (c0 >> 3) + k8l;
    if (k8 >= 68) return;
    const int rr = (tid & 31) * 2;
    #pragma unroll
    for (int u = 0; u < 2; ++u) {
        const int r = rr + u;
        unsigned int hp[4], lp[4];
        #pragma unroll
        for (int i = 0; i < 4; ++i) {
            const float v0 = tile[r][k8l * 8 + 2 * i];
            const float v1 = tile[r][k8l * 8 + 2 * i + 1];
            hp[i] = (hi16(v1) << 16) | hi16(v0);
            lp[i] = (lo16(v1) << 16) | lo16(v0);
        }
        const size_t p = ((size_t)k8 * MP + r0 + r) * 8;
        *(uint4*)(xh + p) = make_uint4(hp[0], hp[1], hp[2], hp[3]);
        *(uint4*)(xl + p) = make_uint4(lp[0], lp[1], lp[2], lp[3]);
    }
}

// ---- all 4 weights fp32 -> bf16 hi/lo [K8][N][8] in ONE launch ----
#define W1_T (68 * 256 * 8)
#define W2_T (32 * 128 * 8)
#define L_T  (16 * 512 * 8)
__global__ __launch_bounds__(256) void conv_w_all_kernel(
    const float* __restrict__ w1, const float* __restrict__ w2,
    const float* __restrict__ l0, const float* __restrict__ l1,
    ushort_t* __restrict__ w1h, ushort_t* __restrict__ w1l,
    ushort_t* __restrict__ w2h, ushort_t* __restrict__ w2l,
    ushort_t* __restrict__ l0h, ushort_t* __restrict__ l0l,
    ushort_t* __restrict__ l1h, ushort_t* __restrict__ l1l)
{
    int idx = blockIdx.x * 256 + threadIdx.x;
    const float* w; ushort_t *bh, *bl; int K, N, local;
    if (idx < W1_T) { w = w1; bh = w1h; bl = w1l; K = F_IN; N = HIDDEN; local = idx; }
    else if (idx < W1_T + W2_T) { w = w2; bh = w2h; bl = w2l; K = HIDDEN; N = DIM; local = idx - W1_T; }
    else if (idx < W1_T + W2_T + L_T) { w = l0; bh = l0h; bl = l0l; K = DIM; N = 512; local = idx - W1_T - W2_T; }
    else if (idx < W1_T + W2_T + 2 * L_T) { w = l1; bh = l1h; bl = l1l; K = DIM; N = 512; local = idx - W1_T - W2_T - L_T; }
    else return;
    const int j = local & 7;
    const int rem = local >> 3;
    const int n = rem % N;
    const int k = (rem / N) * 8 + j;
    const float v = (k < K) ? w[(size_t)k * N + n] : 0.f;
    bh[local] = (ushort_t)hi16(v);
    bl[local] = (ushort_t)lo16(v);
}

// ---- wa for BOTH layers in one launch ----
__global__ __launch_bounds__(256) void wa2_kernel(
    const float* __restrict__ lin0, const float* __restrict__ lin1,
    const float* __restrict__ atts0, const float* __restrict__ attd0,
    const float* __restrict__ atts1, const float* __restrict__ attd1,
    float* __restrict__ wa_s0, float* __restrict__ wa_d0,
    float* __restrict__ wa_s1, float* __restrict__ wa_d1)
{
    const int wrk = blockIdx.x * 256 + threadIdx.x;
    if (wrk >= 2048) return;
    const int L = wrk >> 10;
    const int sd = (wrk >> 9) & 1;
    const int p = wrk & 511;
    const int h = p >> 7, d = p & 127;
    const float* lin = L ? lin1 : lin0;
    const float* av = L ? (sd ? attd1 : atts1) : (sd ? attd0 : atts0);
    float* out = L ? (sd ? wa_d1 : wa_s1) : (sd ? wa_d0 : wa_s0);
    const float* lp = lin + (size_t)d * (NH * DIM) + h * DIM;
    const float* ap = av + h * DIM;
    float acc = 0.f;
    #pragma unroll 8
    for (int i = 0; i < DIM; ++i) acc += lp[i] * ap[i];
    out[h * DIM + d] = acc;
}

// ---- a_s[n,h], a_d[n,h] from xbuf (fp32 [N][128]) ----
__global__ __launch_bounds__(256) void as_ad_kernel(
    const float* __restrict__ xb, const float* __restrict__ wa_s,
    const float* __restrict__ wa_d, float* __restrict__ a_s, float* __restrict__ a_d)
{
    const int gw = blockIdx.x * 4 + (threadIdx.x >> 6);
    const int lane = threadIdx.x & 63;
    if (gw >= N_NODES * NH) return;
    const int n = gw >> 2, h = gw & 3;
    const float* hp = xb + (size_t)n * DIM;
    float2 hv = *(const float2*)(hp + lane * 2);
    float2 sv = *(const float2*)(wa_s + h * DIM + lane * 2);
    float2 dv = *(const float2*)(wa_d + h * DIM + lane * 2);
    float s = hv.x * sv.x + hv.y * sv.y;
    float d = hv.x * dv.x + hv.y * dv.y;
    #pragma unroll
    for (int off = 32; off > 0; off >>= 1) {
        s += __shfl_down(s, off);
        d += __shfl_down(d, off);
    }
    if (lane == 0) { a_s[n * 4 + h] = s; a_d[n * 4 + h] = d; }
}

// ---- rel attention tables for BOTH layers: blockIdx.x = layer ----
__global__ __launch_bounds__(128) void rel_table2_kernel(
    const float* __restrict__ rel_emb,
    const float* __restrict__ line0, const float* __restrict__ atte0,
    const float* __restrict__ line1, const float* __restrict__ atte1,
    float* __restrict__ table)          // [2][128]
{
    __shared__ float we[32][NH];
    const int L = blockIdx.x;
    const float* line = L ? line1 : line0;
    const float* atte = L ? atte1 : atte0;
    float* tab = table + L * 128;
    const int tid = threadIdx.x;
    const int k = tid >> 2, h = tid & 3;
    float acc = 0.f;
    for (int d = 0; d < DIM; ++d)
        acc += line[(size_t)k * (NH * DIM) + h * DIM + d] * atte[h * DIM + d];
    we[k][h] = acc;
    __syncthreads();
    if (tid < 26 * NH) {
        int r = tid >> 2, hh = tid & 3;
        float t = 0.f;
        for (int kk = 0; kk < 32; ++kk) t += rel_emb[r * 32 + kk] * we[kk][hh];
        tab[r * 4 + hh] = t;
    }
}

// ================= CSR build =================
__global__ __launch_bounds__(256) void hist_kernel(
    const int* __restrict__ dst, int* __restrict__ cnt)
{
    const int e = blockIdx.x * blockDim.x + threadIdx.x;
    if (e >= N_EDGES) return;
    atomicAdd(&cnt[dst[e]], 1);
}

__global__ __launch_bounds__(1024) void scan_kernel(
    const int* __restrict__ cnt, int* __restrict__ ptr, int* __restrict__ ptr_copy)
{
    __shared__ int tsum[1024];
    const int tid = threadIdx.x;
    const int CH = 20;
    const int base = tid * CH;
    int s = 0;
    #pragma unroll
    for (int i = 0; i < CH; ++i) {
        int idx = base + i;
        if (idx < N_NODES) s += cnt[idx];
    }
    tsum[tid] = s;
    __syncthreads();
    for (int off = 1; off < 1024; off <<= 1) {
        int v = (tid >= off) ? tsum[tid - off] : 0;
        __syncthreads();
        tsum[tid] += v;
        __syncthreads();
    }
    int run = (tid == 0) ? 0 : tsum[tid - 1];
    #pragma unroll
    for (int i = 0; i < CH; ++i) {
        int idx = base + i;
        if (idx < N_NODES) {
            ptr[idx] = run;
            ptr_copy[idx] = run;
            run += cnt[idx];
        }
    }
    if (tid == 0) ptr[N_NODES] = N_EDGES;
}

__global__ __launch_bounds__(256) void scatter_kernel(
    const int* __restrict__ src, const int* __restrict__ dst, const int* __restrict__ etype,
    int* __restrict__ ptr_copy, int2* __restrict__ se)
{
    const int e = blockIdx.x * blockDim.x + threadIdx.x;
    if (e >= N_EDGES) return;
    const int d = dst[e];
    const int pos = atomicAdd(&ptr_copy[d], 1);
    se[pos] = make_int2(src[e], etype[e]);
}

// ===== fused per-node GAT aggregate; R9's plain x2 loop + fused epilogue =====
// hb: bf16 [n][512]. Lane l covers cols l*8..l*8+7, head = l>>4 — own-head
// math only; shfl_xor(16,32) sums heads. Optional fused next-layer a_s/a_d.
__global__ __launch_bounds__(256) void node_agg_f_kernel(
    const int* __restrict__ ptr, const int2* __restrict__ se,
    const float* __restrict__ a_s, const float* __restrict__ a_d,
    const float* __restrict__ table, const ushort_t* __restrict__ hb,
    const float* __restrict__ bias,
    float* __restrict__ outf, ushort_t* __restrict__ oa,
    const float* __restrict__ wa_s2, const float* __restrict__ wa_d2,
    float* __restrict__ a_s2, float* __restrict__ a_d2)
{
    const int n = blockIdx.x * 4 + (threadIdx.x >> 6);
    const int lane = threadIdx.x & 63;
    if (n >= N_NODES) return;
    const int beg = ptr[n], end = ptr[n + 1];
    const int head = lane >> 4;
    const int cbase = lane * 8;
    const float adh = a_d[n * 4 + head];

    float acc[8] = {};
    float dh = 0.f, eh = 0.f;

    int j = beg;
    for (; j + 2 <= end; j += 2) {
        const int2 E0 = se[j], E1 = se[j + 1];
        const uint4 g0 = *(const uint4*)(hb + (size_t)E0.x * 512 + cbase);
        const uint4 g1 = *(const uint4*)(hb + (size_t)E1.x * 512 + cbase);
        const float a0 = a_s[E0.x * 4 + head];
        const float t0 = table[E0.y * 4 + head];
        const float a1 = a_s[E1.x * 4 + head];
        const float t1 = table[E1.y * 4 + head];
        const float p0 = __expf(lrelu02(a0 + adh + t0));
        const float p1 = __expf(lrelu02(a1 + adh + t1));
        eh += t0 + t1;
        dh += p0 + p1;
        acc[0] += p0 * bfl(g0.x) + p1 * bfl(g1.x);
        acc[1] += p0 * bfh(g0.x) + p1 * bfh(g1.x);
        acc[2] += p0 * bfl(g0.y) + p1 * bfl(g1.y);
        acc[3] += p0 * bfh(g0.y) + p1 * bfh(g1.y);
        acc[4] += p0 * bfl(g0.z) + p1 * bfl(g1.z);
        acc[5] += p0 * bfh(g0.z) + p1 * bfh(g1.z);
        acc[6] += p0 * bfl(g0.w) + p1 * bfl(g1.w);
        acc[7] += p0 * bfh(g0.w) + p1 * bfh(g1.w);
    }
    if (j < end) {
        const int2 E0 = se[j];
        const uint4 g0 = *(const uint4*)(hb + (size_t)E0.x * 512 + cbase);
        const float a0 = a_s[E0.x * 4 + head];
        const float t0 = table[E0.y * 4 + head];
        const float p0 = __expf(lrelu02(a0 + adh + t0));
        eh += t0; dh += p0;
        acc[0] += p0 * bfl(g0.x); acc[1] += p0 * bfh(g0.x);
        acc[2] += p0 * bfl(g0.y); acc[3] += p0 * bfh(g0.y);
        acc[4] += p0 * bfl(g0.z); acc[5] += p0 * bfh(g0.z);
        acc[6] += p0 * bfl(g0.w); acc[7] += p0 * bfh(g0.w);
    }

    // self-loop (fill_value='mean')
    const float inv = 1.0f / fmaxf((float)(end - beg), 1.0f);
    const float ps = __expf(lrelu02(a_s[n * 4 + head] + adh + eh * inv));
    dh += ps;
    {
        const uint4 gs = *(const uint4*)(hb + (size_t)n * 512 + cbase);
        acc[0] += ps * bfl(gs.x); acc[1] += ps * bfh(gs.x);
        acc[2] += ps * bfl(gs.y); acc[3] += ps * bfh(gs.y);
        acc[4] += ps * bfl(gs.z); acc[5] += ps * bfh(gs.z);
        acc[6] += ps * bfl(gs.w); acc[7] += ps * bfh(gs.w);
    }

    const float ih = 0.25f / (dh + 1e-16f);
    float t[8];
    #pragma unroll
    for (int k = 0; k < 8; ++k) {
        t[k] = acc[k] * ih;
        t[k] += __shfl_xor(t[k], 16);
        t[k] += __shfl_xor(t[k], 32);
    }
    if (lane < 16) {
        const float4 b0 = *(const float4*)(bias + cbase);
        const float4 b1 = *(const float4*)(bias + cbase + 4);
        float o[8];
        o[0] = fmaxf(t[0] + b0.x, 0.f); o[1] = fmaxf(t[1] + b0.y, 0.f);
        o[2] = fmaxf(t[2] + b0.z, 0.f); o[3] = fmaxf(t[3] + b0.w, 0.f);
        o[4] = fmaxf(t[4] + b1.x, 0.f); o[5] = fmaxf(t[5] + b1.y, 0.f);
        o[6] = fmaxf(t[6] + b1.z, 0.f); o[7] = fmaxf(t[7] + b1.w, 0.f);
        if (outf) {
            float4 v0 = {o[0], o[1], o[2], o[3]};
            float4 v1 = {o[4], o[5], o[6], o[7]};
            *(float4*)(outf + (size_t)n * DIM + cbase) = v0;
            *(float4*)(outf + (size_t)n * DIM + cbase + 4) = v1;
        }
        if (oa) {
            unsigned int up[4];
            #pragma unroll
            for (int i = 0; i < 4; ++i)
                up[i] = (rnd16(o[2*i+1]) << 16) | rnd16(o[2*i]);
            *(uint4*)(oa + ((size_t)lane * MP + n) * 8) = make_uint4(up[0], up[1], up[2], up[3]);
        }
        // fused next-layer a_s/a_d: per-head 128-dot over the output row
        if (wa_s2) {
            float pss[4] = {0,0,0,0}, pdd[4] = {0,0,0,0};
            #pragma unroll
            for (int h = 0; h < NH; ++h) {
                const float* ws = wa_s2 + h * DIM + cbase;
                const float* wd = wa_d2 + h * DIM + cbase;
                #pragma unroll
                for (int i = 0; i < 8; ++i) {
                    pss[h] += o[i] * ws[i];
                    pdd[h] += o[i] * wd[i];
                }
            }
            #pragma unroll
            for (int m = 1; m < 16; m <<= 1) {
                #pragma unroll
                for (int h = 0; h < NH; ++h) {
                    pss[h] += __shfl_xor(pss[h], m);
                    pdd[h] += __shfl_xor(pdd[h], m);
                }
            }
            if (lane == 0) {
                float4 vs = {pss[0], pss[1], pss[2], pss[3]};
                float4 vd = {pdd[0], pdd[1], pdd[2], pdd[3]};
                *(float4*)(a_s2 + n * 4) = vs;
                *(float4*)(a_d2 + n * 4) = vd;
            }
        }
    }
}

extern "C" void kernel_launch(void* const* d_in, const int* in_sizes, int n_in,
                              void* d_out, int out_size, void* d_ws, size_t ws_size,
                              hipStream_t stream)
{
    const float* x       = (const float*)d_in[0];
    const int*   eidx    = (const int*)d_in[1];
    const int*   etype   = (const int*)d_in[2];
    const float* w1      = (const float*)d_in[3];
    const float* b1      = (const float*)d_in[4];
    const float* w2      = (const float*)d_in[5];
    const float* b2      = (const float*)d_in[6];
    const float* rel_emb = (const float*)d_in[7];
    const float* lin[2]  = {(const float*)d_in[8],  (const float*)d_in[14]};
    const float* line[2] = {(const float*)d_in[9],  (const float*)d_in[15]};
    const float* atts[2] = {(const float*)d_in[10], (const float*)d_in[16]};
    const float* attd[2] = {(const float*)d_in[11], (const float*)d_in[17]};
    const float* atte[2] = {(const float*)d_in[12], (const float*)d_in[18]};
    const float* bias[2] = {(const float*)d_in[13], (const float*)d_in[19]};
    const int* src = eidx;
    const int* dst = eidx + N_EDGES;

    // ---- workspace layout ----
    char* base = (char*)d_ws;
    size_t off = 0;
    auto alloc = [&](size_t bytes) -> void* {
        void* p = base + off;
        off = (off + bytes + 255) & ~(size_t)255;
        return p;
    };
    ushort_t* xh  = (ushort_t*)alloc((size_t)68 * MP * 8 * 2);  // hb overlays (dead after enc1)
    ushort_t* xl  = (ushort_t*)alloc((size_t)68 * MP * 8 * 2);
    ushort_t* h1h = (ushort_t*)alloc((size_t)32 * MP * 8 * 2);
    ushort_t* h1l = (ushort_t*)alloc((size_t)32 * MP * 8 * 2);
    ushort_t* x0a = (ushort_t*)alloc((size_t)16 * MP * 8 * 2);
    void* reg1    = alloc((size_t)16 * MP * 8 * 4);             // xbuf0 fp32 | x1a
    ushort_t* w1h = (ushort_t*)alloc(W1_T * 2);
    ushort_t* w1l = (ushort_t*)alloc(W1_T * 2);
    ushort_t* w2h = (ushort_t*)alloc(W2_T * 2);
    ushort_t* w2l = (ushort_t*)alloc(W2_T * 2);
    ushort_t* l0h = (ushort_t*)alloc(L_T * 2);
    ushort_t* l0l = (ushort_t*)alloc(L_T * 2);
    ushort_t* l1h = (ushort_t*)alloc(L_T * 2);
    ushort_t* l1l = (ushort_t*)alloc(L_T * 2);
    float* a_s0  = (float*)alloc(N_NODES * 4 * 4);
    float* a_d0  = (float*)alloc(N_NODES * 4 * 4);
    float* a_s1  = (float*)alloc(N_NODES * 4 * 4);
    float* a_d1  = (float*)alloc(N_NODES * 4 * 4);
    float* table = (float*)alloc(2 * 128 * 4);
    float* wa_s0 = (float*)alloc(512 * 4);
    float* wa_d0 = (float*)alloc(512 * 4);
    float* wa_s1 = (float*)alloc(512 * 4);
    float* wa_d1 = (float*)alloc(512 * 4);
    int*  cnt_i  = (int*)alloc(N_NODES * 4);
    int*  ptr    = (int*)alloc((N_NODES + 4) * 4);
    int*  ptrc   = (int*)alloc(N_NODES * 4);
    int2* se     = (int2*)alloc((size_t)N_EDGES * 8);

    ushort_t* hb = xh;              // bf16 hfeat [MP][512], 20.5 MB (xh dead after enc1)
    float* xbuf0 = (float*)reg1;
    ushort_t* x1a = (ushort_t*)reg1;  // node_agg L0 bf16 A-layout out (xbuf0 dead after as_ad L0)

    const int mtiles = MP / 64;     // 313

    // ---- input conversions (merged launches) ----
    conv_a_t_kernel<<<dim3(MP / 64, 9), 256, 0, stream>>>(x, xh, xl);
    conv_w_all_kernel<<<(W1_T + W2_T + 2 * L_T + 255) / 256, 256, 0, stream>>>(
        w1, w2, lin[0], lin[1], w1h, w1l, w2h, w2l, l0h, l0l, l1h, l1l);
    wa2_kernel<<<8, 256, 0, stream>>>(lin[0], lin[1], atts[0], attd[0], atts[1], attd[1],
                                      wa_s0, wa_d0, wa_s1, wa_d1);
    rel_table2_kernel<<<2, 128, 0, stream>>>(rel_emb, line[0], atte[0], line[1], atte[1], table);

    // ---- CSR build ----
    hipMemsetAsync(cnt_i, 0, N_NODES * sizeof(int), stream);
    hist_kernel<<<(N_EDGES + 255) / 256, 256, 0, stream>>>(dst, cnt_i);
    scan_kernel<<<1, 1024, 0, stream>>>(cnt_i, ptr, ptrc);
    scatter_kernel<<<(N_EDGES + 255) / 256, 256, 0, stream>>>(src, dst, etype, ptrc, se);

    // ---- node encoder (3-term split) ----
    gemm_mfma_v2<<<dim3(HIDDEN / 128, mtiles), 256, 0, stream>>>(
        xh, xl, w1h, w1l, b1, N_NODES, 68, HIDDEN, 1, nullptr, h1h, h1l, nullptr, nullptr);
    gemm_mfma_v2<<<dim3(DIM / 128, mtiles), 256, 0, stream>>>(
        h1h, h1l, w2h, w2l, b2, N_NODES, 32, DIM, 0, xbuf0, nullptr, nullptr, nullptr, x0a);

    // ---- layer 0 (2-term: A quantized bf16) ----
    gemm_mfma_v2<<<dim3((NH * DIM) / 128, mtiles), 256, 0, stream>>>(
        x0a, nullptr, l0h, l0l, nullptr, N_NODES, 16, NH * DIM, 0, nullptr, nullptr, nullptr, hb, nullptr);
    as_ad_kernel<<<N_NODES, 256, 0, stream>>>(xbuf0, wa_s0, wa_d0, a_s0, a_d0);
    node_agg_f_kernel<<<(N_NODES + 3) / 4, 256, 0, stream>>>(
        ptr, se, a_s0, a_d0, table, hb, bias[0], nullptr, x1a,
        wa_s1, wa_d1, a_s1, a_d1);

    // ---- layer 1 (2-term; a_s/a_d computed by node_agg L0) ----
    gemm_mfma_v2<<<dim3((NH * DIM) / 128, mtiles), 256, 0, stream>>>(
        x1a, nullptr, l1h, l1l, nullptr, N_NODES, 16, NH * DIM, 0, nullptr, nullptr, nullptr, hb, nullptr);
    node_agg_f_kernel<<<(N_NODES + 3) / 4, 256, 0, stream>>>(
        ptr, se, a_s1, a_d1, table + 128, hb, bias[1], (float*)d_out, nullptr,
        nullptr, nullptr, nullptr, nullptr);
}

// Round 14
// 416.261 us; speedup vs baseline: 1.7132x; 1.0202x over previous
//
#include <hip/hip_runtime.h>
#include <math.h>

#define N_NODES 20000
#define MP      20032          // M padded to 64
#define N_EDGES 320000
#define F_IN    518
#define HIDDEN  256
#define DIM     128
#define NH      4

typedef __attribute__((ext_vector_type(8))) short bf16x8;
typedef __attribute__((ext_vector_type(4))) float f32x4;
typedef unsigned short ushort_t;

__device__ __forceinline__ float lrelu02(float x) { return x > 0.f ? x : 0.2f * x; }

__device__ __forceinline__ void gl_lds16(const void* g, void* l) {
    __builtin_amdgcn_global_load_lds(
        (const __attribute__((address_space(1))) unsigned int*)g,
        (__attribute__((address_space(3))) unsigned int*)l, 16, 0, 0);
}

__device__ __forceinline__ unsigned int hi16(float v) { return __float_as_uint(v) >> 16; }
__device__ __forceinline__ unsigned int lo16(float v) {
    unsigned int h = __float_as_uint(v) & 0xFFFF0000u;
    return __float_as_uint(v - __uint_as_float(h)) >> 16;
}
// round-to-nearest-even bf16
__device__ __forceinline__ unsigned int rnd16(float v) {
    unsigned int u = __float_as_uint(v);
    return (u + 0x7FFFu + ((u >> 16) & 1u)) >> 16;
}
__device__ __forceinline__ float bfl(unsigned int u) { return __uint_as_float(u << 16); }
__device__ __forceinline__ float bfh(unsigned int u) { return __uint_as_float(u & 0xFFFF0000u); }

// ====== split-bf16 MFMA GEMM, operands pre-split, k-chunk-major ======
__global__ __launch_bounds__(256, 4) void gemm_mfma_v2(
    const ushort_t* __restrict__ Ah, const ushort_t* __restrict__ Al,
    const ushort_t* __restrict__ Bh, const ushort_t* __restrict__ Bl,
    const float* __restrict__ bias,
    int M, int K8, int N, int act,
    float* __restrict__ Cf,                                      // fp32 [M][N]
    ushort_t* __restrict__ Ch, ushort_t* __restrict__ Cl,        // split A-layout
    ushort_t* __restrict__ Cb,                                   // plain bf16 [M][N]
    ushort_t* __restrict__ Ca)                                   // plain bf16 A-layout
{
    __shared__ __align__(16) ushort_t lds[12288];
    const int tid = threadIdx.x;
    const int w = tid >> 6, lane = tid & 63;
    const int row0 = blockIdx.y * 64, col0 = blockIdx.x * 128;
    const int nkb = K8 >> 2;
    const int m16 = lane & 15, q = lane >> 4;
    const bool use_al = (Al != nullptr);

    f32x4 acc[4][2] = {};

    for (int kb = 0; kb < nkb; ++kb) {
        const size_t kc = (size_t)(kb * 4 + w);
        const size_t aoff = (kc * MP + row0) * 8 + lane * 8;
        const size_t boff = (kc * N + col0) * 8 + lane * 8;
        gl_lds16(Ah + aoff, &lds[w * 512]);
        if (use_al) gl_lds16(Al + aoff, &lds[2048 + w * 512]);
        gl_lds16(Bh + boff,       &lds[4096 + w * 1024]);
        gl_lds16(Bh + boff + 512, &lds[4096 + w * 1024 + 512]);
        gl_lds16(Bl + boff,       &lds[8192 + w * 1024]);
        gl_lds16(Bl + boff + 512, &lds[8192 + w * 1024 + 512]);
        __syncthreads();

        bf16x8 fah[4], fal[4], fbh[2], fbl[2];
        const int fa = q * 512 + m16 * 8;
        #pragma unroll
        for (int mi = 0; mi < 4; ++mi) {
            fah[mi] = *(const bf16x8*)&lds[fa + mi * 128];
            if (use_al) fal[mi] = *(const bf16x8*)&lds[2048 + fa + mi * 128];
        }
        const int fb = q * 1024 + (w * 32 + m16) * 8;
        #pragma unroll
        for (int ni = 0; ni < 2; ++ni) {
            fbh[ni] = *(const bf16x8*)&lds[4096 + fb + ni * 128];
            fbl[ni] = *(const bf16x8*)&lds[8192 + fb + ni * 128];
        }
        #pragma unroll
        for (int mi = 0; mi < 4; ++mi)
            #pragma unroll
            for (int ni = 0; ni < 2; ++ni) {
                acc[mi][ni] = __builtin_amdgcn_mfma_f32_16x16x32_bf16(fah[mi], fbh[ni], acc[mi][ni], 0, 0, 0);
                acc[mi][ni] = __builtin_amdgcn_mfma_f32_16x16x32_bf16(fah[mi], fbl[ni], acc[mi][ni], 0, 0, 0);
            }
        if (use_al) {
            #pragma unroll
            for (int mi = 0; mi < 4; ++mi)
                #pragma unroll
                for (int ni = 0; ni < 2; ++ni)
                    acc[mi][ni] = __builtin_amdgcn_mfma_f32_16x16x32_bf16(fal[mi], fbh[ni], acc[mi][ni], 0, 0, 0);
        }
        __syncthreads();
    }

    // epilogue: C/D row=(lane>>4)*4+reg, col=lane&15
    #pragma unroll
    for (int ni = 0; ni < 2; ++ni) {
        const int col = col0 + w * 32 + ni * 16 + m16;
        const float bb = bias ? bias[col] : 0.f;
        #pragma unroll
        for (int mi = 0; mi < 4; ++mi) {
            #pragma unroll
            for (int r = 0; r < 4; ++r) {
                const int row = row0 + mi * 16 + q * 4 + r;
                if (row < M) {
                    float v = acc[mi][ni][r] + bb;
                    if (act) v = fmaxf(v, 0.f);
                    if (Cf) Cf[(size_t)row * N + col] = v;
                    if (Cb) Cb[(size_t)row * N + col] = (ushort_t)rnd16(v);
                    const size_t p = (((size_t)(col >> 3)) * MP + row) * 8 + (col & 7);
                    if (Ch) { Ch[p] = (ushort_t)hi16(v); Cl[p] = (ushort_t)lo16(v); }
                    if (Ca) Ca[p] = (ushort_t)rnd16(v);
                }
            }
        }
    }
}

// ---- x fp32 [N_NODES][F_IN] -> xh/xl bf16 [K8][MP][8], coalesced via LDS tile ----
__global__ __launch_bounds__(256) void conv_a_t_kernel(
    const float* __restrict__ x, ushort_t* __restrict__ xh, ushort_t* __restrict__ xl)
{
    __shared__ float tile[64][68];
    const int tid = threadIdx.x;
    const int r0 = blockIdx.x * 64;
    const int c0 = blockIdx.y * 64;

    #pragma unroll
    for (int it = 0; it < 4; ++it) {
        const int r = (tid >> 4) + it * 16;
        const int c = (tid & 15) * 4;
        const int gr = r0 + r, gc = c0 + c;
        float4 v = {0.f, 0.f, 0.f, 0.f};
        if (gr < N_NODES) {
            if (gc + 3 < F_IN) {
                v = *(const float4*)(x + (size_t)gr * F_IN + gc);
            } else {
                float tmp[4] = {0.f, 0.f, 0.f, 0.f};
                #pragma unroll
                for (int u = 0; u < 4; ++u)
                    if (gc + u < F_IN) tmp[u] = x[(size_t)gr * F_IN + gc + u];
                v.x = tmp[0]; v.y = tmp[1]; v.z = tmp[2]; v.w = tmp[3];
            }
        }
        tile[r][c] = v.x; tile[r][c+1] = v.y; tile[r][c+2] = v.z; tile[r][c+3] = v.w;
    }
    __syncthreads();

    const int k8l = tid >> 5;
    const int k8 = (c0 >> 3) + k8l;
    if (k8 >= 68) return;
    const int rr = (tid & 31) * 2;
    #pragma unroll
    for (int u = 0; u < 2; ++u) {
        const int r = rr + u;
        unsigned int hp[4], lp[4];
        #pragma unroll
        for (int i = 0; i < 4; ++i) {
            const float v0 = tile[r][k8l * 8 + 2 * i];
            const float v1 = tile[r][k8l * 8 + 2 * i + 1];
            hp[i] = (hi16(v1) << 16) | hi16(v0);
            lp[i] = (lo16(v1) << 16) | lo16(v0);
        }
        const size_t p = ((size_t)k8 * MP + r0 + r) * 8;
        *(uint4*)(xh + p) = make_uint4(hp[0], hp[1], hp[2], hp[3]);
        *(uint4*)(xl + p) = make_uint4(lp[0], lp[1], lp[2], lp[3]);
    }
}

// ---- all 4 weights fp32 -> bf16 hi/lo [K8][N][8] in ONE launch ----
#define W1_T (68 * 256 * 8)
#define W2_T (32 * 128 * 8)
#define L_T  (16 * 512 * 8)
__global__ __launch_bounds__(256) void conv_w_all_kernel(
    const float* __restrict__ w1, const float* __restrict__ w2,
    const float* __restrict__ l0, const float* __restrict__ l1,
    ushort_t* __restrict__ w1h, ushort_t* __restrict__ w1l,
    ushort_t* __restrict__ w2h, ushort_t* __restrict__ w2l,
    ushort_t* __restrict__ l0h, ushort_t* __restrict__ l0l,
    ushort_t* __restrict__ l1h, ushort_t* __restrict__ l1l)
{
    int idx = blockIdx.x * 256 + threadIdx.x;
    const float* w; ushort_t *bh, *bl; int K, N, local;
    if (idx < W1_T) { w = w1; bh = w1h; bl = w1l; K = F_IN; N = HIDDEN; local = idx; }
    else if (idx < W1_T + W2_T) { w = w2; bh = w2h; bl = w2l; K = HIDDEN; N = DIM; local = idx - W1_T; }
    else if (idx < W1_T + W2_T + L_T) { w = l0; bh = l0h; bl = l0l; K = DIM; N = 512; local = idx - W1_T - W2_T; }
    else if (idx < W1_T + W2_T + 2 * L_T) { w = l1; bh = l1h; bl = l1l; K = DIM; N = 512; local = idx - W1_T - W2_T - L_T; }
    else return;
    const int j = local & 7;
    const int rem = local >> 3;
    const int n = rem % N;
    const int k = (rem / N) * 8 + j;
    const float v = (k < K) ? w[(size_t)k * N + n] : 0.f;
    bh[local] = (ushort_t)hi16(v);
    bl[local] = (ushort_t)lo16(v);
}

// ---- wa for BOTH layers in one launch ----
__global__ __launch_bounds__(256) void wa2_kernel(
    const float* __restrict__ lin0, const float* __restrict__ lin1,
    const float* __restrict__ atts0, const float* __restrict__ attd0,
    const float* __restrict__ atts1, const float* __restrict__ attd1,
    float* __restrict__ wa_s0, float* __restrict__ wa_d0,
    float* __restrict__ wa_s1, float* __restrict__ wa_d1)
{
    const int wrk = blockIdx.x * 256 + threadIdx.x;
    if (wrk >= 2048) return;
    const int L = wrk >> 10;
    const int sd = (wrk >> 9) & 1;
    const int p = wrk & 511;
    const int h = p >> 7, d = p & 127;
    const float* lin = L ? lin1 : lin0;
    const float* av = L ? (sd ? attd1 : atts1) : (sd ? attd0 : atts0);
    float* out = L ? (sd ? wa_d1 : wa_s1) : (sd ? wa_d0 : wa_s0);
    const float* lp = lin + (size_t)d * (NH * DIM) + h * DIM;
    const float* ap = av + h * DIM;
    float acc = 0.f;
    #pragma unroll 8
    for (int i = 0; i < DIM; ++i) acc += lp[i] * ap[i];
    out[h * DIM + d] = acc;
}

// ---- a_s[n,h], a_d[n,h] from xbuf (fp32 [N][128]) ----
__global__ __launch_bounds__(256) void as_ad_kernel(
    const float* __restrict__ xb, const float* __restrict__ wa_s,
    const float* __restrict__ wa_d, float* __restrict__ a_s, float* __restrict__ a_d)
{
    const int gw = blockIdx.x * 4 + (threadIdx.x >> 6);
    const int lane = threadIdx.x & 63;
    if (gw >= N_NODES * NH) return;
    const int n = gw >> 2, h = gw & 3;
    const float* hp = xb + (size_t)n * DIM;
    float2 hv = *(const float2*)(hp + lane * 2);
    float2 sv = *(const float2*)(wa_s + h * DIM + lane * 2);
    float2 dv = *(const float2*)(wa_d + h * DIM + lane * 2);
    float s = hv.x * sv.x + hv.y * sv.y;
    float d = hv.x * dv.x + hv.y * dv.y;
    #pragma unroll
    for (int off = 32; off > 0; off >>= 1) {
        s += __shfl_down(s, off);
        d += __shfl_down(d, off);
    }
    if (lane == 0) { a_s[n * 4 + h] = s; a_d[n * 4 + h] = d; }
}

// ---- rel attention tables for BOTH layers: blockIdx.x = layer ----
__global__ __launch_bounds__(128) void rel_table2_kernel(
    const float* __restrict__ rel_emb,
    const float* __restrict__ line0, const float* __restrict__ atte0,
    const float* __restrict__ line1, const float* __restrict__ atte1,
    float* __restrict__ table)          // [2][128]
{
    __shared__ float we[32][NH];
    const int L = blockIdx.x;
    const float* line = L ? line1 : line0;
    const float* atte = L ? atte1 : atte0;
    float* tab = table + L * 128;
    const int tid = threadIdx.x;
    const int k = tid >> 2, h = tid & 3;
    float acc = 0.f;
    for (int d = 0; d < DIM; ++d)
        acc += line[(size_t)k * (NH * DIM) + h * DIM + d] * atte[h * DIM + d];
    we[k][h] = acc;
    __syncthreads();
    if (tid < 26 * NH) {
        int r = tid >> 2, hh = tid & 3;
        float t = 0.f;
        for (int kk = 0; kk < 32; ++kk) t += rel_emb[r * 32 + kk] * we[kk][hh];
        tab[r * 4 + hh] = t;
    }
}

// ================= CSR build =================
__global__ __launch_bounds__(256) void hist_kernel(
    const int* __restrict__ dst, int* __restrict__ cnt)
{
    const int e = blockIdx.x * blockDim.x + threadIdx.x;
    if (e >= N_EDGES) return;
    atomicAdd(&cnt[dst[e]], 1);
}

__global__ __launch_bounds__(1024) void scan_kernel(
    const int* __restrict__ cnt, int* __restrict__ ptr, int* __restrict__ ptr_copy)
{
    __shared__ int tsum[1024];
    const int tid = threadIdx.x;
    const int CH = 20;
    const int base = tid * CH;
    int s = 0;
    #pragma unroll
    for (int i = 0; i < CH; ++i) {
        int idx = base + i;
        if (idx < N_NODES) s += cnt[idx];
    }
    tsum[tid] = s;
    __syncthreads();
    for (int off = 1; off < 1024; off <<= 1) {
        int v = (tid >= off) ? tsum[tid - off] : 0;
        __syncthreads();
        tsum[tid] += v;
        __syncthreads();
    }
    int run = (tid == 0) ? 0 : tsum[tid - 1];
    #pragma unroll
    for (int i = 0; i < CH; ++i) {
        int idx = base + i;
        if (idx < N_NODES) {
            ptr[idx] = run;
            ptr_copy[idx] = run;
            run += cnt[idx];
        }
    }
    if (tid == 0) ptr[N_NODES] = N_EDGES;
}

__global__ __launch_bounds__(256) void scatter_kernel(
    const int* __restrict__ src, const int* __restrict__ dst, const int* __restrict__ etype,
    int* __restrict__ ptr_copy, int2* __restrict__ se)
{
    const int e = blockIdx.x * blockDim.x + threadIdx.x;
    if (e >= N_EDGES) return;
    const int d = dst[e];
    const int pos = atomicAdd(&ptr_copy[d], 1);
    se[pos] = make_int2(src[e], etype[e]);
}

// ======== shared edge-loop body for node aggregation (inlined) ========
__device__ __forceinline__ void agg_loop(
    int beg, int end, int n, int head, int cbase,
    const int2* __restrict__ se, const float* __restrict__ a_s, float adh,
    const float* __restrict__ table, const ushort_t* __restrict__ hb,
    float acc[8], float& dh, float& eh)
{
    int j = beg;
    for (; j + 2 <= end; j += 2) {
        const int2 E0 = se[j], E1 = se[j + 1];
        const uint4 g0 = *(const uint4*)(hb + (size_t)E0.x * 512 + cbase);
        const uint4 g1 = *(const uint4*)(hb + (size_t)E1.x * 512 + cbase);
        const float a0 = a_s[E0.x * 4 + head];
        const float t0 = table[E0.y * 4 + head];
        const float a1 = a_s[E1.x * 4 + head];
        const float t1 = table[E1.y * 4 + head];
        const float p0 = __expf(lrelu02(a0 + adh + t0));
        const float p1 = __expf(lrelu02(a1 + adh + t1));
        eh += t0 + t1;
        dh += p0 + p1;
        acc[0] += p0 * bfl(g0.x) + p1 * bfl(g1.x);
        acc[1] += p0 * bfh(g0.x) + p1 * bfh(g1.x);
        acc[2] += p0 * bfl(g0.y) + p1 * bfl(g1.y);
        acc[3] += p0 * bfh(g0.y) + p1 * bfh(g1.y);
        acc[4] += p0 * bfl(g0.z) + p1 * bfl(g1.z);
        acc[5] += p0 * bfh(g0.z) + p1 * bfh(g1.z);
        acc[6] += p0 * bfl(g0.w) + p1 * bfl(g1.w);
        acc[7] += p0 * bfh(g0.w) + p1 * bfh(g1.w);
    }
    if (j < end) {
        const int2 E0 = se[j];
        const uint4 g0 = *(const uint4*)(hb + (size_t)E0.x * 512 + cbase);
        const float a0 = a_s[E0.x * 4 + head];
        const float t0 = table[E0.y * 4 + head];
        const float p0 = __expf(lrelu02(a0 + adh + t0));
        eh += t0; dh += p0;
        acc[0] += p0 * bfl(g0.x); acc[1] += p0 * bfh(g0.x);
        acc[2] += p0 * bfl(g0.y); acc[3] += p0 * bfh(g0.y);
        acc[4] += p0 * bfl(g0.z); acc[5] += p0 * bfh(g0.z);
        acc[6] += p0 * bfl(g0.w); acc[7] += p0 * bfh(g0.w);
    }
    // self-loop (fill_value='mean')
    const float inv = 1.0f / fmaxf((float)(end - beg), 1.0f);
    const float ps = __expf(lrelu02(a_s[n * 4 + head] + adh + eh * inv));
    dh += ps;
    const uint4 gs = *(const uint4*)(hb + (size_t)n * 512 + cbase);
    acc[0] += ps * bfl(gs.x); acc[1] += ps * bfh(gs.x);
    acc[2] += ps * bfl(gs.y); acc[3] += ps * bfh(gs.y);
    acc[4] += ps * bfl(gs.z); acc[5] += ps * bfh(gs.z);
    acc[6] += ps * bfl(gs.w); acc[7] += ps * bfh(gs.w);
}

// ===== L0 variant: bf16 A-layout out + FUSED next-layer a_s/a_d =====
__global__ __launch_bounds__(256) void node_agg_f_kernel(
    const int* __restrict__ ptr, const int2* __restrict__ se,
    const float* __restrict__ a_s, const float* __restrict__ a_d,
    const float* __restrict__ table, const ushort_t* __restrict__ hb,
    const float* __restrict__ bias, ushort_t* __restrict__ oa,
    const float* __restrict__ wa_s2, const float* __restrict__ wa_d2,
    float* __restrict__ a_s2, float* __restrict__ a_d2)
{
    const int n = blockIdx.x * 4 + (threadIdx.x >> 6);
    const int lane = threadIdx.x & 63;
    if (n >= N_NODES) return;
    const int beg = ptr[n], end = ptr[n + 1];
    const int head = lane >> 4;
    const int cbase = lane * 8;
    const float adh = a_d[n * 4 + head];

    float acc[8] = {};
    float dh = 0.f, eh = 0.f;
    agg_loop(beg, end, n, head, cbase, se, a_s, adh, table, hb, acc, dh, eh);

    const float ih = 0.25f / (dh + 1e-16f);
    float t[8];
    #pragma unroll
    for (int k = 0; k < 8; ++k) {
        t[k] = acc[k] * ih;
        t[k] += __shfl_xor(t[k], 16);
        t[k] += __shfl_xor(t[k], 32);
    }
    if (lane < 16) {
        const float4 b0 = *(const float4*)(bias + cbase);
        const float4 b1 = *(const float4*)(bias + cbase + 4);
        float o[8];
        o[0] = fmaxf(t[0] + b0.x, 0.f); o[1] = fmaxf(t[1] + b0.y, 0.f);
        o[2] = fmaxf(t[2] + b0.z, 0.f); o[3] = fmaxf(t[3] + b0.w, 0.f);
        o[4] = fmaxf(t[4] + b1.x, 0.f); o[5] = fmaxf(t[5] + b1.y, 0.f);
        o[6] = fmaxf(t[6] + b1.z, 0.f); o[7] = fmaxf(t[7] + b1.w, 0.f);
        unsigned int up[4];
        #pragma unroll
        for (int i = 0; i < 4; ++i)
            up[i] = (rnd16(o[2*i+1]) << 16) | rnd16(o[2*i]);
        *(uint4*)(oa + ((size_t)lane * MP + n) * 8) = make_uint4(up[0], up[1], up[2], up[3]);
        // fused next-layer a_s/a_d: per-head 128-dot over the output row
        float pss[4] = {0,0,0,0}, pdd[4] = {0,0,0,0};
        #pragma unroll
        for (int h = 0; h < NH; ++h) {
            const float* ws = wa_s2 + h * DIM + cbase;
            const float* wd = wa_d2 + h * DIM + cbase;
            #pragma unroll
            for (int i = 0; i < 8; ++i) {
                pss[h] += o[i] * ws[i];
                pdd[h] += o[i] * wd[i];
            }
        }
        #pragma unroll
        for (int m = 1; m < 16; m <<= 1) {
            #pragma unroll
            for (int h = 0; h < NH; ++h) {
                pss[h] += __shfl_xor(pss[h], m);
                pdd[h] += __shfl_xor(pdd[h], m);
            }
        }
        if (lane == 0) {
            float4 vs = {pss[0], pss[1], pss[2], pss[3]};
            float4 vd = {pdd[0], pdd[1], pdd[2], pdd[3]};
            *(float4*)(a_s2 + n * 4) = vs;
            *(float4*)(a_d2 + n * 4) = vd;
        }
    }
}

// ===== L1 variant: minimal R9 shape — fp32 out only, no fusion =====
__global__ __launch_bounds__(256) void node_agg_s_kernel(
    const int* __restrict__ ptr, const int2* __restrict__ se,
    const float* __restrict__ a_s, const float* __restrict__ a_d,
    const float* __restrict__ table, const ushort_t* __restrict__ hb,
    const float* __restrict__ bias, float* __restrict__ outf)
{
    const int n = blockIdx.x * 4 + (threadIdx.x >> 6);
    const int lane = threadIdx.x & 63;
    if (n >= N_NODES) return;
    const int beg = ptr[n], end = ptr[n + 1];
    const int head = lane >> 4;
    const int cbase = lane * 8;
    const float adh = a_d[n * 4 + head];

    float acc[8] = {};
    float dh = 0.f, eh = 0.f;
    agg_loop(beg, end, n, head, cbase, se, a_s, adh, table, hb, acc, dh, eh);

    const float ih = 0.25f / (dh + 1e-16f);
    float t[8];
    #pragma unroll
    for (int k = 0; k < 8; ++k) {
        t[k] = acc[k] * ih;
        t[k] += __shfl_xor(t[k], 16);
        t[k] += __shfl_xor(t[k], 32);
    }
    if (lane < 16) {
        const float4 b0 = *(const float4*)(bias + cbase);
        const float4 b1 = *(const float4*)(bias + cbase + 4);
        float4 v0, v1;
        v0.x = fmaxf(t[0] + b0.x, 0.f); v0.y = fmaxf(t[1] + b0.y, 0.f);
        v0.z = fmaxf(t[2] + b0.z, 0.f); v0.w = fmaxf(t[3] + b0.w, 0.f);
        v1.x = fmaxf(t[4] + b1.x, 0.f); v1.y = fmaxf(t[5] + b1.y, 0.f);
        v1.z = fmaxf(t[6] + b1.z, 0.f); v1.w = fmaxf(t[7] + b1.w, 0.f);
        *(float4*)(outf + (size_t)n * DIM + cbase) = v0;
        *(float4*)(outf + (size_t)n * DIM + cbase + 4) = v1;
    }
}

extern "C" void kernel_launch(void* const* d_in, const int* in_sizes, int n_in,
                              void* d_out, int out_size, void* d_ws, size_t ws_size,
                              hipStream_t stream)
{
    const float* x       = (const float*)d_in[0];
    const int*   eidx    = (const int*)d_in[1];
    const int*   etype   = (const int*)d_in[2];
    const float* w1      = (const float*)d_in[3];
    const float* b1      = (const float*)d_in[4];
    const float* w2      = (const float*)d_in[5];
    const float* b2      = (const float*)d_in[6];
    const float* rel_emb = (const float*)d_in[7];
    const float* lin[2]  = {(const float*)d_in[8],  (const float*)d_in[14]};
    const float* line[2] = {(const float*)d_in[9],  (const float*)d_in[15]};
    const float* atts[2] = {(const float*)d_in[10], (const float*)d_in[16]};
    const float* attd[2] = {(const float*)d_in[11], (const float*)d_in[17]};
    const float* atte[2] = {(const float*)d_in[12], (const float*)d_in[18]};
    const float* bias[2] = {(const float*)d_in[13], (const float*)d_in[19]};
    const int* src = eidx;
    const int* dst = eidx + N_EDGES;

    // ---- workspace layout ----
    char* base = (char*)d_ws;
    size_t off = 0;
    auto alloc = [&](size_t bytes) -> void* {
        void* p = base + off;
        off = (off + bytes + 255) & ~(size_t)255;
        return p;
    };
    ushort_t* xh  = (ushort_t*)alloc((size_t)68 * MP * 8 * 2);  // hb overlays (dead after enc1)
    ushort_t* xl  = (ushort_t*)alloc((size_t)68 * MP * 8 * 2);
    ushort_t* h1h = (ushort_t*)alloc((size_t)32 * MP * 8 * 2);
    ushort_t* h1l = (ushort_t*)alloc((size_t)32 * MP * 8 * 2);
    ushort_t* x0a = (ushort_t*)alloc((size_t)16 * MP * 8 * 2);
    void* reg1    = alloc((size_t)16 * MP * 8 * 4);             // xbuf0 fp32 | x1a
    ushort_t* w1h = (ushort_t*)alloc(W1_T * 2);
    ushort_t* w1l = (ushort_t*)alloc(W1_T * 2);
    ushort_t* w2h = (ushort_t*)alloc(W2_T * 2);
    ushort_t* w2l = (ushort_t*)alloc(W2_T * 2);
    ushort_t* l0h = (ushort_t*)alloc(L_T * 2);
    ushort_t* l0l = (ushort_t*)alloc(L_T * 2);
    ushort_t* l1h = (ushort_t*)alloc(L_T * 2);
    ushort_t* l1l = (ushort_t*)alloc(L_T * 2);
    float* a_s0  = (float*)alloc(N_NODES * 4 * 4);
    float* a_d0  = (float*)alloc(N_NODES * 4 * 4);
    float* a_s1  = (float*)alloc(N_NODES * 4 * 4);
    float* a_d1  = (float*)alloc(N_NODES * 4 * 4);
    float* table = (float*)alloc(2 * 128 * 4);
    float* wa_s0 = (float*)alloc(512 * 4);
    float* wa_d0 = (float*)alloc(512 * 4);
    float* wa_s1 = (float*)alloc(512 * 4);
    float* wa_d1 = (float*)alloc(512 * 4);
    int*  cnt_i  = (int*)alloc(N_NODES * 4);
    int*  ptr    = (int*)alloc((N_NODES + 4) * 4);
    int*  ptrc   = (int*)alloc(N_NODES * 4);
    int2* se     = (int2*)alloc((size_t)N_EDGES * 8);

    ushort_t* hb = xh;              // bf16 hfeat [MP][512], 20.5 MB (xh dead after enc1)
    float* xbuf0 = (float*)reg1;
    ushort_t* x1a = (ushort_t*)reg1;  // node_agg L0 bf16 A-layout out (xbuf0 dead after as_ad L0)

    const int mtiles = MP / 64;     // 313

    // ---- input conversions (merged launches) ----
    conv_a_t_kernel<<<dim3(MP / 64, 9), 256, 0, stream>>>(x, xh, xl);
    conv_w_all_kernel<<<(W1_T + W2_T + 2 * L_T + 255) / 256, 256, 0, stream>>>(
        w1, w2, lin[0], lin[1], w1h, w1l, w2h, w2l, l0h, l0l, l1h, l1l);
    wa2_kernel<<<8, 256, 0, stream>>>(lin[0], lin[1], atts[0], attd[0], atts[1], attd[1],
                                      wa_s0, wa_d0, wa_s1, wa_d1);
    rel_table2_kernel<<<2, 128, 0, stream>>>(rel_emb, line[0], atte[0], line[1], atte[1], table);

    // ---- CSR build ----
    hipMemsetAsync(cnt_i, 0, N_NODES * sizeof(int), stream);
    hist_kernel<<<(N_EDGES + 255) / 256, 256, 0, stream>>>(dst, cnt_i);
    scan_kernel<<<1, 1024, 0, stream>>>(cnt_i, ptr, ptrc);
    scatter_kernel<<<(N_EDGES + 255) / 256, 256, 0, stream>>>(src, dst, etype, ptrc, se);

    // ---- node encoder (3-term split) ----
    gemm_mfma_v2<<<dim3(HIDDEN / 128, mtiles), 256, 0, stream>>>(
        xh, xl, w1h, w1l, b1, N_NODES, 68, HIDDEN, 1, nullptr, h1h, h1l, nullptr, nullptr);
    gemm_mfma_v2<<<dim3(DIM / 128, mtiles), 256, 0, stream>>>(
        h1h, h1l, w2h, w2l, b2, N_NODES, 32, DIM, 0, xbuf0, nullptr, nullptr, nullptr, x0a);

    // ---- layer 0 (2-term: A quantized bf16) ----
    gemm_mfma_v2<<<dim3((NH * DIM) / 128, mtiles), 256, 0, stream>>>(
        x0a, nullptr, l0h, l0l, nullptr, N_NODES, 16, NH * DIM, 0, nullptr, nullptr, nullptr, hb, nullptr);
    as_ad_kernel<<<N_NODES, 256, 0, stream>>>(xbuf0, wa_s0, wa_d0, a_s0, a_d0);
    node_agg_f_kernel<<<(N_NODES + 3) / 4, 256, 0, stream>>>(
        ptr, se, a_s0, a_d0, table, hb, bias[0], x1a,
        wa_s1, wa_d1, a_s1, a_d1);

    // ---- layer 1 (2-term; a_s/a_d computed by node_agg L0; minimal kernel) ----
    gemm_mfma_v2<<<dim3((NH * DIM) / 128, mtiles), 256, 0, stream>>>(
        x1a, nullptr, l1h, l1l, nullptr, N_NODES, 16, NH * DIM, 0, nullptr, nullptr, nullptr, hb, nullptr);
    node_agg_s_kernel<<<(N_NODES + 3) / 4, 256, 0, stream>>>(
        ptr, se, a_s1, a_d1, table + 128, hb, bias[1], (float*)d_out);
}